// Round 2
// baseline (5283.958 us; speedup 1.0000x reference)
//
#include <hip/hip_runtime.h>
#include <cstdint>
#include <cstddef>

#define B_ 512
#define L_ 192
#define D_ 256
#define H_ 4
#define DH_ 64
#define FF_ 1024
#define NL_ 2
#define LP_ 30
#define LNEG_ 300
#define NF_ 13
#define M_ (B_*L_)   // 98304 tokens
#define NT_ 330      // LP_+LNEG_

// ---------------- embedding gather: x = attr_emb[attr] + ind_emb[attr_inds] ----------------
__global__ __launch_bounds__(256) void k_embed(
    const int* __restrict__ attr, const int* __restrict__ inds,
    const float* __restrict__ attr_emb, const float* __restrict__ ind_emb,
    float* __restrict__ x)
{
  int idx = blockIdx.x*256 + threadIdx.x;     // over M_*64 float4s
  int token = idx >> 6;
  int c = (idx & 63) * 4;
  int a = attr[token];
  int id = inds[token];
  const float4 e  = *(const float4*)(attr_emb + (size_t)a*D_ + c);
  const float4 ie = *(const float4*)(ind_emb  + (size_t)id*D_ + c);
  float4 o; o.x=e.x+ie.x; o.y=e.y+ie.y; o.z=e.z+ie.z; o.w=e.w+ie.w;
  *(float4*)(x + (size_t)token*D_ + c) = o;
}

// ---------------- fp32 GEMM: C[M,N] = A[M,K] @ W[N,K]^T + bias (+relu) ----------------
#define BM 128
#define BN 128
#define BK 16

__global__ __launch_bounds__(256) void k_gemm(
    const float* __restrict__ A, const float* __restrict__ W,
    const float* __restrict__ bias, float* __restrict__ C,
    int M, int N, int K, int relu)
{
  __shared__ float As[BK][BM+4];
  __shared__ float Bs[BK][BN+4];
  const int tid = threadIdx.x;
  const int tx = tid & 15, ty = tid >> 4;
  const int m0 = blockIdx.y * BM, n0 = blockIdx.x * BN;
  const int lr = tid >> 2;          // 0..63
  const int lk = (tid & 3) * 4;     // 0,4,8,12
  float acc[8][8];
  #pragma unroll
  for (int i=0;i<8;++i)
    #pragma unroll
    for (int j=0;j<8;++j) acc[i][j]=0.f;

  for (int k0 = 0; k0 < K; k0 += BK) {
    #pragma unroll
    for (int hh = 0; hh < 2; ++hh) {
      int row = lr + hh*64;
      float4 av = *(const float4*)(A + (size_t)(m0+row)*K + k0 + lk);
      As[lk+0][row]=av.x; As[lk+1][row]=av.y; As[lk+2][row]=av.z; As[lk+3][row]=av.w;
      float4 wv = *(const float4*)(W + (size_t)(n0+row)*K + k0 + lk);
      Bs[lk+0][row]=wv.x; Bs[lk+1][row]=wv.y; Bs[lk+2][row]=wv.z; Bs[lk+3][row]=wv.w;
    }
    __syncthreads();
    #pragma unroll
    for (int k=0;k<BK;++k) {
      float a[8], bb[8];
      *(float4*)&a[0]  = *(const float4*)&As[k][ty*8];
      *(float4*)&a[4]  = *(const float4*)&As[k][ty*8+4];
      *(float4*)&bb[0] = *(const float4*)&Bs[k][tx*8];
      *(float4*)&bb[4] = *(const float4*)&Bs[k][tx*8+4];
      #pragma unroll
      for (int i=0;i<8;++i)
        #pragma unroll
        for (int j=0;j<8;++j)
          acc[i][j] = fmaf(a[i], bb[j], acc[i][j]);
    }
    __syncthreads();
  }
  float bv[8];
  #pragma unroll
  for (int j=0;j<8;++j) bv[j] = bias[n0 + tx*8 + j];
  #pragma unroll
  for (int i=0;i<8;++i) {
    float* cp = C + (size_t)(m0 + ty*8 + i)*N + n0 + tx*8;
    #pragma unroll
    for (int j0=0;j0<8;j0+=4) {
      float4 o;
      o.x = acc[i][j0+0]+bv[j0+0];
      o.y = acc[i][j0+1]+bv[j0+1];
      o.z = acc[i][j0+2]+bv[j0+2];
      o.w = acc[i][j0+3]+bv[j0+3];
      if (relu) { o.x=fmaxf(o.x,0.f); o.y=fmaxf(o.y,0.f); o.z=fmaxf(o.z,0.f); o.w=fmaxf(o.w,0.f); }
      *(float4*)(cp + j0) = o;
    }
  }
}

// ---------------- attention: one block per (b,h) within chunk; K,V staged in LDS ----------------
__global__ __launch_bounds__(192) void k_attn(
    const float* __restrict__ qkv, float* __restrict__ ctx,
    const int* __restrict__ lens, int b0)
{
  __shared__ float Ks[L_*DH_];   // 49152 B
  __shared__ float Vs[L_*DH_];   // 49152 B
  const int bh = blockIdx.x;
  const int bl = bh >> 2, h = bh & 3;       // chunk-local batch index
  const int len = lens[b0 + bl];            // keys beyond len: exp underflows to 0 -> skip
  const float* base = qkv + (size_t)bl*L_*768 + (size_t)h*DH_;
  const int t = threadIdx.x;
  #pragma unroll
  for (int i=0;i<16;++i) {
    int fi = t + i*192;          // 0..3071 float4s
    int l = fi >> 4, dq = (fi & 15)*4;
    *(float4*)&Ks[l*DH_+dq] = *(const float4*)(base + (size_t)l*768 + 256 + dq);
    *(float4*)&Vs[l*DH_+dq] = *(const float4*)(base + (size_t)l*768 + 512 + dq);
  }
  __syncthreads();
  float q[DH_];
  const float* qp = base + (size_t)t*768;
  #pragma unroll
  for (int d=0; d<DH_; d+=4) {
    float4 v = *(const float4*)(qp + d);
    q[d]=v.x; q[d+1]=v.y; q[d+2]=v.z; q[d+3]=v.w;
  }
  float m = -1e30f, ssum = 0.f;
  float o[DH_];
  #pragma unroll
  for (int d=0;d<DH_;++d) o[d]=0.f;
  for (int k=0;k<len;++k) {
    const float* kr = &Ks[k*DH_];
    float s = 0.f;
    #pragma unroll
    for (int d=0;d<DH_;++d) s = fmaf(q[d], kr[d], s);
    s *= 0.125f;                 // 1/sqrt(64)
    if (s > m) {                 // online softmax rescale
      float r = __expf(m - s);
      ssum *= r;
      #pragma unroll
      for (int d=0;d<DH_;++d) o[d] *= r;
      m = s;
    }
    float e = __expf(s - m);
    ssum += e;
    const float* vr = &Vs[k*DH_];
    #pragma unroll
    for (int d=0;d<DH_;++d) o[d] = fmaf(e, vr[d], o[d]);
  }
  float inv = 1.f/ssum;
  float* op = ctx + ((size_t)bl*L_ + t)*D_ + (size_t)h*DH_;
  #pragma unroll
  for (int d=0;d<DH_;d+=4) {
    float4 v; v.x=o[d]*inv; v.y=o[d+1]*inv; v.z=o[d+2]*inv; v.w=o[d+3]*inv;
    *(float4*)(op + d) = v;
  }
}

// ---------------- residual + LayerNorm: x = LN(x + t)*s + b ; one wave per token ----------------
__global__ __launch_bounds__(256) void k_lnadd(
    float* __restrict__ x, const float* __restrict__ t,
    const float* __restrict__ s, const float* __restrict__ bb)
{
  int token = blockIdx.x*4 + (threadIdx.x >> 6);
  int lane = threadIdx.x & 63;
  float* xp = x + (size_t)token*D_;
  const float* tp = t + (size_t)token*D_;
  int d = lane*4;
  float4 xv = *(const float4*)(xp + d);
  float4 tv = *(const float4*)(tp + d);
  float y[4] = {xv.x+tv.x, xv.y+tv.y, xv.z+tv.z, xv.w+tv.w};
  float sum = y[0]+y[1]+y[2]+y[3];
  #pragma unroll
  for (int off=32; off>0; off>>=1) sum += __shfl_xor(sum, off, 64);
  float mean = sum * (1.f/256.f);
  float v0=y[0]-mean, v1=y[1]-mean, v2=y[2]-mean, v3=y[3]-mean;
  float vs = v0*v0+v1*v1+v2*v2+v3*v3;
  #pragma unroll
  for (int off=32; off>0; off>>=1) vs += __shfl_xor(vs, off, 64);
  float inv = rsqrtf(vs*(1.f/256.f) + 1e-5f);
  float4 sv = *(const float4*)(s + d);
  float4 bv = *(const float4*)(bb + d);
  float4 o;
  o.x = v0*inv*sv.x + bv.x;
  o.y = v1*inv*sv.y + bv.y;
  o.z = v2*inv*sv.z + bv.z;
  o.w = v3*inv*sv.w + bv.w;
  *(float4*)(xp + d) = o;
}

// ---------------- ragged weighted pooling + concat with id embeddings ----------------
__global__ __launch_bounds__(256) void k_pool(
    const float* __restrict__ x, const float* __restrict__ attr_tf,
    const float* __restrict__ attr_feat,
    const int* __restrict__ lens_u, const int* __restrict__ lens_i,
    const int* __restrict__ user_ids, const int* __restrict__ item_ids,
    const float* __restrict__ user_tab, const float* __restrict__ item_tab,
    const float* __restrict__ feat_w, const float* __restrict__ feat_b,
    float* __restrict__ user_out, float* __restrict__ item_out)
{
  __shared__ float wu[L_], tf[L_];
  const int b = blockIdx.x;
  const int t = threadIdx.x;
  if (t < L_) {
    const float* f = attr_feat + ((size_t)b*L_ + t)*NF_;
    float sacc = feat_b[0];
    #pragma unroll
    for (int j=0;j<NF_;++j) sacc = fmaf(f[j], feat_w[j], sacc);
    wu[t] = 1.f/(1.f+__expf(-sacc));
    tf[t] = attr_tf[b*L_+t];
  }
  __syncthreads();
  const int Lu = lens_u[b], Li = lens_i[b];
  const float* xb = x + (size_t)b*L_*D_;
  float su=0.f, si=0.f;
  for (int l=0;l<Lu+Li;++l) {               // uniform bound across block: no divergence
    float val = xb[(size_t)l*D_ + t] * tf[l];
    if (l < Lu) su = fmaf(val, wu[l], su);
    else        si = fmaf(val, 1.f-wu[l], si);
  }
  user_out[(size_t)b*512 + t]       = su/(float)Lu;
  item_out[(size_t)b*512 + t]       = si/(float)Li;
  user_out[(size_t)b*512 + 256 + t] = user_tab[(size_t)user_ids[b]*D_ + t];
  item_out[(size_t)b*512 + 256 + t] = item_tab[(size_t)item_ids[b]*D_ + t];
}

// ---------------- logits + mask + new_targets: one wave per (b,target) ----------------
__global__ __launch_bounds__(256) void k_logits(
    const int* __restrict__ pos_t, const int* __restrict__ neg_t,
    const int* __restrict__ pos_l, const int* __restrict__ neg_l,
    const float* __restrict__ oeu, const float* __restrict__ oei,
    const float* __restrict__ user_out, const float* __restrict__ item_out,
    float* __restrict__ out)
{
  const int g = blockIdx.x*4 + (threadIdx.x >> 6);
  const int lane = threadIdx.x & 63;
  const int b = g / NT_;
  const int k = g - b*NT_;
  const int tid_ = (k < LP_) ? pos_t[b*LP_ + k] : neg_t[b*LNEG_ + (k-LP_)];
  const float* eu = oeu + (size_t)tid_*512;
  const float* ei = oei + (size_t)tid_*512;
  const float* uo = user_out + (size_t)b*512;
  const float* io = item_out + (size_t)b*512;
  const int d0 = lane*8;
  float s = 0.f;
  float4 a0 = *(const float4*)(eu+d0), a1 = *(const float4*)(eu+d0+4);
  float4 u0 = *(const float4*)(uo+d0), u1 = *(const float4*)(uo+d0+4);
  s += a0.x*u0.x + a0.y*u0.y + a0.z*u0.z + a0.w*u0.w;
  s += a1.x*u1.x + a1.y*u1.y + a1.z*u1.z + a1.w*u1.w;
  float4 c0 = *(const float4*)(ei+d0), c1 = *(const float4*)(ei+d0+4);
  float4 i0 = *(const float4*)(io+d0), i1 = *(const float4*)(io+d0+4);
  s += c0.x*i0.x + c0.y*i0.y + c0.z*i0.z + c0.w*i0.w;
  s += c1.x*i1.x + c1.y*i1.y + c1.z*i1.z + c1.w*i1.w;
  #pragma unroll
  for (int off=32; off>0; off>>=1) s += __shfl_xor(s, off, 64);
  if (lane == 0) {
    out[(size_t)b*NT_ + k] = s;
    float mv, nt;
    if (k < LP_) { mv = (k < pos_l[b]) ? 1.f : 0.f; nt = mv; }
    else         { mv = ((k - LP_) < neg_l[b]) ? 1.f : 0.f; nt = 0.f; }
    out[(size_t)B_*NT_   + (size_t)b*NT_ + k] = mv;   // mask
    out[(size_t)2*B_*NT_ + (size_t)b*NT_ + k] = nt;   // new_targets
  }
}

extern "C" void kernel_launch(void* const* d_in, const int* in_sizes, int n_in,
                              void* d_out, int out_size, void* d_ws, size_t ws_size,
                              hipStream_t stream)
{
  const int*   attr      = (const int*)d_in[0];
  const int*   attr_inds = (const int*)d_in[1];
  const float* attr_tf   = (const float*)d_in[2];
  const float* attr_feat = (const float*)d_in[3];
  const int*   attr_lens = (const int*)d_in[4];
  const int*   lens_u    = (const int*)d_in[5];
  const int*   lens_i    = (const int*)d_in[6];
  const int*   user_ids  = (const int*)d_in[7];
  const int*   item_ids  = (const int*)d_in[8];
  const int*   pos_t     = (const int*)d_in[9];
  const int*   pos_l     = (const int*)d_in[10];
  const int*   neg_t     = (const int*)d_in[11];
  const int*   neg_l     = (const int*)d_in[12];
  const float* attr_emb  = (const float*)d_in[13];
  const float* ind_emb   = (const float*)d_in[14];
  const float* user_tab  = (const float*)d_in[15];
  const float* item_tab  = (const float*)d_in[16];
  const float* oeu       = (const float*)d_in[17];
  const float* oei       = (const float*)d_in[18];
  const float* feat_w    = (const float*)d_in[19];
  const float* feat_b    = (const float*)d_in[20];
  const float* Wqkv      = (const float*)d_in[21];
  const float* bqkv      = (const float*)d_in[22];
  const float* Wo        = (const float*)d_in[23];
  const float* bo        = (const float*)d_in[24];
  const float* ln1s      = (const float*)d_in[25];
  const float* ln1b      = (const float*)d_in[26];
  const float* W1        = (const float*)d_in[27];
  const float* b1        = (const float*)d_in[28];
  const float* W2        = (const float*)d_in[29];
  const float* b2        = (const float*)d_in[30];
  const float* ln2s      = (const float*)d_in[31];
  const float* ln2b      = (const float*)d_in[32];

  // ---- adaptive workspace layout (floats): uo[B,512] | io[B,512] | x[M,256] | scratch ----
  // scratch per chunk (Bc batch rows, Mc = Bc*192 tokens):
  //   attention phase: qkv_c[Mc,768] + ctx_c[Mc,256] + t_c[Mc,256]  = Mc*1280
  //   FF phase:        h_c[Mc,1024] (aliases qkv_c+ctx_c) + t2_c[Mc,256] (aliases t_c)
  float* ws = (float*)d_ws;
  float* uo = ws;
  float* io = uo + (size_t)B_*512;
  float* x  = io + (size_t)B_*512;
  float* scratch = x + (size_t)M_*D_;
  const size_t fixed_floats = (size_t)B_*1024 + (size_t)M_*D_;

  int Bc = 8;
  for (int cand = 512; cand >= 8; cand >>= 1) {
    size_t need = (fixed_floats + (size_t)cand*L_*1280) * sizeof(float);
    if (need <= ws_size) { Bc = cand; break; }
  }
  const int nchunks = B_ / Bc;
  const size_t Mc = (size_t)Bc * L_;

  float* out = (float*)d_out;

  k_embed<<<M_*64/256, 256, 0, stream>>>(attr, attr_inds, attr_emb, ind_emb, x);
  for (int l=0; l<NL_; ++l) {
    const float* Wqkv_l = Wqkv + (size_t)l*768*D_;
    const float* bqkv_l = bqkv + (size_t)l*768;
    const float* Wo_l   = Wo   + (size_t)l*D_*D_;
    const float* bo_l   = bo   + (size_t)l*D_;
    const float* W1_l   = W1   + (size_t)l*FF_*D_;
    const float* b1_l   = b1   + (size_t)l*FF_;
    const float* W2_l   = W2   + (size_t)l*D_*FF_;
    const float* b2_l   = b2   + (size_t)l*D_;
    for (int c=0; c<nchunks; ++c) {
      const size_t row0 = (size_t)c * Mc;
      float* xc    = x + row0*D_;
      float* qkv_c = scratch;
      float* ctx_c = scratch + Mc*768;
      float* t_c   = scratch + Mc*1024;
      // qkv = x @ Wqkv^T + bqkv   [Mc,768]
      k_gemm<<<dim3(768/BN, Mc/BM), 256, 0, stream>>>(xc, Wqkv_l, bqkv_l, qkv_c, (int)Mc, 768, D_, 0);
      // ctx = attention(qkv)
      k_attn<<<Bc*H_, 192, 0, stream>>>(qkv_c, ctx_c, attr_lens, c*Bc);
      // t = ctx @ Wo^T + bo       [Mc,256]
      k_gemm<<<dim3(D_/BN, Mc/BM), 256, 0, stream>>>(ctx_c, Wo_l, bo_l, t_c, (int)Mc, D_, D_, 0);
      // x = LN(x + t)
      k_lnadd<<<Mc/4, 256, 0, stream>>>(xc, t_c, ln1s + (size_t)l*D_, ln1b + (size_t)l*D_);
      // h = relu(x @ W1^T + b1)   [Mc,1024]  (aliases qkv_c/ctx_c region)
      float* h_c  = scratch;
      float* t2_c = scratch + Mc*1024;
      k_gemm<<<dim3(FF_/BN, Mc/BM), 256, 0, stream>>>(xc, W1_l, b1_l, h_c, (int)Mc, FF_, D_, 1);
      // t2 = h @ W2^T + b2        [Mc,256]
      k_gemm<<<dim3(D_/BN, Mc/BM), 256, 0, stream>>>(h_c, W2_l, b2_l, t2_c, (int)Mc, D_, FF_, 0);
      // x = LN(x + t2)
      k_lnadd<<<Mc/4, 256, 0, stream>>>(xc, t2_c, ln2s + (size_t)l*D_, ln2b + (size_t)l*D_);
    }
  }
  k_pool<<<B_, 256, 0, stream>>>(x, attr_tf, attr_feat, lens_u, lens_i, user_ids, item_ids,
                                 user_tab, item_tab, feat_w, feat_b, uo, io);
  k_logits<<<B_*NT_/4, 256, 0, stream>>>(pos_t, neg_t, pos_l, neg_l, oeu, oei, uo, io, out);
}

// Round 3
// 2099.697 us; speedup vs baseline: 2.5165x; 2.5165x over previous
//
#include <hip/hip_runtime.h>
#include <hip/hip_bf16.h>
#include <cstdint>
#include <cstddef>

#define B_ 512
#define L_ 192
#define D_ 256
#define H_ 4
#define DH_ 64
#define FF_ 1024
#define NL_ 2
#define LP_ 30
#define LNEG_ 300
#define NF_ 13
#define M_ (B_*L_)   // 98304 tokens
#define NT_ 330      // LP_+LNEG_

typedef __attribute__((ext_vector_type(8))) short bf16x8;
typedef __attribute__((ext_vector_type(4))) float f32x4;

// RNE float -> bf16 bits (finite inputs only)
__device__ __forceinline__ ushort f2b(float f) {
  union { float f; uint32_t u; } v; v.f = f;
  uint32_t u = v.u;
  return (ushort)((u + 0x7FFFu + ((u >> 16) & 1u)) >> 16);
}

// ---------------- fp32 -> bf16 weight conversion (8 elems/thread, exact grids) ----------------
__global__ __launch_bounds__(256) void k_f2b(const float* __restrict__ in, ushort* __restrict__ out) {
  const int i = (blockIdx.x*256 + threadIdx.x)*8;
  float4 a = *(const float4*)(in+i);
  float4 b = *(const float4*)(in+i+4);
  ushort4 o1; o1.x=f2b(a.x); o1.y=f2b(a.y); o1.z=f2b(a.z); o1.w=f2b(a.w);
  ushort4 o2; o2.x=f2b(b.x); o2.y=f2b(b.y); o2.z=f2b(b.z); o2.w=f2b(b.w);
  *(ushort4*)(out+i)   = o1;
  *(ushort4*)(out+i+4) = o2;
}

// ---------------- embedding gather: x = attr_emb[attr] + ind_emb[attr_inds]; also bf16 copy ----------------
__global__ __launch_bounds__(256) void k_embed(
    const int* __restrict__ attr, const int* __restrict__ inds,
    const float* __restrict__ attr_emb, const float* __restrict__ ind_emb,
    float* __restrict__ x, ushort* __restrict__ xb)
{
  int idx = blockIdx.x*256 + threadIdx.x;     // over M_*64 float4s
  int token = idx >> 6;
  int c = (idx & 63) * 4;
  int a = attr[token];
  int id = inds[token];
  const float4 e  = *(const float4*)(attr_emb + (size_t)a*D_ + c);
  const float4 ie = *(const float4*)(ind_emb  + (size_t)id*D_ + c);
  float4 o; o.x=e.x+ie.x; o.y=e.y+ie.y; o.z=e.z+ie.z; o.w=e.w+ie.w;
  *(float4*)(x + (size_t)token*D_ + c) = o;
  ushort4 ob; ob.x=f2b(o.x); ob.y=f2b(o.y); ob.z=f2b(o.z); ob.w=f2b(o.w);
  *(ushort4*)(xb + (size_t)token*D_ + c) = ob;
}

// ---------------- bf16 MFMA GEMM: C[M,N] = A[M,K](bf16) @ W[N,K](bf16)^T + bias ----------------
// 128x128 tile, BK=64, 4 waves (2x2 of 64x64), mfma_f32_16x16x32_bf16,
// global_load_lds width-16 staging (m97 structure).
template<int OUT_BF16, int RELU>
__global__ __launch_bounds__(256) void k_gemm_mfma(
    const ushort* __restrict__ A, const ushort* __restrict__ W,
    const float* __restrict__ bias, void* __restrict__ Cv,
    int M, int N, int K)
{
  __shared__ alignas(16) ushort As[8192];   // [128][64] bf16, 16 KB
  __shared__ alignas(16) ushort Bs[8192];
  const int tid = threadIdx.x;
  const int w = tid >> 6, l = tid & 63;
  const int m0 = blockIdx.y*128, n0 = blockIdx.x*128;
  const int wr = w >> 1, wc = w & 1;

  f32x4 acc[4][4];
  #pragma unroll
  for (int i=0;i<4;++i)
    #pragma unroll
    for (int j=0;j<4;++j) acc[i][j] = (f32x4){0.f,0.f,0.f,0.f};

  for (int k0=0; k0<K; k0+=64) {
    #pragma unroll
    for (int i=0;i<4;++i) {
      const int li  = i*4096 + tid*16;        // byte offset in 16 KB tile
      const int row = li >> 7;                // 128 B per row
      const int col = (li & 127) >> 1;        // bf16 element in row
      const ushort* ga = A + (size_t)(m0+row)*K + k0 + col;
      const ushort* gb = W + (size_t)(n0+row)*K + k0 + col;
      ushort* la = As + i*2048 + w*512;       // wave-uniform dest base; HW adds lane*16 B
      ushort* lb = Bs + i*2048 + w*512;
      __builtin_amdgcn_global_load_lds((const __attribute__((address_space(1))) unsigned int*)ga,
                                       (__attribute__((address_space(3))) unsigned int*)la, 16, 0, 0);
      __builtin_amdgcn_global_load_lds((const __attribute__((address_space(1))) unsigned int*)gb,
                                       (__attribute__((address_space(3))) unsigned int*)lb, 16, 0, 0);
    }
    __syncthreads();
    #pragma unroll
    for (int ks=0; ks<2; ++ks) {
      bf16x8 af[4], bfr[4];
      #pragma unroll
      for (int i2=0;i2<4;++i2) {
        af[i2]  = *(const bf16x8*)(As + (size_t)(wr*64 + i2*16 + (l&15))*64 + (l>>4)*8 + ks*32);
        bfr[i2] = *(const bf16x8*)(Bs + (size_t)(wc*64 + i2*16 + (l&15))*64 + (l>>4)*8 + ks*32);
      }
      #pragma unroll
      for (int mi=0;mi<4;++mi)
        #pragma unroll
        for (int ni=0;ni<4;++ni)
          acc[mi][ni] = __builtin_amdgcn_mfma_f32_16x16x32_bf16(af[mi], bfr[ni], acc[mi][ni], 0,0,0);
    }
    __syncthreads();
  }
  const int col0 = n0 + wc*64 + (l&15);
  const int row0 = m0 + wr*64 + ((l>>4)<<2);
  #pragma unroll
  for (int ni=0;ni<4;++ni) {
    const float bv = bias[col0 + ni*16];
    #pragma unroll
    for (int mi=0;mi<4;++mi) {
      #pragma unroll
      for (int r=0;r<4;++r) {
        float v = acc[mi][ni][r] + bv;
        if (RELU) v = fmaxf(v, 0.f);
        const size_t idx = (size_t)(row0 + mi*16 + r)*N + col0 + ni*16;
        if (OUT_BF16) ((ushort*)Cv)[idx] = f2b(v);
        else          ((float*)Cv)[idx]  = v;
      }
    }
  }
}

// ---------------- attention: block per (b,h), K/V streamed in 96-key fp32 LDS tiles ----------------
__global__ __launch_bounds__(192) void k_attn(
    const float* __restrict__ qkv, ushort* __restrict__ ctx,
    const int* __restrict__ lens, int b0)
{
  __shared__ alignas(16) float Ks[96][64];   // 24 KB
  __shared__ alignas(16) float Vs[96][64];   // 24 KB
  const int bl = blockIdx.x >> 2, h = blockIdx.x & 3;
  const int len = lens[b0 + bl];
  const float* base = qkv + (size_t)bl*L_*768 + h*64;
  const int t = threadIdx.x;
  float q[64];
  const float* qp = base + (size_t)t*768;
  #pragma unroll
  for (int d=0; d<64; d+=4) {
    float4 v = *(const float4*)(qp+d);
    q[d]=v.x; q[d+1]=v.y; q[d+2]=v.z; q[d+3]=v.w;
  }
  float m=-1e30f, ssum=0.f, o[64];
  #pragma unroll
  for (int d=0;d<64;++d) o[d]=0.f;
  const int ntile = (len + 95)/96;
  for (int tl=0; tl<ntile; ++tl) {
    const int kb = tl*96;
    const int kn = min(96, len-kb);
    for (int i=t; i<kn*16; i+=192) {
      int r = i>>4, c = (i&15)<<2;
      const float* src = base + (size_t)(kb+r)*768;
      *(float4*)&Ks[r][c] = *(const float4*)(src + 256 + c);
      *(float4*)&Vs[r][c] = *(const float4*)(src + 512 + c);
    }
    __syncthreads();
    if (t < len) {
      for (int k=0;k<kn;++k) {
        const float* kr = Ks[k];
        float s0=0.f,s1=0.f,s2=0.f,s3=0.f;
        #pragma unroll
        for (int d=0;d<64;d+=4) {
          s0=fmaf(q[d],  kr[d],  s0); s1=fmaf(q[d+1],kr[d+1],s1);
          s2=fmaf(q[d+2],kr[d+2],s2); s3=fmaf(q[d+3],kr[d+3],s3);
        }
        float s = ((s0+s1)+(s2+s3))*0.125f;
        if (s > m) {               // rare after warm-up
          float r2 = __expf(m - s);
          ssum *= r2;
          #pragma unroll
          for (int d=0;d<64;++d) o[d]*=r2;
          m = s;
        }
        float e = __expf(s - m);
        ssum += e;
        const float* vr = Vs[k];
        #pragma unroll
        for (int d=0;d<64;++d) o[d] = fmaf(e, vr[d], o[d]);
      }
    }
    __syncthreads();
  }
  ushort* op = ctx + ((size_t)bl*L_ + t)*D_ + h*64;
  if (t < len) {
    float inv = 1.f/ssum;
    #pragma unroll
    for (int d=0;d<64;d+=4) {
      ushort4 ov; ov.x=f2b(o[d]*inv); ov.y=f2b(o[d+1]*inv);
      ov.z=f2b(o[d+2]*inv); ov.w=f2b(o[d+3]*inv);
      *(ushort4*)(op+d) = ov;
    }
  } else {                        // rows never used downstream (pool masks them); keep finite
    ushort4 z; z.x=0; z.y=0; z.z=0; z.w=0;
    #pragma unroll
    for (int d=0;d<64;d+=4) *(ushort4*)(op+d) = z;
  }
}

// ---------------- residual + LayerNorm: x = LN(x + t)*s + b (fp32) + bf16 copy ----------------
__global__ __launch_bounds__(256) void k_lnadd(
    float* __restrict__ x, ushort* __restrict__ xb, const float* __restrict__ t,
    const float* __restrict__ s, const float* __restrict__ bb)
{
  int token = blockIdx.x*4 + (threadIdx.x >> 6);
  int lane = threadIdx.x & 63;
  float* xp = x + (size_t)token*D_;
  const float* tp = t + (size_t)token*D_;
  int d = lane*4;
  float4 xv = *(const float4*)(xp + d);
  float4 tv = *(const float4*)(tp + d);
  float y[4] = {xv.x+tv.x, xv.y+tv.y, xv.z+tv.z, xv.w+tv.w};
  float sum = y[0]+y[1]+y[2]+y[3];
  #pragma unroll
  for (int off=32; off>0; off>>=1) sum += __shfl_xor(sum, off, 64);
  float mean = sum * (1.f/256.f);
  float v0=y[0]-mean, v1=y[1]-mean, v2=y[2]-mean, v3=y[3]-mean;
  float vs = v0*v0+v1*v1+v2*v2+v3*v3;
  #pragma unroll
  for (int off=32; off>0; off>>=1) vs += __shfl_xor(vs, off, 64);
  float inv = rsqrtf(vs*(1.f/256.f) + 1e-5f);
  float4 sv = *(const float4*)(s + d);
  float4 bv = *(const float4*)(bb + d);
  float4 o;
  o.x = v0*inv*sv.x + bv.x;
  o.y = v1*inv*sv.y + bv.y;
  o.z = v2*inv*sv.z + bv.z;
  o.w = v3*inv*sv.w + bv.w;
  *(float4*)(xp + d) = o;
  ushort4 ob; ob.x=f2b(o.x); ob.y=f2b(o.y); ob.z=f2b(o.z); ob.w=f2b(o.w);
  *(ushort4*)(xb + (size_t)token*D_ + d) = ob;
}

// ---------------- ragged weighted pooling + concat with id embeddings ----------------
__global__ __launch_bounds__(256) void k_pool(
    const float* __restrict__ x, const float* __restrict__ attr_tf,
    const float* __restrict__ attr_feat,
    const int* __restrict__ lens_u, const int* __restrict__ lens_i,
    const int* __restrict__ user_ids, const int* __restrict__ item_ids,
    const float* __restrict__ user_tab, const float* __restrict__ item_tab,
    const float* __restrict__ feat_w, const float* __restrict__ feat_b,
    float* __restrict__ user_out, float* __restrict__ item_out)
{
  __shared__ float wu[L_], tf[L_];
  const int b = blockIdx.x;
  const int t = threadIdx.x;
  if (t < L_) {
    const float* f = attr_feat + ((size_t)b*L_ + t)*NF_;
    float sacc = feat_b[0];
    #pragma unroll
    for (int j=0;j<NF_;++j) sacc = fmaf(f[j], feat_w[j], sacc);
    wu[t] = 1.f/(1.f+__expf(-sacc));
    tf[t] = attr_tf[b*L_+t];
  }
  __syncthreads();
  const int Lu = lens_u[b], Li = lens_i[b];
  const float* xb = x + (size_t)b*L_*D_;
  float su=0.f, si=0.f;
  for (int l=0;l<Lu+Li;++l) {
    float val = xb[(size_t)l*D_ + t] * tf[l];
    if (l < Lu) su = fmaf(val, wu[l], su);
    else        si = fmaf(val, 1.f-wu[l], si);
  }
  user_out[(size_t)b*512 + t]       = su/(float)Lu;
  item_out[(size_t)b*512 + t]       = si/(float)Li;
  user_out[(size_t)b*512 + 256 + t] = user_tab[(size_t)user_ids[b]*D_ + t];
  item_out[(size_t)b*512 + 256 + t] = item_tab[(size_t)item_ids[b]*D_ + t];
}

// ---------------- logits + mask + new_targets: one wave per (b,target) ----------------
__global__ __launch_bounds__(256) void k_logits(
    const int* __restrict__ pos_t, const int* __restrict__ neg_t,
    const int* __restrict__ pos_l, const int* __restrict__ neg_l,
    const float* __restrict__ oeu, const float* __restrict__ oei,
    const float* __restrict__ user_out, const float* __restrict__ item_out,
    float* __restrict__ out)
{
  const int g = blockIdx.x*4 + (threadIdx.x >> 6);
  const int lane = threadIdx.x & 63;
  const int b = g / NT_;
  const int k = g - b*NT_;
  const int tid_ = (k < LP_) ? pos_t[b*LP_ + k] : neg_t[b*LNEG_ + (k-LP_)];
  const float* eu = oeu + (size_t)tid_*512;
  const float* ei = oei + (size_t)tid_*512;
  const float* uo = user_out + (size_t)b*512;
  const float* io = item_out + (size_t)b*512;
  const int d0 = lane*8;
  float s = 0.f;
  float4 a0 = *(const float4*)(eu+d0), a1 = *(const float4*)(eu+d0+4);
  float4 u0 = *(const float4*)(uo+d0), u1 = *(const float4*)(uo+d0+4);
  s += a0.x*u0.x + a0.y*u0.y + a0.z*u0.z + a0.w*u0.w;
  s += a1.x*u1.x + a1.y*u1.y + a1.z*u1.z + a1.w*u1.w;
  float4 c0 = *(const float4*)(ei+d0), c1 = *(const float4*)(ei+d0+4);
  float4 i0 = *(const float4*)(io+d0), i1 = *(const float4*)(io+d0+4);
  s += c0.x*i0.x + c0.y*i0.y + c0.z*i0.z + c0.w*i0.w;
  s += c1.x*i1.x + c1.y*i1.y + c1.z*i1.z + c1.w*i1.w;
  #pragma unroll
  for (int off=32; off>0; off>>=1) s += __shfl_xor(s, off, 64);
  if (lane == 0) {
    out[(size_t)b*NT_ + k] = s;
    float mv, nt;
    if (k < LP_) { mv = (k < pos_l[b]) ? 1.f : 0.f; nt = mv; }
    else         { mv = ((k - LP_) < neg_l[b]) ? 1.f : 0.f; nt = 0.f; }
    out[(size_t)B_*NT_   + (size_t)b*NT_ + k] = mv;   // mask
    out[(size_t)2*B_*NT_ + (size_t)b*NT_ + k] = nt;   // new_targets
  }
}

extern "C" void kernel_launch(void* const* d_in, const int* in_sizes, int n_in,
                              void* d_out, int out_size, void* d_ws, size_t ws_size,
                              hipStream_t stream)
{
  const int*   attr      = (const int*)d_in[0];
  const int*   attr_inds = (const int*)d_in[1];
  const float* attr_tf   = (const float*)d_in[2];
  const float* attr_feat = (const float*)d_in[3];
  const int*   attr_lens = (const int*)d_in[4];
  const int*   lens_u    = (const int*)d_in[5];
  const int*   lens_i    = (const int*)d_in[6];
  const int*   user_ids  = (const int*)d_in[7];
  const int*   item_ids  = (const int*)d_in[8];
  const int*   pos_t     = (const int*)d_in[9];
  const int*   pos_l     = (const int*)d_in[10];
  const int*   neg_t     = (const int*)d_in[11];
  const int*   neg_l     = (const int*)d_in[12];
  const float* attr_emb  = (const float*)d_in[13];
  const float* ind_emb   = (const float*)d_in[14];
  const float* user_tab  = (const float*)d_in[15];
  const float* item_tab  = (const float*)d_in[16];
  const float* oeu       = (const float*)d_in[17];
  const float* oei       = (const float*)d_in[18];
  const float* feat_w    = (const float*)d_in[19];
  const float* feat_b    = (const float*)d_in[20];
  const float* Wqkv      = (const float*)d_in[21];
  const float* bqkv      = (const float*)d_in[22];
  const float* Wo        = (const float*)d_in[23];
  const float* bo        = (const float*)d_in[24];
  const float* ln1s      = (const float*)d_in[25];
  const float* ln1b      = (const float*)d_in[26];
  const float* W1        = (const float*)d_in[27];
  const float* b1        = (const float*)d_in[28];
  const float* W2        = (const float*)d_in[29];
  const float* b2        = (const float*)d_in[30];
  const float* ln2s      = (const float*)d_in[31];
  const float* ln2b      = (const float*)d_in[32];

  // ---- workspace layout ----
  // uo[B,512]f32 | io[B,512]f32 | x[M,256]f32 | xb[M,256]bf16 | weights bf16 (1572864) | scratch
  float* ws = (float*)d_ws;
  float* uo = ws;
  float* io = uo + (size_t)B_*512;
  float* x  = io + (size_t)B_*512;
  ushort* xb   = (ushort*)(x + (size_t)M_*D_);
  ushort* wq_b = xb + (size_t)M_*D_;
  ushort* wo_b = wq_b + (size_t)2*768*256;
  ushort* w1_b = wo_b + (size_t)2*256*256;
  ushort* w2_b = w1_b + (size_t)2*1024*256;
  float* scratch = (float*)(w2_b + (size_t)2*256*1024);

  const size_t fixed_floats = (size_t)B_*1024 + (size_t)M_*D_ + (size_t)M_*(D_/2) + 786432;
  int Bc = 8;
  for (int cand = 256; cand >= 8; cand >>= 1) {
    size_t need = (fixed_floats + (size_t)cand*L_*1152) * sizeof(float);
    if (need <= ws_size) { Bc = cand; break; }
  }
  const int nchunks = B_ / Bc;
  const size_t Mc = (size_t)Bc * L_;   // multiple of 128 for all even Bc >= 8? Bc*192: Bc=8 -> 1536 = 12*128 OK

  float* out = (float*)d_out;

  // weight conversions (exact grids; counts all divisible by 2048)
  k_f2b<<<(2*768*256)/2048,  256, 0, stream>>>(Wqkv, wq_b);
  k_f2b<<<(2*256*256)/2048,  256, 0, stream>>>(Wo,   wo_b);
  k_f2b<<<(2*1024*256)/2048, 256, 0, stream>>>(W1,   w1_b);
  k_f2b<<<(2*256*1024)/2048, 256, 0, stream>>>(W2,   w2_b);

  k_embed<<<M_*64/256, 256, 0, stream>>>(attr, attr_inds, attr_emb, ind_emb, x, xb);

  for (int l=0; l<NL_; ++l) {
    const float* bqkv_l = bqkv + (size_t)l*768;
    const float* bo_l   = bo   + (size_t)l*D_;
    const float* b1_l   = b1   + (size_t)l*FF_;
    const float* b2_l   = b2   + (size_t)l*D_;
    for (int c=0; c<nchunks; ++c) {
      const size_t row0 = (size_t)c * Mc;
      float*  xc    = x  + row0*D_;
      ushort* xb_c  = xb + row0*D_;
      float*  qkv_c = scratch;                          // [Mc,768] f32
      ushort* ctx_b = (ushort*)(scratch + Mc*768);      // [Mc,256] bf16
      float*  t_c   = scratch + Mc*768 + Mc*128;        // [Mc,256] f32
      ushort* h_b   = (ushort*)scratch;                 // [Mc,1024] bf16 (aliases qkv region, FF phase)
      float*  t2_c  = scratch + Mc*512;                 // [Mc,256] f32 (FF phase)

      k_gemm_mfma<0,0><<<dim3(768/128, Mc/128), 256, 0, stream>>>(
          xb_c, wq_b + (size_t)l*768*256, bqkv_l, qkv_c, (int)Mc, 768, 256);
      k_attn<<<Bc*H_, 192, 0, stream>>>(qkv_c, ctx_b, attr_lens, c*Bc);
      k_gemm_mfma<0,0><<<dim3(256/128, Mc/128), 256, 0, stream>>>(
          ctx_b, wo_b + (size_t)l*256*256, bo_l, t_c, (int)Mc, 256, 256);
      k_lnadd<<<Mc/4, 256, 0, stream>>>(xc, xb_c, t_c, ln1s + (size_t)l*D_, ln1b + (size_t)l*D_);
      k_gemm_mfma<1,1><<<dim3(1024/128, Mc/128), 256, 0, stream>>>(
          xb_c, w1_b + (size_t)l*1024*256, b1_l, h_b, (int)Mc, 1024, 256);
      k_gemm_mfma<0,0><<<dim3(256/128, Mc/128), 256, 0, stream>>>(
          h_b, w2_b + (size_t)l*256*1024, b2_l, t2_c, (int)Mc, 256, 1024);
      k_lnadd<<<Mc/4, 256, 0, stream>>>(xc, xb_c, t2_c, ln2s + (size_t)l*D_, ln2b + (size_t)l*D_);
    }
  }
  k_pool<<<B_, 256, 0, stream>>>(x, attr_tf, attr_feat, lens_u, lens_i, user_ids, item_ids,
                                 user_tab, item_tab, feat_w, feat_b, uo, io);
  k_logits<<<B_*NT_/4, 256, 0, stream>>>(pos_t, neg_t, pos_l, neg_l, oeu, oei, uo, io, out);
}

// Round 4
// 1348.845 us; speedup vs baseline: 3.9174x; 1.5567x over previous
//
#include <hip/hip_runtime.h>
#include <hip/hip_bf16.h>
#include <cstdint>
#include <cstddef>

#define B_ 512
#define L_ 192
#define D_ 256
#define H_ 4
#define DH_ 64
#define FF_ 1024
#define NL_ 2
#define LP_ 30
#define LNEG_ 300
#define NF_ 13
#define M_ (B_*L_)   // 98304 tokens
#define NT_ 330      // LP_+LNEG_

typedef __attribute__((ext_vector_type(8))) short bf16x8;
typedef __attribute__((ext_vector_type(4))) float f32x4;

// RNE float -> bf16 bits (finite inputs only)
__device__ __forceinline__ ushort f2b(float f) {
  union { float f; uint32_t u; } v; v.f = f;
  uint32_t u = v.u;
  return (ushort)((u + 0x7FFFu + ((u >> 16) & 1u)) >> 16);
}

// ---------------- fp32 -> bf16 weight conversion ----------------
__global__ __launch_bounds__(256) void k_f2b(const float* __restrict__ in, ushort* __restrict__ out) {
  const int i = (blockIdx.x*256 + threadIdx.x)*8;
  float4 a = *(const float4*)(in+i);
  float4 b = *(const float4*)(in+i+4);
  ushort4 o1; o1.x=f2b(a.x); o1.y=f2b(a.y); o1.z=f2b(a.z); o1.w=f2b(a.w);
  ushort4 o2; o2.x=f2b(b.x); o2.y=f2b(b.y); o2.z=f2b(b.z); o2.w=f2b(b.w);
  *(ushort4*)(out+i)   = o1;
  *(ushort4*)(out+i+4) = o2;
}

// ---------------- embedding gather + bf16 copy ----------------
__global__ __launch_bounds__(256) void k_embed(
    const int* __restrict__ attr, const int* __restrict__ inds,
    const float* __restrict__ attr_emb, const float* __restrict__ ind_emb,
    float* __restrict__ x, ushort* __restrict__ xb)
{
  int idx = blockIdx.x*256 + threadIdx.x;
  int token = idx >> 6;
  int c = (idx & 63) * 4;
  int a = attr[token];
  int id = inds[token];
  const float4 e  = *(const float4*)(attr_emb + (size_t)a*D_ + c);
  const float4 ie = *(const float4*)(ind_emb  + (size_t)id*D_ + c);
  float4 o; o.x=e.x+ie.x; o.y=e.y+ie.y; o.z=e.z+ie.z; o.w=e.w+ie.w;
  *(float4*)(x + (size_t)token*D_ + c) = o;
  ushort4 ob; ob.x=f2b(o.x); ob.y=f2b(o.y); ob.z=f2b(o.z); ob.w=f2b(o.w);
  *(ushort4*)(xb + (size_t)token*D_ + c) = ob;
}

// ---------------- bf16 MFMA GEMM: C[M,N] = A[M,K] @ W[N,K]^T + bias ----------------
template<int OUT_BF16, int RELU>
__global__ __launch_bounds__(256) void k_gemm_mfma(
    const ushort* __restrict__ A, const ushort* __restrict__ W,
    const float* __restrict__ bias, void* __restrict__ Cv,
    int M, int N, int K)
{
  __shared__ alignas(16) ushort As[8192];   // [128][64] bf16
  __shared__ alignas(16) ushort Bs[8192];
  const int tid = threadIdx.x;
  const int w = tid >> 6, l = tid & 63;
  const int m0 = blockIdx.y*128, n0 = blockIdx.x*128;
  const int wr = w >> 1, wc = w & 1;

  f32x4 acc[4][4];
  #pragma unroll
  for (int i=0;i<4;++i)
    #pragma unroll
    for (int j=0;j<4;++j) acc[i][j] = (f32x4){0.f,0.f,0.f,0.f};

  for (int k0=0; k0<K; k0+=64) {
    #pragma unroll
    for (int i=0;i<4;++i) {
      const int li  = i*4096 + tid*16;
      const int row = li >> 7;
      const int col = (li & 127) >> 1;
      const ushort* ga = A + (size_t)(m0+row)*K + k0 + col;
      const ushort* gb = W + (size_t)(n0+row)*K + k0 + col;
      ushort* la = As + i*2048 + w*512;
      ushort* lb = Bs + i*2048 + w*512;
      __builtin_amdgcn_global_load_lds((const __attribute__((address_space(1))) unsigned int*)ga,
                                       (__attribute__((address_space(3))) unsigned int*)la, 16, 0, 0);
      __builtin_amdgcn_global_load_lds((const __attribute__((address_space(1))) unsigned int*)gb,
                                       (__attribute__((address_space(3))) unsigned int*)lb, 16, 0, 0);
    }
    __syncthreads();
    #pragma unroll
    for (int ks=0; ks<2; ++ks) {
      bf16x8 af[4], bfr[4];
      #pragma unroll
      for (int i2=0;i2<4;++i2) {
        af[i2]  = *(const bf16x8*)(As + (size_t)(wr*64 + i2*16 + (l&15))*64 + (l>>4)*8 + ks*32);
        bfr[i2] = *(const bf16x8*)(Bs + (size_t)(wc*64 + i2*16 + (l&15))*64 + (l>>4)*8 + ks*32);
      }
      #pragma unroll
      for (int mi=0;mi<4;++mi)
        #pragma unroll
        for (int ni=0;ni<4;++ni)
          acc[mi][ni] = __builtin_amdgcn_mfma_f32_16x16x32_bf16(af[mi], bfr[ni], acc[mi][ni], 0,0,0);
    }
    __syncthreads();
  }
  const int col0 = n0 + wc*64 + (l&15);
  const int row0 = m0 + wr*64 + ((l>>4)<<2);
  #pragma unroll
  for (int ni=0;ni<4;++ni) {
    const float bv = bias[col0 + ni*16];
    #pragma unroll
    for (int mi=0;mi<4;++mi) {
      #pragma unroll
      for (int r=0;r<4;++r) {
        float v = acc[mi][ni][r] + bv;
        if (RELU) v = fmaxf(v, 0.f);
        const size_t idx = (size_t)(row0 + mi*16 + r)*N + col0 + ni*16;
        if (OUT_BF16) ((ushort*)Cv)[idx] = f2b(v);
        else          ((float*)Cv)[idx]  = v;
      }
    }
  }
}

// ---------------- MFMA flash attention: block per (b,h), 4 waves x 16-query strips ----------------
// LDS (80 KB, 2 blocks/CU):
//   Kb [192 rows][128 B] bf16, swz byte^=(row&7)<<4            (24 KB)
//   Vt [64 rows][512 B]  bf16 (V transposed), swz ^=(d&7)<<4   (32 KB)
//   Pw per wave: [6 chunks][16 q][64 B], swz ^=((q>>2)&3)<<4   (4x6 KB)
__global__ __launch_bounds__(256) void k_attn_mfma(
    const ushort* __restrict__ qkv, ushort* __restrict__ ctx,
    const int* __restrict__ lens, int b0)
{
  __shared__ alignas(16) char lds[81920];
  char* Kb = lds;
  char* Vt = lds + 24576;
  const int tid = threadIdx.x;
  const int w = tid >> 6, l = tid & 63;
  const int g = l >> 4, c = l & 15;
  char* Pw = lds + 57344 + w*6144;
  const int bl = blockIdx.x >> 2, h = blockIdx.x & 3;
  const int len = lens[b0 + bl];
  const int nkt = (len + 15) >> 4;   // 16-key score tiles
  const int nkf = (len + 31) >> 5;   // 32-key PV chunks
  const ushort* base = qkv + (size_t)bl*L_*768;

  // stage K (row-major, swizzled)
  for (int idx = tid; idx < 1536; idx += 256) {
    int row = idx >> 3, ch = idx & 7;
    uint4 v = *(const uint4*)(base + (size_t)row*768 + 256 + h*64 + ch*8);
    *(uint4*)(Kb + ((row*128 + ch*16) ^ ((row&7)<<4))) = v;
  }
  // stage V transposed (coalesced global reads, scattered LDS u16 writes)
  {
    int d0 = (tid & 15)*4;
    for (int key = tid >> 4; key < 192; key += 16) {
      ushort4 v = *(const ushort4*)(base + (size_t)key*768 + 512 + h*64 + d0);
      ushort vv[4] = {v.x, v.y, v.z, v.w};
      #pragma unroll
      for (int j=0;j<4;++j) {
        int d = d0 + j;
        *(ushort*)(Vt + ((d*512 + key*2) ^ ((d&7)<<4))) = vv[j];
      }
    }
  }
  __syncthreads();

  // zero P tail keys [nkt*16, nkf*32) once (persists across strips)
  for (int t = nkt; t < 2*nkf; ++t) {
    #pragma unroll
    for (int r=0;r<4;++r) {
      int q = 4*g + r;
      *(ushort*)(Pw + (((t>>1)*1024 + q*64 + ((t&1)*16 + c)*2) ^ (((q>>2)&3)<<4))) = 0;
    }
  }

  for (int s = w; s < 12; s += 4) {
    ushort* orow = ctx + ((size_t)bl*L_ + s*16)*256 + h*64;
    if (s*16 >= len) {          // rows never used downstream; keep finite
      #pragma unroll
      for (int dt=0;dt<4;++dt)
        #pragma unroll
        for (int r=0;r<4;++r)
          orow[(size_t)(4*g+r)*256 + dt*16 + c] = 0;
      continue;
    }
    // Q fragments from global (A-frag: row = l&15, k = g*8+j)
    const ushort* qp = base + (size_t)(s*16 + c)*768 + h*64 + g*8;
    bf16x8 aq0 = *(const bf16x8*)qp;
    bf16x8 aq1 = *(const bf16x8*)(qp + 32);

    // QK^T: D[q=4g+r][key=16t+c]
    f32x4 sc[12];
    #pragma unroll
    for (int t=0;t<12;++t) {
      sc[t] = (f32x4){0.f,0.f,0.f,0.f};
      if (t < nkt) {
        int ba0 = ((t*16 + c)*128 + g*16)      ^ ((c&7)<<4);
        int ba1 = ((t*16 + c)*128 + g*16 + 64) ^ ((c&7)<<4);
        bf16x8 k0 = *(const bf16x8*)(Kb + ba0);
        bf16x8 k1 = *(const bf16x8*)(Kb + ba1);
        sc[t] = __builtin_amdgcn_mfma_f32_16x16x32_bf16(aq0, k0, sc[t], 0,0,0);
        sc[t] = __builtin_amdgcn_mfma_f32_16x16x32_bf16(aq1, k1, sc[t], 0,0,0);
        if (t == nkt-1 && t*16 + c >= len)
          sc[t] = (f32x4){-1e30f,-1e30f,-1e30f,-1e30f};
      }
    }
    // row max over keys: in-register tiles + shuffle over the 16 key-lanes
    float mr[4] = {-1e30f,-1e30f,-1e30f,-1e30f};
    #pragma unroll
    for (int t=0;t<12;++t) if (t<nkt) {
      #pragma unroll
      for (int r=0;r<4;++r) mr[r] = fmaxf(mr[r], sc[t][r]);
    }
    #pragma unroll
    for (int r=0;r<4;++r) {
      mr[r] = fmaxf(mr[r], __shfl_xor(mr[r], 1, 16));
      mr[r] = fmaxf(mr[r], __shfl_xor(mr[r], 2, 16));
      mr[r] = fmaxf(mr[r], __shfl_xor(mr[r], 4, 16));
      mr[r] = fmaxf(mr[r], __shfl_xor(mr[r], 8, 16));
    }
    // p = exp((s-m)/8), row sums, store P (bf16) to per-wave LDS
    float sr[4] = {0.f,0.f,0.f,0.f};
    #pragma unroll
    for (int t=0;t<12;++t) if (t<nkt) {
      #pragma unroll
      for (int r=0;r<4;++r) {
        float p = __expf((sc[t][r] - mr[r]) * 0.125f);
        sr[r] += p;
        int q = 4*g + r;
        *(ushort*)(Pw + (((t>>1)*1024 + q*64 + ((t&1)*16 + c)*2) ^ (((q>>2)&3)<<4))) = f2b(p);
      }
    }
    #pragma unroll
    for (int r=0;r<4;++r) {
      sr[r] += __shfl_xor(sr[r], 1, 16);
      sr[r] += __shfl_xor(sr[r], 2, 16);
      sr[r] += __shfl_xor(sr[r], 4, 16);
      sr[r] += __shfl_xor(sr[r], 8, 16);
    }
    // PV: O[q=4g+r][d=dt*16+c] += P[q][k] * V[k][d]
    f32x4 oa[4];
    #pragma unroll
    for (int dt=0;dt<4;++dt) oa[dt] = (f32x4){0.f,0.f,0.f,0.f};
    #pragma unroll
    for (int kf=0;kf<6;++kf) if (kf<nkf) {
      bf16x8 pf = *(const bf16x8*)(Pw + ((kf*1024 + c*64 + g*16) ^ (((c>>2)&3)<<4)));
      #pragma unroll
      for (int dt=0;dt<4;++dt) {
        int d = dt*16 + c;
        bf16x8 vf = *(const bf16x8*)(Vt + ((d*512 + kf*64 + g*16) ^ ((d&7)<<4)));
        oa[dt] = __builtin_amdgcn_mfma_f32_16x16x32_bf16(pf, vf, oa[dt], 0,0,0);
      }
    }
    float inv[4];
    #pragma unroll
    for (int r=0;r<4;++r) inv[r] = 1.f / sr[r];
    #pragma unroll
    for (int dt=0;dt<4;++dt)
      #pragma unroll
      for (int r=0;r<4;++r)
        orow[(size_t)(4*g+r)*256 + dt*16 + c] = f2b(oa[dt][r] * inv[r]);
  }
}

// ---------------- residual + LayerNorm (fp32) + bf16 copy ----------------
__global__ __launch_bounds__(256) void k_lnadd(
    float* __restrict__ x, ushort* __restrict__ xb, const float* __restrict__ t,
    const float* __restrict__ s, const float* __restrict__ bb)
{
  int token = blockIdx.x*4 + (threadIdx.x >> 6);
  int lane = threadIdx.x & 63;
  float* xp = x + (size_t)token*D_;
  const float* tp = t + (size_t)token*D_;
  int d = lane*4;
  float4 xv = *(const float4*)(xp + d);
  float4 tv = *(const float4*)(tp + d);
  float y[4] = {xv.x+tv.x, xv.y+tv.y, xv.z+tv.z, xv.w+tv.w};
  float sum = y[0]+y[1]+y[2]+y[3];
  #pragma unroll
  for (int off=32; off>0; off>>=1) sum += __shfl_xor(sum, off, 64);
  float mean = sum * (1.f/256.f);
  float v0=y[0]-mean, v1=y[1]-mean, v2=y[2]-mean, v3=y[3]-mean;
  float vs = v0*v0+v1*v1+v2*v2+v3*v3;
  #pragma unroll
  for (int off=32; off>0; off>>=1) vs += __shfl_xor(vs, off, 64);
  float inv = rsqrtf(vs*(1.f/256.f) + 1e-5f);
  float4 sv = *(const float4*)(s + d);
  float4 bv = *(const float4*)(bb + d);
  float4 o;
  o.x = v0*inv*sv.x + bv.x;
  o.y = v1*inv*sv.y + bv.y;
  o.z = v2*inv*sv.z + bv.z;
  o.w = v3*inv*sv.w + bv.w;
  *(float4*)(xp + d) = o;
  ushort4 ob; ob.x=f2b(o.x); ob.y=f2b(o.y); ob.z=f2b(o.z); ob.w=f2b(o.w);
  *(ushort4*)(xb + (size_t)token*D_ + d) = ob;
}

// ---------------- ragged weighted pooling + concat with id embeddings ----------------
__global__ __launch_bounds__(256) void k_pool(
    const float* __restrict__ x, const float* __restrict__ attr_tf,
    const float* __restrict__ attr_feat,
    const int* __restrict__ lens_u, const int* __restrict__ lens_i,
    const int* __restrict__ user_ids, const int* __restrict__ item_ids,
    const float* __restrict__ user_tab, const float* __restrict__ item_tab,
    const float* __restrict__ feat_w, const float* __restrict__ feat_b,
    float* __restrict__ user_out, float* __restrict__ item_out)
{
  __shared__ float wu[L_], tf[L_];
  const int b = blockIdx.x;
  const int t = threadIdx.x;
  if (t < L_) {
    const float* f = attr_feat + ((size_t)b*L_ + t)*NF_;
    float sacc = feat_b[0];
    #pragma unroll
    for (int j=0;j<NF_;++j) sacc = fmaf(f[j], feat_w[j], sacc);
    wu[t] = 1.f/(1.f+__expf(-sacc));
    tf[t] = attr_tf[b*L_+t];
  }
  __syncthreads();
  const int Lu = lens_u[b], Li = lens_i[b];
  const float* xb = x + (size_t)b*L_*D_;
  float su=0.f, si=0.f;
  for (int l=0;l<Lu+Li;++l) {
    float val = xb[(size_t)l*D_ + t] * tf[l];
    if (l < Lu) su = fmaf(val, wu[l], su);
    else        si = fmaf(val, 1.f-wu[l], si);
  }
  user_out[(size_t)b*512 + t]       = su/(float)Lu;
  item_out[(size_t)b*512 + t]       = si/(float)Li;
  user_out[(size_t)b*512 + 256 + t] = user_tab[(size_t)user_ids[b]*D_ + t];
  item_out[(size_t)b*512 + 256 + t] = item_tab[(size_t)item_ids[b]*D_ + t];
}

// ---------------- logits + mask + new_targets ----------------
__global__ __launch_bounds__(256) void k_logits(
    const int* __restrict__ pos_t, const int* __restrict__ neg_t,
    const int* __restrict__ pos_l, const int* __restrict__ neg_l,
    const float* __restrict__ oeu, const float* __restrict__ oei,
    const float* __restrict__ user_out, const float* __restrict__ item_out,
    float* __restrict__ out)
{
  const int g = blockIdx.x*4 + (threadIdx.x >> 6);
  const int lane = threadIdx.x & 63;
  const int b = g / NT_;
  const int k = g - b*NT_;
  const int tid_ = (k < LP_) ? pos_t[b*LP_ + k] : neg_t[b*LNEG_ + (k-LP_)];
  const float* eu = oeu + (size_t)tid_*512;
  const float* ei = oei + (size_t)tid_*512;
  const float* uo = user_out + (size_t)b*512;
  const float* io = item_out + (size_t)b*512;
  const int d0 = lane*8;
  float s = 0.f;
  float4 a0 = *(const float4*)(eu+d0), a1 = *(const float4*)(eu+d0+4);
  float4 u0 = *(const float4*)(uo+d0), u1 = *(const float4*)(uo+d0+4);
  s += a0.x*u0.x + a0.y*u0.y + a0.z*u0.z + a0.w*u0.w;
  s += a1.x*u1.x + a1.y*u1.y + a1.z*u1.z + a1.w*u1.w;
  float4 c0 = *(const float4*)(ei+d0), c1 = *(const float4*)(ei+d0+4);
  float4 i0 = *(const float4*)(io+d0), i1 = *(const float4*)(io+d0+4);
  s += c0.x*i0.x + c0.y*i0.y + c0.z*i0.z + c0.w*i0.w;
  s += c1.x*i1.x + c1.y*i1.y + c1.z*i1.z + c1.w*i1.w;
  #pragma unroll
  for (int off=32; off>0; off>>=1) s += __shfl_xor(s, off, 64);
  if (lane == 0) {
    out[(size_t)b*NT_ + k] = s;
    float mv, nt;
    if (k < LP_) { mv = (k < pos_l[b]) ? 1.f : 0.f; nt = mv; }
    else         { mv = ((k - LP_) < neg_l[b]) ? 1.f : 0.f; nt = 0.f; }
    out[(size_t)B_*NT_   + (size_t)b*NT_ + k] = mv;
    out[(size_t)2*B_*NT_ + (size_t)b*NT_ + k] = nt;
  }
}

extern "C" void kernel_launch(void* const* d_in, const int* in_sizes, int n_in,
                              void* d_out, int out_size, void* d_ws, size_t ws_size,
                              hipStream_t stream)
{
  const int*   attr      = (const int*)d_in[0];
  const int*   attr_inds = (const int*)d_in[1];
  const float* attr_tf   = (const float*)d_in[2];
  const float* attr_feat = (const float*)d_in[3];
  const int*   attr_lens = (const int*)d_in[4];
  const int*   lens_u    = (const int*)d_in[5];
  const int*   lens_i    = (const int*)d_in[6];
  const int*   user_ids  = (const int*)d_in[7];
  const int*   item_ids  = (const int*)d_in[8];
  const int*   pos_t     = (const int*)d_in[9];
  const int*   pos_l     = (const int*)d_in[10];
  const int*   neg_t     = (const int*)d_in[11];
  const int*   neg_l     = (const int*)d_in[12];
  const float* attr_emb  = (const float*)d_in[13];
  const float* ind_emb   = (const float*)d_in[14];
  const float* user_tab  = (const float*)d_in[15];
  const float* item_tab  = (const float*)d_in[16];
  const float* oeu       = (const float*)d_in[17];
  const float* oei       = (const float*)d_in[18];
  const float* feat_w    = (const float*)d_in[19];
  const float* feat_b    = (const float*)d_in[20];
  const float* Wqkv      = (const float*)d_in[21];
  const float* bqkv      = (const float*)d_in[22];
  const float* Wo        = (const float*)d_in[23];
  const float* bo        = (const float*)d_in[24];
  const float* ln1s      = (const float*)d_in[25];
  const float* ln1b      = (const float*)d_in[26];
  const float* W1        = (const float*)d_in[27];
  const float* b1        = (const float*)d_in[28];
  const float* W2        = (const float*)d_in[29];
  const float* b2        = (const float*)d_in[30];
  const float* ln2s      = (const float*)d_in[31];
  const float* ln2b      = (const float*)d_in[32];

  // ---- workspace: uo[B,512] | io[B,512] | x[M,256]f32 | xb[M,256]bf16 | weights bf16 | scratch ----
  float* ws = (float*)d_ws;
  float* uo = ws;
  float* io = uo + (size_t)B_*512;
  float* x  = io + (size_t)B_*512;
  ushort* xb   = (ushort*)(x + (size_t)M_*D_);
  ushort* wq_b = xb + (size_t)M_*D_;
  ushort* wo_b = wq_b + (size_t)2*768*256;
  ushort* w1_b = wo_b + (size_t)2*256*256;
  ushort* w2_b = w1_b + (size_t)2*1024*256;
  float* scratch = (float*)(w2_b + (size_t)2*256*1024);

  const size_t fixed_floats = (size_t)B_*1024 + (size_t)M_*D_ + (size_t)M_*(D_/2) + 786432;
  int Bc = 8;
  for (int cand = 512; cand >= 8; cand >>= 1) {
    size_t need = (fixed_floats + (size_t)cand*L_*768) * sizeof(float);
    if (need <= ws_size) { Bc = cand; break; }
  }
  const int nchunks = B_ / Bc;
  const size_t Mc = (size_t)Bc * L_;

  float* out = (float*)d_out;

  k_f2b<<<(2*768*256)/2048,  256, 0, stream>>>(Wqkv, wq_b);
  k_f2b<<<(2*256*256)/2048,  256, 0, stream>>>(Wo,   wo_b);
  k_f2b<<<(2*1024*256)/2048, 256, 0, stream>>>(W1,   w1_b);
  k_f2b<<<(2*256*1024)/2048, 256, 0, stream>>>(W2,   w2_b);

  k_embed<<<M_*64/256, 256, 0, stream>>>(attr, attr_inds, attr_emb, ind_emb, x, xb);

  for (int l=0; l<NL_; ++l) {
    const float* bqkv_l = bqkv + (size_t)l*768;
    const float* bo_l   = bo   + (size_t)l*D_;
    const float* b1_l   = b1   + (size_t)l*FF_;
    const float* b2_l   = b2   + (size_t)l*D_;
    for (int c=0; c<nchunks; ++c) {
      const size_t row0 = (size_t)c * Mc;
      float*  xc    = x  + row0*D_;
      ushort* xb_c  = xb + row0*D_;
      // attention phase: qkv_b[Mc,768]bf16 | ctx_b[Mc,256]bf16 | t_c[Mc,256]f32
      ushort* qkv_b = (ushort*)scratch;
      ushort* ctx_b = (ushort*)(scratch + Mc*384);
      float*  t_c   = scratch + Mc*512;
      // FF phase: h_b[Mc,1024]bf16 | t2_c[Mc,256]f32
      ushort* h_b   = (ushort*)scratch;
      float*  t2_c  = scratch + Mc*512;

      k_gemm_mfma<1,0><<<dim3(768/128, Mc/128), 256, 0, stream>>>(
          xb_c, wq_b + (size_t)l*768*256, bqkv_l, qkv_b, (int)Mc, 768, 256);
      k_attn_mfma<<<Bc*H_, 256, 0, stream>>>(qkv_b, ctx_b, attr_lens, c*Bc);
      k_gemm_mfma<0,0><<<dim3(256/128, Mc/128), 256, 0, stream>>>(
          ctx_b, wo_b + (size_t)l*256*256, bo_l, t_c, (int)Mc, 256, 256);
      k_lnadd<<<Mc/4, 256, 0, stream>>>(xc, xb_c, t_c, ln1s + (size_t)l*D_, ln1b + (size_t)l*D_);
      k_gemm_mfma<1,1><<<dim3(1024/128, Mc/128), 256, 0, stream>>>(
          xb_c, w1_b + (size_t)l*1024*256, b1_l, h_b, (int)Mc, 1024, 256);
      k_gemm_mfma<0,0><<<dim3(256/128, Mc/128), 256, 0, stream>>>(
          h_b, w2_b + (size_t)l*256*1024, b2_l, t2_c, (int)Mc, 256, 1024);
      k_lnadd<<<Mc/4, 256, 0, stream>>>(xc, xb_c, t2_c, ln2s + (size_t)l*D_, ln2b + (size_t)l*D_);
    }
  }
  k_pool<<<B_, 256, 0, stream>>>(x, attr_tf, attr_feat, lens_u, lens_i, user_ids, item_ids,
                                 user_tab, item_tab, feat_w, feat_b, uo, io);
  k_logits<<<B_*NT_/4, 256, 0, stream>>>(pos_t, neg_t, pos_l, neg_l, oeu, oei, uo, io, out);
}

// Round 5
// 888.974 us; speedup vs baseline: 5.9439x; 1.5173x over previous
//
#include <hip/hip_runtime.h>
#include <hip/hip_bf16.h>
#include <cstdint>
#include <cstddef>

#define B_ 512
#define L_ 192
#define D_ 256
#define H_ 4
#define DH_ 64
#define FF_ 1024
#define NL_ 2
#define LP_ 30
#define LNEG_ 300
#define NF_ 13
#define M_ (B_*L_)   // 98304 tokens
#define NT_ 330      // LP_+LNEG_

typedef __attribute__((ext_vector_type(8))) short bf16x8;
typedef __attribute__((ext_vector_type(4))) float f32x4;

// RNE float -> bf16 bits (finite inputs only)
__device__ __forceinline__ ushort f2b(float f) {
  union { float f; uint32_t u; } v; v.f = f;
  uint32_t u = v.u;
  return (ushort)((u + 0x7FFFu + ((u >> 16) & 1u)) >> 16);
}

// ---------------- prefix sums of lens: off[513], per-chunk counts ----------------
__global__ __launch_bounds__(512) void k_prefix(
    const int* __restrict__ lens, int* __restrict__ off,
    int* __restrict__ ccnt, int* __restrict__ ccntp, int Bc, int nchunks)
{
  const int t = threadIdx.x;
  int s = 0;
  for (int i = 0; i < t; ++i) s += lens[i];
  off[t] = s;
  if (t == 511) off[512] = s + lens[511];
  if (t < nchunks) {
    int s2 = 0;
    const int c0 = t * Bc;
    for (int i = 0; i < Bc; ++i) s2 += lens[c0 + i];
    ccnt[t]  = s2;
    ccntp[t] = (s2 + 127) & ~127;
  }
}

// ---------------- fp32 -> bf16 weight conversion ----------------
__global__ __launch_bounds__(256) void k_f2b(const float* __restrict__ in, ushort* __restrict__ out) {
  const int i = (blockIdx.x*256 + threadIdx.x)*8;
  float4 a = *(const float4*)(in+i);
  float4 b = *(const float4*)(in+i+4);
  ushort4 o1; o1.x=f2b(a.x); o1.y=f2b(a.y); o1.z=f2b(a.z); o1.w=f2b(a.w);
  ushort4 o2; o2.x=f2b(b.x); o2.y=f2b(b.y); o2.z=f2b(b.z); o2.w=f2b(b.w);
  *(ushort4*)(out+i)   = o1;
  *(ushort4*)(out+i+4) = o2;
}

// ---------------- embedding gather into COMPACT token space ----------------
__global__ __launch_bounds__(256) void k_embed(
    const int* __restrict__ attr, const int* __restrict__ inds,
    const int* __restrict__ lens, const int* __restrict__ off,
    const float* __restrict__ attr_emb, const float* __restrict__ ind_emb,
    float* __restrict__ x, ushort* __restrict__ xb)
{
  int idx = blockIdx.x*256 + threadIdx.x;
  int token = idx >> 6;
  int c = (idx & 63) * 4;
  int b = token / L_;
  int l = token - b*L_;
  if (l >= lens[b]) return;                    // padding token: no compact slot
  size_t crow = (size_t)off[b] + l;
  int a = attr[token];
  int id = inds[token];
  const float4 e  = *(const float4*)(attr_emb + (size_t)a*D_ + c);
  const float4 ie = *(const float4*)(ind_emb  + (size_t)id*D_ + c);
  float4 o; o.x=e.x+ie.x; o.y=e.y+ie.y; o.z=e.z+ie.z; o.w=e.w+ie.w;
  *(float4*)(x + crow*D_ + c) = o;
  ushort4 ob; ob.x=f2b(o.x); ob.y=f2b(o.y); ob.z=f2b(o.z); ob.w=f2b(o.w);
  *(ushort4*)(xb + crow*D_ + c) = ob;
}

// ---------------- bf16 MFMA GEMM on compact rows: C[m,N] = A[aoff+m,K] @ W[N,K]^T + bias ----------------
// Grid y sized worst-case; blocks past *cntp (128-padded valid rows) exit immediately.
template<int OUT_BF16, int RELU>
__global__ __launch_bounds__(256) void k_gemm_mfma(
    const ushort* __restrict__ A, const int* __restrict__ aoffp,
    const int* __restrict__ cntp,
    const ushort* __restrict__ W, const float* __restrict__ bias,
    void* __restrict__ Cv, int N, int K)
{
  if ((int)blockIdx.y * 128 >= *cntp) return;
  __shared__ alignas(16) ushort As[8192];   // [128][64] bf16
  __shared__ alignas(16) ushort Bs[8192];
  const int abase = *aoffp;
  const int tid = threadIdx.x;
  const int w = tid >> 6, l = tid & 63;
  const int m0 = blockIdx.y*128, n0 = blockIdx.x*128;
  const int wr = w >> 1, wc = w & 1;

  f32x4 acc[4][4];
  #pragma unroll
  for (int i=0;i<4;++i)
    #pragma unroll
    for (int j=0;j<4;++j) acc[i][j] = (f32x4){0.f,0.f,0.f,0.f};

  for (int k0=0; k0<K; k0+=64) {
    #pragma unroll
    for (int i=0;i<4;++i) {
      const int li  = i*4096 + tid*16;
      const int row = li >> 7;
      const int col = (li & 127) >> 1;
      const ushort* ga = A + (size_t)(abase+m0+row)*K + k0 + col;
      const ushort* gb = W + (size_t)(n0+row)*K + k0 + col;
      ushort* la = As + i*2048 + w*512;
      ushort* lb = Bs + i*2048 + w*512;
      __builtin_amdgcn_global_load_lds((const __attribute__((address_space(1))) unsigned int*)ga,
                                       (__attribute__((address_space(3))) unsigned int*)la, 16, 0, 0);
      __builtin_amdgcn_global_load_lds((const __attribute__((address_space(1))) unsigned int*)gb,
                                       (__attribute__((address_space(3))) unsigned int*)lb, 16, 0, 0);
    }
    __syncthreads();
    #pragma unroll
    for (int ks=0; ks<2; ++ks) {
      bf16x8 af[4], bfr[4];
      #pragma unroll
      for (int i2=0;i2<4;++i2) {
        af[i2]  = *(const bf16x8*)(As + (size_t)(wr*64 + i2*16 + (l&15))*64 + (l>>4)*8 + ks*32);
        bfr[i2] = *(const bf16x8*)(Bs + (size_t)(wc*64 + i2*16 + (l&15))*64 + (l>>4)*8 + ks*32);
      }
      #pragma unroll
      for (int mi=0;mi<4;++mi)
        #pragma unroll
        for (int ni=0;ni<4;++ni)
          acc[mi][ni] = __builtin_amdgcn_mfma_f32_16x16x32_bf16(af[mi], bfr[ni], acc[mi][ni], 0,0,0);
    }
    __syncthreads();
  }
  const int col0 = n0 + wc*64 + (l&15);
  const int row0 = m0 + wr*64 + ((l>>4)<<2);
  #pragma unroll
  for (int ni=0;ni<4;++ni) {
    const float bv = bias[col0 + ni*16];
    #pragma unroll
    for (int mi=0;mi<4;++mi) {
      #pragma unroll
      for (int r=0;r<4;++r) {
        float v = acc[mi][ni][r] + bv;
        if (RELU) v = fmaxf(v, 0.f);
        const size_t idx = (size_t)(row0 + mi*16 + r)*N + col0 + ni*16;
        if (OUT_BF16) ((ushort*)Cv)[idx] = f2b(v);
        else          ((float*)Cv)[idx]  = v;
      }
    }
  }
}

// ---------------- MFMA flash attention on compact rows: block per (b,h) ----------------
// LDS (80 KB): Kb[192][128B] swz ^=(row&7)<<4 | Vt[64 d-rows][512B] swz ^=(d&7)<<4 | Pw/wave [6][16][64B] swz ^=((q>>2)&3)<<4
__global__ __launch_bounds__(256) void k_attn_mfma(
    const ushort* __restrict__ qkv, ushort* __restrict__ ctx,
    const int* __restrict__ offc)
{
  __shared__ alignas(16) char lds[81920];
  char* Kb = lds;
  char* Vt = lds + 24576;
  const int tid = threadIdx.x;
  const int w = tid >> 6, l = tid & 63;
  const int g = l >> 4, c = l & 15;
  char* Pw = lds + 57344 + w*6144;
  const int bl = blockIdx.x >> 2, h = blockIdx.x & 3;
  const int rowbase = offc[bl] - offc[0];
  const int len = offc[bl+1] - offc[bl];
  const int nkt = (len + 15) >> 4;
  const int nkf = (len + 31) >> 5;
  const ushort* base = qkv + (size_t)rowbase*768;
  ushort* cbase = ctx + (size_t)rowbase*256;

  // stage K rows [0, nkt*16) (tail rows read in-bounds garbage, masked later)
  const int lenk8 = nkt*16*8;
  for (int idx = tid; idx < lenk8; idx += 256) {
    int row = idx >> 3, ch = idx & 7;
    uint4 v = *(const uint4*)(base + (size_t)row*768 + 256 + h*64 + ch*8);
    *(uint4*)(Kb + ((row*128 + ch*16) ^ ((row&7)<<4))) = v;
  }
  // stage V transposed for keys [0, nkf*32)
  {
    const int lenv = nkf*32;
    int d0 = (tid & 15)*4;
    for (int key = tid >> 4; key < lenv; key += 16) {
      ushort4 v = *(const ushort4*)(base + (size_t)key*768 + 512 + h*64 + d0);
      ushort vv[4] = {v.x, v.y, v.z, v.w};
      #pragma unroll
      for (int j=0;j<4;++j) {
        int d = d0 + j;
        *(ushort*)(Vt + ((d*512 + key*2) ^ ((d&7)<<4))) = vv[j];
      }
    }
  }
  __syncthreads();

  // zero P for tail keys [nkt*16, nkf*32)
  for (int t = nkt; t < 2*nkf; ++t) {
    #pragma unroll
    for (int r=0;r<4;++r) {
      int q = 4*g + r;
      *(ushort*)(Pw + (((t>>1)*1024 + q*64 + ((t&1)*16 + c)*2) ^ (((q>>2)&3)<<4))) = 0;
    }
  }

  const int nst = (len + 15) >> 4;
  for (int s = w; s < nst; s += 4) {
    // Q fragments (rows beyond len read in-bounds garbage; outputs guarded)
    const ushort* qp = base + (size_t)(s*16 + c)*768 + h*64 + g*8;
    bf16x8 aq0 = *(const bf16x8*)qp;
    bf16x8 aq1 = *(const bf16x8*)(qp + 32);

    f32x4 sc[12];
    #pragma unroll
    for (int t=0;t<12;++t) {
      sc[t] = (f32x4){0.f,0.f,0.f,0.f};
      if (t < nkt) {
        int ba0 = ((t*16 + c)*128 + g*16)      ^ ((c&7)<<4);
        int ba1 = ((t*16 + c)*128 + g*16 + 64) ^ ((c&7)<<4);
        bf16x8 k0 = *(const bf16x8*)(Kb + ba0);
        bf16x8 k1 = *(const bf16x8*)(Kb + ba1);
        sc[t] = __builtin_amdgcn_mfma_f32_16x16x32_bf16(aq0, k0, sc[t], 0,0,0);
        sc[t] = __builtin_amdgcn_mfma_f32_16x16x32_bf16(aq1, k1, sc[t], 0,0,0);
        if (t == nkt-1 && t*16 + c >= len)
          sc[t] = (f32x4){-1e30f,-1e30f,-1e30f,-1e30f};
      }
    }
    float mr[4] = {-1e30f,-1e30f,-1e30f,-1e30f};
    #pragma unroll
    for (int t=0;t<12;++t) if (t<nkt) {
      #pragma unroll
      for (int r=0;r<4;++r) mr[r] = fmaxf(mr[r], sc[t][r]);
    }
    #pragma unroll
    for (int r=0;r<4;++r) {
      mr[r] = fmaxf(mr[r], __shfl_xor(mr[r], 1, 16));
      mr[r] = fmaxf(mr[r], __shfl_xor(mr[r], 2, 16));
      mr[r] = fmaxf(mr[r], __shfl_xor(mr[r], 4, 16));
      mr[r] = fmaxf(mr[r], __shfl_xor(mr[r], 8, 16));
    }
    float sr[4] = {0.f,0.f,0.f,0.f};
    #pragma unroll
    for (int t=0;t<12;++t) if (t<nkt) {
      #pragma unroll
      for (int r=0;r<4;++r) {
        float p = __expf((sc[t][r] - mr[r]) * 0.125f);
        sr[r] += p;
        int q = 4*g + r;
        *(ushort*)(Pw + (((t>>1)*1024 + q*64 + ((t&1)*16 + c)*2) ^ (((q>>2)&3)<<4))) = f2b(p);
      }
    }
    #pragma unroll
    for (int r=0;r<4;++r) {
      sr[r] += __shfl_xor(sr[r], 1, 16);
      sr[r] += __shfl_xor(sr[r], 2, 16);
      sr[r] += __shfl_xor(sr[r], 4, 16);
      sr[r] += __shfl_xor(sr[r], 8, 16);
    }
    f32x4 oa[4];
    #pragma unroll
    for (int dt=0;dt<4;++dt) oa[dt] = (f32x4){0.f,0.f,0.f,0.f};
    #pragma unroll
    for (int kf=0;kf<6;++kf) if (kf<nkf) {
      bf16x8 pf = *(const bf16x8*)(Pw + ((kf*1024 + c*64 + g*16) ^ (((c>>2)&3)<<4)));
      #pragma unroll
      for (int dt=0;dt<4;++dt) {
        int d = dt*16 + c;
        bf16x8 vf = *(const bf16x8*)(Vt + ((d*512 + kf*64 + g*16) ^ ((d&7)<<4)));
        oa[dt] = __builtin_amdgcn_mfma_f32_16x16x32_bf16(pf, vf, oa[dt], 0,0,0);
      }
    }
    float inv[4];
    #pragma unroll
    for (int r=0;r<4;++r) inv[r] = 1.f / sr[r];
    ushort* orow = cbase + (size_t)(s*16)*256 + h*64;
    #pragma unroll
    for (int r=0;r<4;++r) {
      int q = 4*g + r;
      if (s*16 + q < len) {     // compact space: every row < len is a real token
        #pragma unroll
        for (int dt=0;dt<4;++dt)
          orow[(size_t)q*256 + dt*16 + c] = f2b(oa[dt][r] * inv[r]);
      }
    }
  }
}

// ---------------- residual + LayerNorm on compact rows ----------------
__global__ __launch_bounds__(256) void k_lnadd(
    float* __restrict__ x, ushort* __restrict__ xb, const float* __restrict__ t,
    const float* __restrict__ s, const float* __restrict__ bb,
    const int* __restrict__ offp, const int* __restrict__ cntp)
{
  int token = blockIdx.x*4 + (threadIdx.x >> 6);
  if (token >= *cntp) return;
  size_t row = (size_t)(*offp) + token;
  int lane = threadIdx.x & 63;
  float* xp = x + row*D_;
  const float* tp = t + (size_t)token*D_;
  int d = lane*4;
  float4 xv = *(const float4*)(xp + d);
  float4 tv = *(const float4*)(tp + d);
  float y[4] = {xv.x+tv.x, xv.y+tv.y, xv.z+tv.z, xv.w+tv.w};
  float sum = y[0]+y[1]+y[2]+y[3];
  #pragma unroll
  for (int off=32; off>0; off>>=1) sum += __shfl_xor(sum, off, 64);
  float mean = sum * (1.f/256.f);
  float v0=y[0]-mean, v1=y[1]-mean, v2=y[2]-mean, v3=y[3]-mean;
  float vs = v0*v0+v1*v1+v2*v2+v3*v3;
  #pragma unroll
  for (int off=32; off>0; off>>=1) vs += __shfl_xor(vs, off, 64);
  float inv = rsqrtf(vs*(1.f/256.f) + 1e-5f);
  float4 sv = *(const float4*)(s + d);
  float4 bv = *(const float4*)(bb + d);
  float4 o;
  o.x = v0*inv*sv.x + bv.x;
  o.y = v1*inv*sv.y + bv.y;
  o.z = v2*inv*sv.z + bv.z;
  o.w = v3*inv*sv.w + bv.w;
  *(float4*)(xp + d) = o;
  ushort4 ob; ob.x=f2b(o.x); ob.y=f2b(o.y); ob.z=f2b(o.z); ob.w=f2b(o.w);
  *(ushort4*)(xb + row*D_ + d) = ob;
}

// ---------------- ragged weighted pooling (compact x) + concat id embeddings ----------------
__global__ __launch_bounds__(256) void k_pool(
    const float* __restrict__ x, const int* __restrict__ off,
    const float* __restrict__ attr_tf, const float* __restrict__ attr_feat,
    const int* __restrict__ lens_u, const int* __restrict__ lens_i,
    const int* __restrict__ user_ids, const int* __restrict__ item_ids,
    const float* __restrict__ user_tab, const float* __restrict__ item_tab,
    const float* __restrict__ feat_w, const float* __restrict__ feat_b,
    float* __restrict__ user_out, float* __restrict__ item_out)
{
  __shared__ float wu[L_], tf[L_];
  const int b = blockIdx.x;
  const int t = threadIdx.x;
  if (t < L_) {
    const float* f = attr_feat + ((size_t)b*L_ + t)*NF_;
    float sacc = feat_b[0];
    #pragma unroll
    for (int j=0;j<NF_;++j) sacc = fmaf(f[j], feat_w[j], sacc);
    wu[t] = 1.f/(1.f+__expf(-sacc));
    tf[t] = attr_tf[b*L_+t];
  }
  __syncthreads();
  const int Lu = lens_u[b], Li = lens_i[b];
  const float* xrow = x + (size_t)off[b]*D_;
  float su=0.f, si=0.f;
  for (int l=0;l<Lu+Li;++l) {
    float val = xrow[(size_t)l*D_ + t] * tf[l];
    if (l < Lu) su = fmaf(val, wu[l], su);
    else        si = fmaf(val, 1.f-wu[l], si);
  }
  user_out[(size_t)b*512 + t]       = su/(float)Lu;
  item_out[(size_t)b*512 + t]       = si/(float)Li;
  user_out[(size_t)b*512 + 256 + t] = user_tab[(size_t)user_ids[b]*D_ + t];
  item_out[(size_t)b*512 + 256 + t] = item_tab[(size_t)item_ids[b]*D_ + t];
}

// ---------------- logits + mask + new_targets ----------------
__global__ __launch_bounds__(256) void k_logits(
    const int* __restrict__ pos_t, const int* __restrict__ neg_t,
    const int* __restrict__ pos_l, const int* __restrict__ neg_l,
    const float* __restrict__ oeu, const float* __restrict__ oei,
    const float* __restrict__ user_out, const float* __restrict__ item_out,
    float* __restrict__ out)
{
  const int g = blockIdx.x*4 + (threadIdx.x >> 6);
  const int lane = threadIdx.x & 63;
  const int b = g / NT_;
  const int k = g - b*NT_;
  const int tid_ = (k < LP_) ? pos_t[b*LP_ + k] : neg_t[b*LNEG_ + (k-LP_)];
  const float* eu = oeu + (size_t)tid_*512;
  const float* ei = oei + (size_t)tid_*512;
  const float* uo = user_out + (size_t)b*512;
  const float* io = item_out + (size_t)b*512;
  const int d0 = lane*8;
  float s = 0.f;
  float4 a0 = *(const float4*)(eu+d0), a1 = *(const float4*)(eu+d0+4);
  float4 u0 = *(const float4*)(uo+d0), u1 = *(const float4*)(uo+d0+4);
  s += a0.x*u0.x + a0.y*u0.y + a0.z*u0.z + a0.w*u0.w;
  s += a1.x*u1.x + a1.y*u1.y + a1.z*u1.z + a1.w*u1.w;
  float4 c0 = *(const float4*)(ei+d0), c1 = *(const float4*)(ei+d0+4);
  float4 i0 = *(const float4*)(io+d0), i1 = *(const float4*)(io+d0+4);
  s += c0.x*i0.x + c0.y*i0.y + c0.z*i0.z + c0.w*i0.w;
  s += c1.x*i1.x + c1.y*i1.y + c1.z*i1.z + c1.w*i1.w;
  #pragma unroll
  for (int off=32; off>0; off>>=1) s += __shfl_xor(s, off, 64);
  if (lane == 0) {
    out[(size_t)b*NT_ + k] = s;
    float mv, nt;
    if (k < LP_) { mv = (k < pos_l[b]) ? 1.f : 0.f; nt = mv; }
    else         { mv = ((k - LP_) < neg_l[b]) ? 1.f : 0.f; nt = 0.f; }
    out[(size_t)B_*NT_   + (size_t)b*NT_ + k] = mv;
    out[(size_t)2*B_*NT_ + (size_t)b*NT_ + k] = nt;
  }
}

extern "C" void kernel_launch(void* const* d_in, const int* in_sizes, int n_in,
                              void* d_out, int out_size, void* d_ws, size_t ws_size,
                              hipStream_t stream)
{
  const int*   attr      = (const int*)d_in[0];
  const int*   attr_inds = (const int*)d_in[1];
  const float* attr_tf   = (const float*)d_in[2];
  const float* attr_feat = (const float*)d_in[3];
  const int*   attr_lens = (const int*)d_in[4];
  const int*   lens_u    = (const int*)d_in[5];
  const int*   lens_i    = (const int*)d_in[6];
  const int*   user_ids  = (const int*)d_in[7];
  const int*   item_ids  = (const int*)d_in[8];
  const int*   pos_t     = (const int*)d_in[9];
  const int*   pos_l     = (const int*)d_in[10];
  const int*   neg_t     = (const int*)d_in[11];
  const int*   neg_l     = (const int*)d_in[12];
  const float* attr_emb  = (const float*)d_in[13];
  const float* ind_emb   = (const float*)d_in[14];
  const float* user_tab  = (const float*)d_in[15];
  const float* item_tab  = (const float*)d_in[16];
  const float* oeu       = (const float*)d_in[17];
  const float* oei       = (const float*)d_in[18];
  const float* feat_w    = (const float*)d_in[19];
  const float* feat_b    = (const float*)d_in[20];
  const float* Wqkv      = (const float*)d_in[21];
  const float* bqkv      = (const float*)d_in[22];
  const float* Wo        = (const float*)d_in[23];
  const float* bo        = (const float*)d_in[24];
  const float* ln1s      = (const float*)d_in[25];
  const float* ln1b      = (const float*)d_in[26];
  const float* W1        = (const float*)d_in[27];
  const float* b1        = (const float*)d_in[28];
  const float* W2        = (const float*)d_in[29];
  const float* b2        = (const float*)d_in[30];
  const float* ln2s      = (const float*)d_in[31];
  const float* ln2b      = (const float*)d_in[32];

  // ---- ws layout: ints[768] | uo[B,512] | io[B,512] | x[M,256]f32 | xb[M,256]bf16 | weights bf16 | chunk scratch ----
  int* ioff  = (int*)d_ws;            // off[513]
  int* ccnt  = ioff + 520;            // per-chunk valid rows [64]
  int* ccntp = ccnt + 64;             // 128-padded            [64]
  float* ws = (float*)d_ws + 768;
  float* uo = ws;
  float* io = uo + (size_t)B_*512;
  float* x  = io + (size_t)B_*512;
  ushort* xb   = (ushort*)(x + (size_t)M_*D_);
  ushort* wq_b = xb + (size_t)M_*D_;
  ushort* wo_b = wq_b + (size_t)2*768*256;
  ushort* w1_b = wo_b + (size_t)2*256*256;
  ushort* w2_b = w1_b + (size_t)2*1024*256;
  float* scratch = (float*)(w2_b + (size_t)2*256*1024);

  const size_t fixed_floats = 768 + (size_t)B_*1024 + (size_t)M_*D_ + (size_t)M_*(D_/2) + 786432;
  int Bc = 8;
  for (int cand = 512; cand >= 8; cand >>= 1) {
    size_t need = (fixed_floats + (size_t)cand*L_*768) * sizeof(float);
    if (need <= ws_size) { Bc = cand; break; }
  }
  const int nchunks = B_ / Bc;
  const size_t Mc = (size_t)Bc * L_;   // multiple of 128 for Bc>=8 powers of 2

  float* out = (float*)d_out;

  k_prefix<<<1, 512, 0, stream>>>(attr_lens, ioff, ccnt, ccntp, Bc, nchunks);
  k_f2b<<<(2*768*256)/2048,  256, 0, stream>>>(Wqkv, wq_b);
  k_f2b<<<(2*256*256)/2048,  256, 0, stream>>>(Wo,   wo_b);
  k_f2b<<<(2*1024*256)/2048, 256, 0, stream>>>(W1,   w1_b);
  k_f2b<<<(2*256*1024)/2048, 256, 0, stream>>>(W2,   w2_b);
  k_embed<<<M_*64/256, 256, 0, stream>>>(attr, attr_inds, attr_lens, ioff, attr_emb, ind_emb, x, xb);

  for (int l=0; l<NL_; ++l) {
    const float* bqkv_l = bqkv + (size_t)l*768;
    const float* bo_l   = bo   + (size_t)l*D_;
    const float* b1_l   = b1   + (size_t)l*FF_;
    const float* b2_l   = b2   + (size_t)l*D_;
    for (int c=0; c<nchunks; ++c) {
      const int* offc = ioff + c*Bc;       // chunk batch-offset base (off[b0]); ioff[0]==0 used for local-A GEMMs
      const int* cntp = ccntp + c;
      const int* cnt  = ccnt + c;
      // attention phase: qkv_b[Mc,768]bf16 | ctx_b[Mc,256]bf16 | t_c[Mc,256]f32
      ushort* qkv_b = (ushort*)scratch;
      ushort* ctx_b = (ushort*)(scratch + Mc*384);
      float*  t_c   = scratch + Mc*512;
      // FF phase: h_b[Mc,1024]bf16 | t2_c[Mc,256]f32
      ushort* h_b   = (ushort*)scratch;
      float*  t2_c  = scratch + Mc*512;

      k_gemm_mfma<1,0><<<dim3(768/128, Mc/128), 256, 0, stream>>>(
          xb, offc, cntp, wq_b + (size_t)l*768*256, bqkv_l, qkv_b, 768, 256);
      k_attn_mfma<<<Bc*H_, 256, 0, stream>>>(qkv_b, ctx_b, offc);
      k_gemm_mfma<0,0><<<dim3(256/128, Mc/128), 256, 0, stream>>>(
          ctx_b, ioff, cntp, wo_b + (size_t)l*256*256, bo_l, t_c, 256, 256);
      k_lnadd<<<Mc/4, 256, 0, stream>>>(x, xb, t_c, ln1s + (size_t)l*D_, ln1b + (size_t)l*D_, offc, cnt);
      k_gemm_mfma<1,1><<<dim3(1024/128, Mc/128), 256, 0, stream>>>(
          xb, offc, cntp, w1_b + (size_t)l*1024*256, b1_l, h_b, 1024, 256);
      k_gemm_mfma<0,0><<<dim3(256/128, Mc/128), 256, 0, stream>>>(
          h_b, ioff, cntp, w2_b + (size_t)l*256*1024, b2_l, t2_c, 256, 1024);
      k_lnadd<<<Mc/4, 256, 0, stream>>>(x, xb, t2_c, ln2s + (size_t)l*D_, ln2b + (size_t)l*D_, offc, cnt);
    }
  }
  k_pool<<<B_, 256, 0, stream>>>(x, ioff, attr_tf, attr_feat, lens_u, lens_i, user_ids, item_ids,
                                 user_tab, item_tab, feat_w, feat_b, uo, io);
  k_logits<<<B_*NT_/4, 256, 0, stream>>>(pos_t, neg_t, pos_l, neg_l, oeu, oei, uo, io, out);
}

// Round 6
// 817.203 us; speedup vs baseline: 6.4659x; 1.0878x over previous
//
#include <hip/hip_runtime.h>
#include <hip/hip_bf16.h>
#include <cstdint>
#include <cstddef>

#define B_ 512
#define L_ 192
#define D_ 256
#define H_ 4
#define DH_ 64
#define FF_ 1024
#define NL_ 2
#define LP_ 30
#define LNEG_ 300
#define NF_ 13
#define M_ (B_*L_)   // 98304 tokens
#define NT_ 330      // LP_+LNEG_

typedef __attribute__((ext_vector_type(8))) short bf16x8;
typedef __attribute__((ext_vector_type(4))) float f32x4;

// RNE float -> bf16 bits (finite inputs only)
__device__ __forceinline__ ushort f2b(float f) {
  union { float f; uint32_t u; } v; v.f = f;
  uint32_t u = v.u;
  return (ushort)((u + 0x7FFFu + ((u >> 16) & 1u)) >> 16);
}

// ---------------- prefix sums of lens: off[513], per-chunk counts ----------------
__global__ __launch_bounds__(512) void k_prefix(
    const int* __restrict__ lens, int* __restrict__ off,
    int* __restrict__ ccnt, int* __restrict__ ccntp, int Bc, int nchunks)
{
  const int t = threadIdx.x;
  int s = 0;
  for (int i = 0; i < t; ++i) s += lens[i];
  off[t] = s;
  if (t == 511) off[512] = s + lens[511];
  if (t < nchunks) {
    int s2 = 0;
    const int c0 = t * Bc;
    for (int i = 0; i < Bc; ++i) s2 += lens[c0 + i];
    ccnt[t]  = s2;
    ccntp[t] = (s2 + 127) & ~127;
  }
}

// ---------------- fp32 -> bf16 conversion of all 4 weight groups in one launch ----------------
// block ranges: [0,192) Wqkv | [192,256) Wo | [256,512) W1 | [512,768) W2   (2048 elems/block)
__global__ __launch_bounds__(256) void k_f2b4(
    const float* __restrict__ wq, const float* __restrict__ wo,
    const float* __restrict__ w1, const float* __restrict__ w2,
    ushort* __restrict__ oq, ushort* __restrict__ oo,
    ushort* __restrict__ o1, ushort* __restrict__ o2)
{
  int bb = blockIdx.x;
  const float* in; ushort* out; int base;
  if (bb < 192)      { in = wq; out = oq; base = bb; }
  else if (bb < 256) { in = wo; out = oo; base = bb - 192; }
  else if (bb < 512) { in = w1; out = o1; base = bb - 256; }
  else               { in = w2; out = o2; base = bb - 512; }
  const int i = base*2048 + threadIdx.x*8;
  float4 a = *(const float4*)(in+i);
  float4 b = *(const float4*)(in+i+4);
  ushort4 q1; q1.x=f2b(a.x); q1.y=f2b(a.y); q1.z=f2b(a.z); q1.w=f2b(a.w);
  ushort4 q2; q2.x=f2b(b.x); q2.y=f2b(b.y); q2.z=f2b(b.z); q2.w=f2b(b.w);
  *(ushort4*)(out+i)   = q1;
  *(ushort4*)(out+i+4) = q2;
}

// ---------------- embedding gather into COMPACT token space ----------------
__global__ __launch_bounds__(256) void k_embed(
    const int* __restrict__ attr, const int* __restrict__ inds,
    const int* __restrict__ lens, const int* __restrict__ off,
    const float* __restrict__ attr_emb, const float* __restrict__ ind_emb,
    float* __restrict__ x, ushort* __restrict__ xb)
{
  int idx = blockIdx.x*256 + threadIdx.x;
  int token = idx >> 6;
  int c = (idx & 63) * 4;
  int b = token / L_;
  int l = token - b*L_;
  if (l >= lens[b]) return;
  size_t crow = (size_t)off[b] + l;
  int a = attr[token];
  int id = inds[token];
  const float4 e  = *(const float4*)(attr_emb + (size_t)a*D_ + c);
  const float4 ie = *(const float4*)(ind_emb  + (size_t)id*D_ + c);
  float4 o; o.x=e.x+ie.x; o.y=e.y+ie.y; o.z=e.z+ie.z; o.w=e.w+ie.w;
  *(float4*)(x + crow*D_ + c) = o;
  ushort4 ob; ob.x=f2b(o.x); ob.y=f2b(o.y); ob.z=f2b(o.z); ob.w=f2b(o.w);
  *(ushort4*)(xb + crow*D_ + c) = ob;
}

// ---------------- bf16 MFMA GEMM (128x128): C = A[aoff..] @ W^T + bias ----------------
template<int OUT_BF16, int RELU>
__global__ __launch_bounds__(256) void k_gemm_mfma(
    const ushort* __restrict__ A, const int* __restrict__ aoffp,
    const int* __restrict__ cntp,
    const ushort* __restrict__ W, const float* __restrict__ bias,
    void* __restrict__ Cv, int N, int K)
{
  if ((int)blockIdx.y * 128 >= *cntp) return;
  __shared__ alignas(16) ushort As[8192];
  __shared__ alignas(16) ushort Bs[8192];
  const int abase = *aoffp;
  const int tid = threadIdx.x;
  const int w = tid >> 6, l = tid & 63;
  const int m0 = blockIdx.y*128, n0 = blockIdx.x*128;
  const int wr = w >> 1, wc = w & 1;

  f32x4 acc[4][4];
  #pragma unroll
  for (int i=0;i<4;++i)
    #pragma unroll
    for (int j=0;j<4;++j) acc[i][j] = (f32x4){0.f,0.f,0.f,0.f};

  for (int k0=0; k0<K; k0+=64) {
    #pragma unroll
    for (int i=0;i<4;++i) {
      const int li  = i*4096 + tid*16;
      const int row = li >> 7;
      const int col = (li & 127) >> 1;
      const ushort* ga = A + (size_t)(abase+m0+row)*K + k0 + col;
      const ushort* gb = W + (size_t)(n0+row)*K + k0 + col;
      ushort* la = As + i*2048 + w*512;
      ushort* lb = Bs + i*2048 + w*512;
      __builtin_amdgcn_global_load_lds((const __attribute__((address_space(1))) unsigned int*)ga,
                                       (__attribute__((address_space(3))) unsigned int*)la, 16, 0, 0);
      __builtin_amdgcn_global_load_lds((const __attribute__((address_space(1))) unsigned int*)gb,
                                       (__attribute__((address_space(3))) unsigned int*)lb, 16, 0, 0);
    }
    __syncthreads();
    #pragma unroll
    for (int ks=0; ks<2; ++ks) {
      bf16x8 af[4], bfr[4];
      #pragma unroll
      for (int i2=0;i2<4;++i2) {
        af[i2]  = *(const bf16x8*)(As + (size_t)(wr*64 + i2*16 + (l&15))*64 + (l>>4)*8 + ks*32);
        bfr[i2] = *(const bf16x8*)(Bs + (size_t)(wc*64 + i2*16 + (l&15))*64 + (l>>4)*8 + ks*32);
      }
      #pragma unroll
      for (int mi=0;mi<4;++mi)
        #pragma unroll
        for (int ni=0;ni<4;++ni)
          acc[mi][ni] = __builtin_amdgcn_mfma_f32_16x16x32_bf16(af[mi], bfr[ni], acc[mi][ni], 0,0,0);
    }
    __syncthreads();
  }
  const int col0 = n0 + wc*64 + (l&15);
  const int row0 = m0 + wr*64 + ((l>>4)<<2);
  #pragma unroll
  for (int ni=0;ni<4;++ni) {
    const float bv = bias[col0 + ni*16];
    #pragma unroll
    for (int mi=0;mi<4;++mi) {
      #pragma unroll
      for (int r=0;r<4;++r) {
        float v = acc[mi][ni][r] + bv;
        if (RELU) v = fmaxf(v, 0.f);
        const size_t idx = (size_t)(row0 + mi*16 + r)*N + col0 + ni*16;
        if (OUT_BF16) ((ushort*)Cv)[idx] = f2b(v);
        else          ((float*)Cv)[idx]  = v;
      }
    }
  }
}

// ---------------- fused GEMM(N=256) + residual + LayerNorm: x = LN(x + A@W^T + bias)*s + b ----------------
// BM=64, BN=256 (full rows per block). 4 waves as 2x2 (32 rows x 128 cols each).
__global__ __launch_bounds__(256) void k_gemm_ln(
    const ushort* __restrict__ A,      // chunk-local [.., K] bf16
    const int* __restrict__ cntp, const int* __restrict__ cnt,
    const int* __restrict__ xoffp,     // global compact row base
    const ushort* __restrict__ W,      // [256, K] bf16
    const float* __restrict__ bias,
    const float* __restrict__ lns, const float* __restrict__ lnb,
    float* __restrict__ x, ushort* __restrict__ xb, int K)
{
  const int m0 = blockIdx.x*64;
  if (m0 >= *cntp) return;
  __shared__ alignas(16) ushort As[4096];    // [64][64]
  __shared__ alignas(16) ushort Bs[16384];   // [256][64]
  __shared__ float red[2][2][64];            // [wc][{sum,sq}][row]
  const int tid = threadIdx.x;
  const int w = tid >> 6, l = tid & 63;
  const int g = l >> 4, c16 = l & 15;
  const int wr = w >> 1, wc = w & 1;

  f32x4 acc[2][8];
  #pragma unroll
  for (int i=0;i<2;++i)
    #pragma unroll
    for (int j=0;j<8;++j) acc[i][j] = (f32x4){0.f,0.f,0.f,0.f};

  for (int k0=0; k0<K; k0+=64) {
    #pragma unroll
    for (int i=0;i<2;++i) {
      const int li  = i*4096 + tid*16;
      const int row = li >> 7;
      const int col = (li & 127) >> 1;
      const ushort* ga = A + (size_t)(m0+row)*K + k0 + col;
      ushort* la = As + i*2048 + w*512;
      __builtin_amdgcn_global_load_lds((const __attribute__((address_space(1))) unsigned int*)ga,
                                       (__attribute__((address_space(3))) unsigned int*)la, 16, 0, 0);
    }
    #pragma unroll
    for (int i=0;i<8;++i) {
      const int li  = i*4096 + tid*16;
      const int row = li >> 7;
      const int col = (li & 127) >> 1;
      const ushort* gb = W + (size_t)row*K + k0 + col;
      ushort* lb = Bs + i*2048 + w*512;
      __builtin_amdgcn_global_load_lds((const __attribute__((address_space(1))) unsigned int*)gb,
                                       (__attribute__((address_space(3))) unsigned int*)lb, 16, 0, 0);
    }
    __syncthreads();
    #pragma unroll
    for (int ks=0; ks<2; ++ks) {
      bf16x8 af[2], bfr[8];
      #pragma unroll
      for (int mi=0;mi<2;++mi)
        af[mi] = *(const bf16x8*)(As + (size_t)(wr*32 + mi*16 + c16)*64 + g*8 + ks*32);
      #pragma unroll
      for (int ni=0;ni<8;++ni)
        bfr[ni] = *(const bf16x8*)(Bs + (size_t)(wc*128 + ni*16 + c16)*64 + g*8 + ks*32);
      #pragma unroll
      for (int mi=0;mi<2;++mi)
        #pragma unroll
        for (int ni=0;ni<8;++ni)
          acc[mi][ni] = __builtin_amdgcn_mfma_f32_16x16x32_bf16(af[mi], bfr[ni], acc[mi][ni], 0,0,0);
    }
    __syncthreads();
  }

  // ---- epilogue: y = acc + bias + x_resid; LN over 256 cols; write x f32 + xb bf16 ----
  const int xbase = *xoffp + m0;
  float bvs[8], svs[8], bbs[8];
  #pragma unroll
  for (int ni=0;ni<8;++ni) {
    int col = wc*128 + ni*16 + c16;
    bvs[ni] = bias[col]; svs[ni] = lns[col]; bbs[ni] = lnb[col];
  }
  float ps[2][4], pq[2][4];
  #pragma unroll
  for (int mi=0;mi<2;++mi)
    #pragma unroll
    for (int r=0;r<4;++r) { ps[mi][r]=0.f; pq[mi][r]=0.f; }
  #pragma unroll
  for (int mi=0;mi<2;++mi) {
    #pragma unroll
    for (int r=0;r<4;++r) {
      const int lrow = wr*32 + mi*16 + 4*g + r;
      const float* xr = x + (size_t)(xbase + lrow)*256;
      #pragma unroll
      for (int ni=0;ni<8;++ni) {
        float y = acc[mi][ni][r] + bvs[ni] + xr[wc*128 + ni*16 + c16];
        acc[mi][ni][r] = y;
        ps[mi][r] += y;
        pq[mi][r] += y*y;
      }
    }
  }
  #pragma unroll
  for (int mi=0;mi<2;++mi)
    #pragma unroll
    for (int r=0;r<4;++r) {
      #pragma unroll
      for (int off=1; off<16; off<<=1) {
        ps[mi][r] += __shfl_xor(ps[mi][r], off, 16);
        pq[mi][r] += __shfl_xor(pq[mi][r], off, 16);
      }
    }
  if (c16 == 0) {
    #pragma unroll
    for (int mi=0;mi<2;++mi)
      #pragma unroll
      for (int r=0;r<4;++r) {
        const int lrow = wr*32 + mi*16 + 4*g + r;
        red[wc][0][lrow] = ps[mi][r];
        red[wc][1][lrow] = pq[mi][r];
      }
  }
  __syncthreads();
  const int cexact = *cnt;
  #pragma unroll
  for (int mi=0;mi<2;++mi) {
    #pragma unroll
    for (int r=0;r<4;++r) {
      const int lrow = wr*32 + mi*16 + 4*g + r;
      float tsum = red[0][0][lrow] + red[1][0][lrow];
      float tsq  = red[0][1][lrow] + red[1][1][lrow];
      float mean = tsum * (1.f/256.f);
      float var  = tsq * (1.f/256.f) - mean*mean;
      float inv  = rsqrtf(var + 1e-5f);
      if (m0 + lrow < cexact) {
        float* xr = x + (size_t)(xbase + lrow)*256;
        ushort* xbr = xb + (size_t)(xbase + lrow)*256;
        #pragma unroll
        for (int ni=0;ni<8;++ni) {
          int col = wc*128 + ni*16 + c16;
          float o = (acc[mi][ni][r] - mean)*inv*svs[ni] + bbs[ni];
          xr[col] = o;
          xbr[col] = f2b(o);
        }
      }
    }
  }
}

// ---------------- MFMA flash attention on compact rows: block per (b,h) ----------------
__global__ __launch_bounds__(256) void k_attn_mfma(
    const ushort* __restrict__ qkv, ushort* __restrict__ ctx,
    const int* __restrict__ offc)
{
  __shared__ alignas(16) char lds[81920];
  char* Kb = lds;
  char* Vt = lds + 24576;
  const int tid = threadIdx.x;
  const int w = tid >> 6, l = tid & 63;
  const int g = l >> 4, c = l & 15;
  char* Pw = lds + 57344 + w*6144;
  const int bl = blockIdx.x >> 2, h = blockIdx.x & 3;
  const int rowbase = offc[bl] - offc[0];
  const int len = offc[bl+1] - offc[bl];
  const int nkt = (len + 15) >> 4;
  const int nkf = (len + 31) >> 5;
  const ushort* base = qkv + (size_t)rowbase*768;
  ushort* cbase = ctx + (size_t)rowbase*256;

  const int lenk8 = nkt*16*8;
  for (int idx = tid; idx < lenk8; idx += 256) {
    int row = idx >> 3, ch = idx & 7;
    uint4 v = *(const uint4*)(base + (size_t)row*768 + 256 + h*64 + ch*8);
    *(uint4*)(Kb + ((row*128 + ch*16) ^ ((row&7)<<4))) = v;
  }
  {
    const int lenv = nkf*32;
    int d0 = (tid & 15)*4;
    for (int key = tid >> 4; key < lenv; key += 16) {
      ushort4 v = *(const ushort4*)(base + (size_t)key*768 + 512 + h*64 + d0);
      ushort vv[4] = {v.x, v.y, v.z, v.w};
      #pragma unroll
      for (int j=0;j<4;++j) {
        int d = d0 + j;
        *(ushort*)(Vt + ((d*512 + key*2) ^ ((d&7)<<4))) = vv[j];
      }
    }
  }
  __syncthreads();

  for (int t = nkt; t < 2*nkf; ++t) {
    #pragma unroll
    for (int r=0;r<4;++r) {
      int q = 4*g + r;
      *(ushort*)(Pw + (((t>>1)*1024 + q*64 + ((t&1)*16 + c)*2) ^ (((q>>2)&3)<<4))) = 0;
    }
  }

  const int nst = (len + 15) >> 4;
  for (int s = w; s < nst; s += 4) {
    const ushort* qp = base + (size_t)(s*16 + c)*768 + h*64 + g*8;
    bf16x8 aq0 = *(const bf16x8*)qp;
    bf16x8 aq1 = *(const bf16x8*)(qp + 32);

    f32x4 sc[12];
    #pragma unroll
    for (int t=0;t<12;++t) {
      sc[t] = (f32x4){0.f,0.f,0.f,0.f};
      if (t < nkt) {
        int ba0 = ((t*16 + c)*128 + g*16)      ^ ((c&7)<<4);
        int ba1 = ((t*16 + c)*128 + g*16 + 64) ^ ((c&7)<<4);
        bf16x8 k0 = *(const bf16x8*)(Kb + ba0);
        bf16x8 k1 = *(const bf16x8*)(Kb + ba1);
        sc[t] = __builtin_amdgcn_mfma_f32_16x16x32_bf16(aq0, k0, sc[t], 0,0,0);
        sc[t] = __builtin_amdgcn_mfma_f32_16x16x32_bf16(aq1, k1, sc[t], 0,0,0);
        if (t == nkt-1 && t*16 + c >= len)
          sc[t] = (f32x4){-1e30f,-1e30f,-1e30f,-1e30f};
      }
    }
    float mr[4] = {-1e30f,-1e30f,-1e30f,-1e30f};
    #pragma unroll
    for (int t=0;t<12;++t) if (t<nkt) {
      #pragma unroll
      for (int r=0;r<4;++r) mr[r] = fmaxf(mr[r], sc[t][r]);
    }
    #pragma unroll
    for (int r=0;r<4;++r) {
      mr[r] = fmaxf(mr[r], __shfl_xor(mr[r], 1, 16));
      mr[r] = fmaxf(mr[r], __shfl_xor(mr[r], 2, 16));
      mr[r] = fmaxf(mr[r], __shfl_xor(mr[r], 4, 16));
      mr[r] = fmaxf(mr[r], __shfl_xor(mr[r], 8, 16));
    }
    float sr[4] = {0.f,0.f,0.f,0.f};
    #pragma unroll
    for (int t=0;t<12;++t) if (t<nkt) {
      #pragma unroll
      for (int r=0;r<4;++r) {
        float p = __expf((sc[t][r] - mr[r]) * 0.125f);
        sr[r] += p;
        int q = 4*g + r;
        *(ushort*)(Pw + (((t>>1)*1024 + q*64 + ((t&1)*16 + c)*2) ^ (((q>>2)&3)<<4))) = f2b(p);
      }
    }
    #pragma unroll
    for (int r=0;r<4;++r) {
      sr[r] += __shfl_xor(sr[r], 1, 16);
      sr[r] += __shfl_xor(sr[r], 2, 16);
      sr[r] += __shfl_xor(sr[r], 4, 16);
      sr[r] += __shfl_xor(sr[r], 8, 16);
    }
    f32x4 oa[4];
    #pragma unroll
    for (int dt=0;dt<4;++dt) oa[dt] = (f32x4){0.f,0.f,0.f,0.f};
    #pragma unroll
    for (int kf=0;kf<6;++kf) if (kf<nkf) {
      bf16x8 pf = *(const bf16x8*)(Pw + ((kf*1024 + c*64 + g*16) ^ (((c>>2)&3)<<4)));
      #pragma unroll
      for (int dt=0;dt<4;++dt) {
        int d = dt*16 + c;
        bf16x8 vf = *(const bf16x8*)(Vt + ((d*512 + kf*64 + g*16) ^ ((d&7)<<4)));
        oa[dt] = __builtin_amdgcn_mfma_f32_16x16x32_bf16(pf, vf, oa[dt], 0,0,0);
      }
    }
    float inv[4];
    #pragma unroll
    for (int r=0;r<4;++r) inv[r] = 1.f / sr[r];
    ushort* orow = cbase + (size_t)(s*16)*256 + h*64;
    #pragma unroll
    for (int r=0;r<4;++r) {
      int q = 4*g + r;
      if (s*16 + q < len) {
        #pragma unroll
        for (int dt=0;dt<4;++dt)
          orow[(size_t)q*256 + dt*16 + c] = f2b(oa[dt][r] * inv[r]);
      }
    }
  }
}

// ---------------- ragged weighted pooling (compact x) + concat id embeddings ----------------
__global__ __launch_bounds__(256) void k_pool(
    const float* __restrict__ x, const int* __restrict__ off,
    const float* __restrict__ attr_tf, const float* __restrict__ attr_feat,
    const int* __restrict__ lens_u, const int* __restrict__ lens_i,
    const int* __restrict__ user_ids, const int* __restrict__ item_ids,
    const float* __restrict__ user_tab, const float* __restrict__ item_tab,
    const float* __restrict__ feat_w, const float* __restrict__ feat_b,
    float* __restrict__ user_out, float* __restrict__ item_out)
{
  __shared__ float wu[L_], tf[L_];
  const int b = blockIdx.x;
  const int t = threadIdx.x;
  if (t < L_) {
    const float* f = attr_feat + ((size_t)b*L_ + t)*NF_;
    float sacc = feat_b[0];
    #pragma unroll
    for (int j=0;j<NF_;++j) sacc = fmaf(f[j], feat_w[j], sacc);
    wu[t] = 1.f/(1.f+__expf(-sacc));
    tf[t] = attr_tf[b*L_+t];
  }
  __syncthreads();
  const int Lu = lens_u[b], Li = lens_i[b];
  const float* xrow = x + (size_t)off[b]*D_;
  float su=0.f, si=0.f;
  for (int l=0;l<Lu+Li;++l) {
    float val = xrow[(size_t)l*D_ + t] * tf[l];
    if (l < Lu) su = fmaf(val, wu[l], su);
    else        si = fmaf(val, 1.f-wu[l], si);
  }
  user_out[(size_t)b*512 + t]       = su/(float)Lu;
  item_out[(size_t)b*512 + t]       = si/(float)Li;
  user_out[(size_t)b*512 + 256 + t] = user_tab[(size_t)user_ids[b]*D_ + t];
  item_out[(size_t)b*512 + 256 + t] = item_tab[(size_t)item_ids[b]*D_ + t];
}

// ---------------- logits + mask + new_targets ----------------
__global__ __launch_bounds__(256) void k_logits(
    const int* __restrict__ pos_t, const int* __restrict__ neg_t,
    const int* __restrict__ pos_l, const int* __restrict__ neg_l,
    const float* __restrict__ oeu, const float* __restrict__ oei,
    const float* __restrict__ user_out, const float* __restrict__ item_out,
    float* __restrict__ out)
{
  const int g = blockIdx.x*4 + (threadIdx.x >> 6);
  const int lane = threadIdx.x & 63;
  const int b = g / NT_;
  const int k = g - b*NT_;
  const int tid_ = (k < LP_) ? pos_t[b*LP_ + k] : neg_t[b*LNEG_ + (k-LP_)];
  const float* eu = oeu + (size_t)tid_*512;
  const float* ei = oei + (size_t)tid_*512;
  const float* uo = user_out + (size_t)b*512;
  const float* io = item_out + (size_t)b*512;
  const int d0 = lane*8;
  float s = 0.f;
  float4 a0 = *(const float4*)(eu+d0), a1 = *(const float4*)(eu+d0+4);
  float4 u0 = *(const float4*)(uo+d0), u1 = *(const float4*)(uo+d0+4);
  s += a0.x*u0.x + a0.y*u0.y + a0.z*u0.z + a0.w*u0.w;
  s += a1.x*u1.x + a1.y*u1.y + a1.z*u1.z + a1.w*u1.w;
  float4 c0 = *(const float4*)(ei+d0), c1 = *(const float4*)(ei+d0+4);
  float4 i0 = *(const float4*)(io+d0), i1 = *(const float4*)(io+d0+4);
  s += c0.x*i0.x + c0.y*i0.y + c0.z*i0.z + c0.w*i0.w;
  s += c1.x*i1.x + c1.y*i1.y + c1.z*i1.z + c1.w*i1.w;
  #pragma unroll
  for (int off=32; off>0; off>>=1) s += __shfl_xor(s, off, 64);
  if (lane == 0) {
    out[(size_t)b*NT_ + k] = s;
    float mv, nt;
    if (k < LP_) { mv = (k < pos_l[b]) ? 1.f : 0.f; nt = mv; }
    else         { mv = ((k - LP_) < neg_l[b]) ? 1.f : 0.f; nt = 0.f; }
    out[(size_t)B_*NT_   + (size_t)b*NT_ + k] = mv;
    out[(size_t)2*B_*NT_ + (size_t)b*NT_ + k] = nt;
  }
}

extern "C" void kernel_launch(void* const* d_in, const int* in_sizes, int n_in,
                              void* d_out, int out_size, void* d_ws, size_t ws_size,
                              hipStream_t stream)
{
  const int*   attr      = (const int*)d_in[0];
  const int*   attr_inds = (const int*)d_in[1];
  const float* attr_tf   = (const float*)d_in[2];
  const float* attr_feat = (const float*)d_in[3];
  const int*   attr_lens = (const int*)d_in[4];
  const int*   lens_u    = (const int*)d_in[5];
  const int*   lens_i    = (const int*)d_in[6];
  const int*   user_ids  = (const int*)d_in[7];
  const int*   item_ids  = (const int*)d_in[8];
  const int*   pos_t     = (const int*)d_in[9];
  const int*   pos_l     = (const int*)d_in[10];
  const int*   neg_t     = (const int*)d_in[11];
  const int*   neg_l     = (const int*)d_in[12];
  const float* attr_emb  = (const float*)d_in[13];
  const float* ind_emb   = (const float*)d_in[14];
  const float* user_tab  = (const float*)d_in[15];
  const float* item_tab  = (const float*)d_in[16];
  const float* oeu       = (const float*)d_in[17];
  const float* oei       = (const float*)d_in[18];
  const float* feat_w    = (const float*)d_in[19];
  const float* feat_b    = (const float*)d_in[20];
  const float* Wqkv      = (const float*)d_in[21];
  const float* bqkv      = (const float*)d_in[22];
  const float* Wo        = (const float*)d_in[23];
  const float* bo        = (const float*)d_in[24];
  const float* ln1s      = (const float*)d_in[25];
  const float* ln1b      = (const float*)d_in[26];
  const float* W1        = (const float*)d_in[27];
  const float* b1        = (const float*)d_in[28];
  const float* W2        = (const float*)d_in[29];
  const float* b2        = (const float*)d_in[30];
  const float* ln2s      = (const float*)d_in[31];
  const float* ln2b      = (const float*)d_in[32];

  // ---- ws layout: ints[768] | uo[B,512] | io[B,512] | x[M,256]f32 | xb[M,256]bf16 | weights bf16 | chunk scratch ----
  int* ioff  = (int*)d_ws;            // off[513]
  int* ccnt  = ioff + 520;            // per-chunk valid rows [<=64]
  int* ccntp = ccnt + 64;             // 128-padded           [<=64]
  float* ws = (float*)d_ws + 768;
  float* uo = ws;
  float* io = uo + (size_t)B_*512;
  float* x  = io + (size_t)B_*512;
  ushort* xb   = (ushort*)(x + (size_t)M_*D_);
  ushort* wq_b = xb + (size_t)M_*D_;
  ushort* wo_b = wq_b + (size_t)2*768*256;
  ushort* w1_b = wo_b + (size_t)2*256*256;
  ushort* w2_b = w1_b + (size_t)2*1024*256;
  float* scratch = (float*)(w2_b + (size_t)2*256*1024);

  // scratch per chunk: attn phase qkv_b(Mc*384) + ctx_b(Mc*128) = Mc*512 floats;
  //                    FF phase  h_b(Mc*512) aliases both.
  const size_t fixed_floats = 768 + (size_t)B_*1024 + (size_t)M_*D_ + (size_t)M_*(D_/2) + 786432;
  int Bc = 8;
  for (int cand = 512; cand >= 8; cand >>= 1) {
    size_t need = (fixed_floats + (size_t)cand*L_*512) * sizeof(float);
    if (need <= ws_size) { Bc = cand; break; }
  }
  const int nchunks = B_ / Bc;
  const size_t Mc = (size_t)Bc * L_;

  float* out = (float*)d_out;

  k_prefix<<<1, 512, 0, stream>>>(attr_lens, ioff, ccnt, ccntp, Bc, nchunks);
  k_f2b4<<<768, 256, 0, stream>>>(Wqkv, Wo, W1, W2, wq_b, wo_b, w1_b, w2_b);
  k_embed<<<M_*64/256, 256, 0, stream>>>(attr, attr_inds, attr_lens, ioff, attr_emb, ind_emb, x, xb);

  for (int l=0; l<NL_; ++l) {
    const float* bqkv_l = bqkv + (size_t)l*768;
    const float* bo_l   = bo   + (size_t)l*D_;
    const float* b1_l   = b1   + (size_t)l*FF_;
    const float* b2_l   = b2   + (size_t)l*D_;
    for (int c=0; c<nchunks; ++c) {
      const int* offc = ioff + c*Bc;
      const int* cntp = ccntp + c;
      const int* cnt  = ccnt + c;
      ushort* qkv_b = (ushort*)scratch;                 // [Mc,768] bf16
      ushort* ctx_b = (ushort*)(scratch + Mc*384);      // [Mc,256] bf16
      ushort* h_b   = (ushort*)scratch;                 // [Mc,1024] bf16 (FF phase, aliases)

      k_gemm_mfma<1,0><<<dim3(768/128, Mc/128), 256, 0, stream>>>(
          xb, offc, cntp, wq_b + (size_t)l*768*256, bqkv_l, qkv_b, 768, 256);
      k_attn_mfma<<<Bc*H_, 256, 0, stream>>>(qkv_b, ctx_b, offc);
      k_gemm_ln<<<Mc/64, 256, 0, stream>>>(
          ctx_b, cntp, cnt, offc, wo_b + (size_t)l*256*256, bo_l,
          ln1s + (size_t)l*D_, ln1b + (size_t)l*D_, x, xb, 256);
      k_gemm_mfma<1,1><<<dim3(1024/128, Mc/128), 256, 0, stream>>>(
          xb, offc, cntp, w1_b + (size_t)l*1024*256, b1_l, h_b, 1024, 256);
      k_gemm_ln<<<Mc/64, 256, 0, stream>>>(
          h_b, cntp, cnt, offc, w2_b + (size_t)l*256*1024, b2_l,
          ln2s + (size_t)l*D_, ln2b + (size_t)l*D_, x, xb, 1024);
    }
  }
  k_pool<<<B_, 256, 0, stream>>>(x, ioff, attr_tf, attr_feat, lens_u, lens_i, user_ids, item_ids,
                                 user_tab, item_tab, feat_w, feat_b, uo, io);
  k_logits<<<B_*NT_/4, 256, 0, stream>>>(pos_t, neg_t, pos_l, neg_l, oeu, oei, uo, io, out);
}

// Round 7
// 766.770 us; speedup vs baseline: 6.8912x; 1.0658x over previous
//
#include <hip/hip_runtime.h>
#include <hip/hip_bf16.h>
#include <cstdint>
#include <cstddef>

#define B_ 512
#define L_ 192
#define D_ 256
#define H_ 4
#define DH_ 64
#define FF_ 1024
#define NL_ 2
#define LP_ 30
#define LNEG_ 300
#define NF_ 13
#define M_ (B_*L_)   // 98304 tokens
#define NT_ 330      // LP_+LNEG_
#define V_ 30000

typedef __attribute__((ext_vector_type(8))) short bf16x8;
typedef __attribute__((ext_vector_type(4))) float f32x4;

// RNE float -> bf16 bits (finite inputs only)
__device__ __forceinline__ ushort f2b(float f) {
  union { float f; uint32_t u; } v; v.f = f;
  uint32_t u = v.u;
  return (ushort)((u + 0x7FFFu + ((u >> 16) & 1u)) >> 16);
}
__device__ __forceinline__ float b2f(ushort u) {
  union { uint32_t u; float f; } v; v.u = (uint32_t)u << 16; return v.f;
}

// ---------------- prefix sums of lens: off[513], per-chunk counts ----------------
__global__ __launch_bounds__(512) void k_prefix(
    const int* __restrict__ lens, int* __restrict__ off,
    int* __restrict__ ccnt, int* __restrict__ ccntp, int Bc, int nchunks)
{
  const int t = threadIdx.x;
  int s = 0;
  for (int i = 0; i < t; ++i) s += lens[i];
  off[t] = s;
  if (t == 511) off[512] = s + lens[511];
  if (t < nchunks) {
    int s2 = 0;
    const int c0 = t * Bc;
    for (int i = 0; i < Bc; ++i) s2 += lens[c0 + i];
    ccnt[t]  = s2;
    ccntp[t] = (s2 + 127) & ~127;
  }
}

// ---------------- generic fp32 -> bf16 conversion (2048 elems/block) ----------------
__global__ __launch_bounds__(256) void k_f2b(const float* __restrict__ in, ushort* __restrict__ out) {
  const int i = (blockIdx.x*256 + threadIdx.x)*8;
  float4 a = *(const float4*)(in+i);
  float4 b = *(const float4*)(in+i+4);
  ushort4 o1; o1.x=f2b(a.x); o1.y=f2b(a.y); o1.z=f2b(a.z); o1.w=f2b(a.w);
  ushort4 o2; o2.x=f2b(b.x); o2.y=f2b(b.y); o2.z=f2b(b.z); o2.w=f2b(b.w);
  *(ushort4*)(out+i)   = o1;
  *(ushort4*)(out+i+4) = o2;
}

// ---------------- weight conversion, all 4 groups in one launch ----------------
__global__ __launch_bounds__(256) void k_f2b4(
    const float* __restrict__ wq, const float* __restrict__ wo,
    const float* __restrict__ w1, const float* __restrict__ w2,
    ushort* __restrict__ oq, ushort* __restrict__ oo,
    ushort* __restrict__ o1, ushort* __restrict__ o2)
{
  int bb = blockIdx.x;
  const float* in; ushort* out; int base;
  if (bb < 192)      { in = wq; out = oq; base = bb; }
  else if (bb < 256) { in = wo; out = oo; base = bb - 192; }
  else if (bb < 512) { in = w1; out = o1; base = bb - 256; }
  else               { in = w2; out = o2; base = bb - 512; }
  const int i = base*2048 + threadIdx.x*8;
  float4 a = *(const float4*)(in+i);
  float4 b = *(const float4*)(in+i+4);
  ushort4 q1; q1.x=f2b(a.x); q1.y=f2b(a.y); q1.z=f2b(a.z); q1.w=f2b(a.w);
  ushort4 q2; q2.x=f2b(b.x); q2.y=f2b(b.y); q2.z=f2b(b.z); q2.w=f2b(b.w);
  *(ushort4*)(out+i)   = q1;
  *(ushort4*)(out+i+4) = q2;
}

// ---------------- embedding gather into COMPACT token space (bf16 state only) ----------------
__global__ __launch_bounds__(256) void k_embed(
    const int* __restrict__ attr, const int* __restrict__ inds,
    const int* __restrict__ lens, const int* __restrict__ off,
    const float* __restrict__ attr_emb, const float* __restrict__ ind_emb,
    ushort* __restrict__ xb)
{
  int idx = blockIdx.x*256 + threadIdx.x;
  int token = idx >> 6;
  int c = (idx & 63) * 4;
  int b = token / L_;
  int l = token - b*L_;
  if (l >= lens[b]) return;
  size_t crow = (size_t)off[b] + l;
  int a = attr[token];
  int id = inds[token];
  const float4 e  = *(const float4*)(attr_emb + (size_t)a*D_ + c);
  const float4 ie = *(const float4*)(ind_emb  + (size_t)id*D_ + c);
  ushort4 ob; ob.x=f2b(e.x+ie.x); ob.y=f2b(e.y+ie.y); ob.z=f2b(e.z+ie.z); ob.w=f2b(e.w+ie.w);
  *(ushort4*)(xb + crow*D_ + c) = ob;
}

// ---------------- bf16 MFMA GEMM (128x128): C = A[aoff..] @ W^T + bias ----------------
template<int OUT_BF16, int RELU>
__global__ __launch_bounds__(256) void k_gemm_mfma(
    const ushort* __restrict__ A, const int* __restrict__ aoffp,
    const int* __restrict__ cntp,
    const ushort* __restrict__ W, const float* __restrict__ bias,
    void* __restrict__ Cv, int N, int K)
{
  if ((int)blockIdx.y * 128 >= *cntp) return;
  __shared__ alignas(16) ushort As[8192];
  __shared__ alignas(16) ushort Bs[8192];
  const int abase = *aoffp;
  const int tid = threadIdx.x;
  const int w = tid >> 6, l = tid & 63;
  const int m0 = blockIdx.y*128, n0 = blockIdx.x*128;
  const int wr = w >> 1, wc = w & 1;

  f32x4 acc[4][4];
  #pragma unroll
  for (int i=0;i<4;++i)
    #pragma unroll
    for (int j=0;j<4;++j) acc[i][j] = (f32x4){0.f,0.f,0.f,0.f};

  for (int k0=0; k0<K; k0+=64) {
    #pragma unroll
    for (int i=0;i<4;++i) {
      const int li  = i*4096 + tid*16;
      const int row = li >> 7;
      const int col = (li & 127) >> 1;
      const ushort* ga = A + (size_t)(abase+m0+row)*K + k0 + col;
      const ushort* gb = W + (size_t)(n0+row)*K + k0 + col;
      ushort* la = As + i*2048 + w*512;
      ushort* lb = Bs + i*2048 + w*512;
      __builtin_amdgcn_global_load_lds((const __attribute__((address_space(1))) unsigned int*)ga,
                                       (__attribute__((address_space(3))) unsigned int*)la, 16, 0, 0);
      __builtin_amdgcn_global_load_lds((const __attribute__((address_space(1))) unsigned int*)gb,
                                       (__attribute__((address_space(3))) unsigned int*)lb, 16, 0, 0);
    }
    __syncthreads();
    #pragma unroll
    for (int ks=0; ks<2; ++ks) {
      bf16x8 af[4], bfr[4];
      #pragma unroll
      for (int i2=0;i2<4;++i2) {
        af[i2]  = *(const bf16x8*)(As + (size_t)(wr*64 + i2*16 + (l&15))*64 + (l>>4)*8 + ks*32);
        bfr[i2] = *(const bf16x8*)(Bs + (size_t)(wc*64 + i2*16 + (l&15))*64 + (l>>4)*8 + ks*32);
      }
      #pragma unroll
      for (int mi=0;mi<4;++mi)
        #pragma unroll
        for (int ni=0;ni<4;++ni)
          acc[mi][ni] = __builtin_amdgcn_mfma_f32_16x16x32_bf16(af[mi], bfr[ni], acc[mi][ni], 0,0,0);
    }
    __syncthreads();
  }
  const int col0 = n0 + wc*64 + (l&15);
  const int row0 = m0 + wr*64 + ((l>>4)<<2);
  #pragma unroll
  for (int ni=0;ni<4;++ni) {
    const float bv = bias[col0 + ni*16];
    #pragma unroll
    for (int mi=0;mi<4;++mi) {
      #pragma unroll
      for (int r=0;r<4;++r) {
        float v = acc[mi][ni][r] + bv;
        if (RELU) v = fmaxf(v, 0.f);
        const size_t idx = (size_t)(row0 + mi*16 + r)*N + col0 + ni*16;
        if (OUT_BF16) ((ushort*)Cv)[idx] = f2b(v);
        else          ((float*)Cv)[idx]  = v;
      }
    }
  }
}

// ---------------- fused GEMM(N=256) + residual + LN, bf16 state: xb = LN(xb + A@W^T + bias)*s + b ----------------
// BM=128, BN=256, 512 threads = 8 waves as 2x4 (each 64 rows x 64 cols).
__global__ __launch_bounds__(512) void k_gemm_ln(
    const ushort* __restrict__ A,      // chunk-local [.., K] bf16
    const int* __restrict__ cntp, const int* __restrict__ cnt,
    const int* __restrict__ xoffp,     // global compact row base
    const ushort* __restrict__ W,      // [256, K] bf16
    const float* __restrict__ bias,
    const float* __restrict__ lns, const float* __restrict__ lnb,
    ushort* __restrict__ xb, int K)
{
  const int m0 = blockIdx.x*128;
  if (m0 >= *cntp) return;
  __shared__ alignas(16) ushort As[8192];    // [128][64]
  __shared__ alignas(16) ushort Bs[16384];   // [256][64]
  __shared__ float red[4][2][128];           // [wc][{sum,sq}][local row]
  const int tid = threadIdx.x;
  const int w = tid >> 6, l = tid & 63;
  const int g = l >> 4, c16 = l & 15;
  const int wr = w >> 2, wc = w & 3;

  f32x4 acc[4][4];
  #pragma unroll
  for (int i=0;i<4;++i)
    #pragma unroll
    for (int j=0;j<4;++j) acc[i][j] = (f32x4){0.f,0.f,0.f,0.f};

  for (int k0=0; k0<K; k0+=64) {
    #pragma unroll
    for (int i=0;i<2;++i) {          // stage As: 16 KB over 512 threads x 16 B = 2 rounds
      const int li  = i*8192 + tid*16;
      const int row = li >> 7;
      const int col = (li & 127) >> 1;
      const ushort* ga = A + (size_t)(m0+row)*K + k0 + col;
      ushort* la = As + i*4096 + w*512;
      __builtin_amdgcn_global_load_lds((const __attribute__((address_space(1))) unsigned int*)ga,
                                       (__attribute__((address_space(3))) unsigned int*)la, 16, 0, 0);
    }
    #pragma unroll
    for (int i=0;i<4;++i) {          // stage Bs: 32 KB = 4 rounds
      const int li  = i*8192 + tid*16;
      const int row = li >> 7;
      const int col = (li & 127) >> 1;
      const ushort* gb = W + (size_t)row*K + k0 + col;
      ushort* lb = Bs + i*4096 + w*512;
      __builtin_amdgcn_global_load_lds((const __attribute__((address_space(1))) unsigned int*)gb,
                                       (__attribute__((address_space(3))) unsigned int*)lb, 16, 0, 0);
    }
    __syncthreads();
    #pragma unroll
    for (int ks=0; ks<2; ++ks) {
      bf16x8 af[4], bfr[4];
      #pragma unroll
      for (int i2=0;i2<4;++i2) {
        af[i2]  = *(const bf16x8*)(As + (size_t)(wr*64 + i2*16 + c16)*64 + g*8 + ks*32);
        bfr[i2] = *(const bf16x8*)(Bs + (size_t)(wc*64 + i2*16 + c16)*64 + g*8 + ks*32);
      }
      #pragma unroll
      for (int mi=0;mi<4;++mi)
        #pragma unroll
        for (int ni=0;ni<4;++ni)
          acc[mi][ni] = __builtin_amdgcn_mfma_f32_16x16x32_bf16(af[mi], bfr[ni], acc[mi][ni], 0,0,0);
    }
    __syncthreads();
  }

  // ---- epilogue: y = acc + bias + resid(bf16); LN over 256 cols; write xb ----
  const int xbase = *xoffp + m0;
  float bvs[4], svs[4], bbs[4];
  #pragma unroll
  for (int ni=0;ni<4;++ni) {
    int col = wc*64 + ni*16 + c16;
    bvs[ni] = bias[col]; svs[ni] = lns[col]; bbs[ni] = lnb[col];
  }
  float ps[4][4], pq[4][4];
  #pragma unroll
  for (int mi=0;mi<4;++mi) {
    #pragma unroll
    for (int r=0;r<4;++r) {
      ps[mi][r]=0.f; pq[mi][r]=0.f;
      const int lrow = wr*64 + mi*16 + 4*g + r;
      const ushort* xr = xb + (size_t)(xbase + lrow)*256;
      #pragma unroll
      for (int ni=0;ni<4;++ni) {
        float y = acc[mi][ni][r] + bvs[ni] + b2f(xr[wc*64 + ni*16 + c16]);
        acc[mi][ni][r] = y;
        ps[mi][r] += y;
        pq[mi][r] += y*y;
      }
    }
  }
  #pragma unroll
  for (int mi=0;mi<4;++mi)
    #pragma unroll
    for (int r=0;r<4;++r) {
      #pragma unroll
      for (int off=1; off<16; off<<=1) {
        ps[mi][r] += __shfl_xor(ps[mi][r], off, 16);
        pq[mi][r] += __shfl_xor(pq[mi][r], off, 16);
      }
    }
  if (c16 == 0) {
    #pragma unroll
    for (int mi=0;mi<4;++mi)
      #pragma unroll
      for (int r=0;r<4;++r) {
        const int lrow = wr*64 + mi*16 + 4*g + r;
        red[wc][0][lrow] = ps[mi][r];
        red[wc][1][lrow] = pq[mi][r];
      }
  }
  __syncthreads();
  const int cexact = *cnt;
  #pragma unroll
  for (int mi=0;mi<4;++mi) {
    #pragma unroll
    for (int r=0;r<4;++r) {
      const int lrow = wr*64 + mi*16 + 4*g + r;
      float tsum = red[0][0][lrow] + red[1][0][lrow] + red[2][0][lrow] + red[3][0][lrow];
      float tsq  = red[0][1][lrow] + red[1][1][lrow] + red[2][1][lrow] + red[3][1][lrow];
      float mean = tsum * (1.f/256.f);
      float var  = tsq * (1.f/256.f) - mean*mean;
      float inv  = rsqrtf(var + 1e-5f);
      if (m0 + lrow < cexact) {
        ushort* xbr = xb + (size_t)(xbase + lrow)*256;
        #pragma unroll
        for (int ni=0;ni<4;++ni) {
          int col = wc*64 + ni*16 + c16;
          xbr[col] = f2b((acc[mi][ni][r] - mean)*inv*svs[ni] + bbs[ni]);
        }
      }
    }
  }
}

// ---------------- MFMA flash attention on compact rows: block per (b,h) ----------------
__global__ __launch_bounds__(256) void k_attn_mfma(
    const ushort* __restrict__ qkv, ushort* __restrict__ ctx,
    const int* __restrict__ offc)
{
  __shared__ alignas(16) char lds[81920];
  char* Kb = lds;
  char* Vt = lds + 24576;
  const int tid = threadIdx.x;
  const int w = tid >> 6, l = tid & 63;
  const int g = l >> 4, c = l & 15;
  char* Pw = lds + 57344 + w*6144;
  const int bl = blockIdx.x >> 2, h = blockIdx.x & 3;
  const int rowbase = offc[bl] - offc[0];
  const int len = offc[bl+1] - offc[bl];
  const int nkt = (len + 15) >> 4;
  const int nkf = (len + 31) >> 5;
  const ushort* base = qkv + (size_t)rowbase*768;
  ushort* cbase = ctx + (size_t)rowbase*256;

  const int lenk8 = nkt*16*8;
  for (int idx = tid; idx < lenk8; idx += 256) {
    int row = idx >> 3, ch = idx & 7;
    uint4 v = *(const uint4*)(base + (size_t)row*768 + 256 + h*64 + ch*8);
    *(uint4*)(Kb + ((row*128 + ch*16) ^ ((row&7)<<4))) = v;
  }
  {
    const int lenv = nkf*32;
    int d0 = (tid & 15)*4;
    for (int key = tid >> 4; key < lenv; key += 16) {
      ushort4 v = *(const ushort4*)(base + (size_t)key*768 + 512 + h*64 + d0);
      ushort vv[4] = {v.x, v.y, v.z, v.w};
      #pragma unroll
      for (int j=0;j<4;++j) {
        int d = d0 + j;
        *(ushort*)(Vt + ((d*512 + key*2) ^ ((d&7)<<4))) = vv[j];
      }
    }
  }
  __syncthreads();

  for (int t = nkt; t < 2*nkf; ++t) {
    #pragma unroll
    for (int r=0;r<4;++r) {
      int q = 4*g + r;
      *(ushort*)(Pw + (((t>>1)*1024 + q*64 + ((t&1)*16 + c)*2) ^ (((q>>2)&3)<<4))) = 0;
    }
  }

  const int nst = (len + 15) >> 4;
  for (int s = w; s < nst; s += 4) {
    const ushort* qp = base + (size_t)(s*16 + c)*768 + h*64 + g*8;
    bf16x8 aq0 = *(const bf16x8*)qp;
    bf16x8 aq1 = *(const bf16x8*)(qp + 32);

    f32x4 sc[12];
    #pragma unroll
    for (int t=0;t<12;++t) {
      sc[t] = (f32x4){0.f,0.f,0.f,0.f};
      if (t < nkt) {
        int ba0 = ((t*16 + c)*128 + g*16)      ^ ((c&7)<<4);
        int ba1 = ((t*16 + c)*128 + g*16 + 64) ^ ((c&7)<<4);
        bf16x8 k0 = *(const bf16x8*)(Kb + ba0);
        bf16x8 k1 = *(const bf16x8*)(Kb + ba1);
        sc[t] = __builtin_amdgcn_mfma_f32_16x16x32_bf16(aq0, k0, sc[t], 0,0,0);
        sc[t] = __builtin_amdgcn_mfma_f32_16x16x32_bf16(aq1, k1, sc[t], 0,0,0);
        if (t == nkt-1 && t*16 + c >= len)
          sc[t] = (f32x4){-1e30f,-1e30f,-1e30f,-1e30f};
      }
    }
    float mr[4] = {-1e30f,-1e30f,-1e30f,-1e30f};
    #pragma unroll
    for (int t=0;t<12;++t) if (t<nkt) {
      #pragma unroll
      for (int r=0;r<4;++r) mr[r] = fmaxf(mr[r], sc[t][r]);
    }
    #pragma unroll
    for (int r=0;r<4;++r) {
      mr[r] = fmaxf(mr[r], __shfl_xor(mr[r], 1, 16));
      mr[r] = fmaxf(mr[r], __shfl_xor(mr[r], 2, 16));
      mr[r] = fmaxf(mr[r], __shfl_xor(mr[r], 4, 16));
      mr[r] = fmaxf(mr[r], __shfl_xor(mr[r], 8, 16));
    }
    float sr[4] = {0.f,0.f,0.f,0.f};
    #pragma unroll
    for (int t=0;t<12;++t) if (t<nkt) {
      #pragma unroll
      for (int r=0;r<4;++r) {
        float p = __expf((sc[t][r] - mr[r]) * 0.125f);
        sr[r] += p;
        int q = 4*g + r;
        *(ushort*)(Pw + (((t>>1)*1024 + q*64 + ((t&1)*16 + c)*2) ^ (((q>>2)&3)<<4))) = f2b(p);
      }
    }
    #pragma unroll
    for (int r=0;r<4;++r) {
      sr[r] += __shfl_xor(sr[r], 1, 16);
      sr[r] += __shfl_xor(sr[r], 2, 16);
      sr[r] += __shfl_xor(sr[r], 4, 16);
      sr[r] += __shfl_xor(sr[r], 8, 16);
    }
    f32x4 oa[4];
    #pragma unroll
    for (int dt=0;dt<4;++dt) oa[dt] = (f32x4){0.f,0.f,0.f,0.f};
    #pragma unroll
    for (int kf=0;kf<6;++kf) if (kf<nkf) {
      bf16x8 pf = *(const bf16x8*)(Pw + ((kf*1024 + c*64 + g*16) ^ (((c>>2)&3)<<4)));
      #pragma unroll
      for (int dt=0;dt<4;++dt) {
        int d = dt*16 + c;
        bf16x8 vf = *(const bf16x8*)(Vt + ((d*512 + kf*64 + g*16) ^ ((d&7)<<4)));
        oa[dt] = __builtin_amdgcn_mfma_f32_16x16x32_bf16(pf, vf, oa[dt], 0,0,0);
      }
    }
    float inv[4];
    #pragma unroll
    for (int r=0;r<4;++r) inv[r] = 1.f / sr[r];
    ushort* orow = cbase + (size_t)(s*16)*256 + h*64;
    #pragma unroll
    for (int r=0;r<4;++r) {
      int q = 4*g + r;
      if (s*16 + q < len) {
        #pragma unroll
        for (int dt=0;dt<4;++dt)
          orow[(size_t)q*256 + dt*16 + c] = f2b(oa[dt][r] * inv[r]);
      }
    }
  }
}

// ---------------- ragged weighted pooling (compact bf16 x) + concat id embeddings ----------------
__global__ __launch_bounds__(256) void k_pool(
    const ushort* __restrict__ xb, const int* __restrict__ off,
    const float* __restrict__ attr_tf, const float* __restrict__ attr_feat,
    const int* __restrict__ lens_u, const int* __restrict__ lens_i,
    const int* __restrict__ user_ids, const int* __restrict__ item_ids,
    const float* __restrict__ user_tab, const float* __restrict__ item_tab,
    const float* __restrict__ feat_w, const float* __restrict__ feat_b,
    float* __restrict__ user_out, float* __restrict__ item_out)
{
  __shared__ float wu[L_], tf[L_];
  const int b = blockIdx.x;
  const int t = threadIdx.x;
  if (t < L_) {
    const float* f = attr_feat + ((size_t)b*L_ + t)*NF_;
    float sacc = feat_b[0];
    #pragma unroll
    for (int j=0;j<NF_;++j) sacc = fmaf(f[j], feat_w[j], sacc);
    wu[t] = 1.f/(1.f+__expf(-sacc));
    tf[t] = attr_tf[b*L_+t];
  }
  __syncthreads();
  const int Lu = lens_u[b], Li = lens_i[b];
  const ushort* xrow = xb + (size_t)off[b]*D_;
  float su=0.f, si=0.f;
  for (int l=0;l<Lu+Li;++l) {
    float val = b2f(xrow[(size_t)l*D_ + t]) * tf[l];
    if (l < Lu) su = fmaf(val, wu[l], su);
    else        si = fmaf(val, 1.f-wu[l], si);
  }
  user_out[(size_t)b*512 + t]       = su/(float)Lu;
  item_out[(size_t)b*512 + t]       = si/(float)Li;
  user_out[(size_t)b*512 + 256 + t] = user_tab[(size_t)user_ids[b]*D_ + t];
  item_out[(size_t)b*512 + 256 + t] = item_tab[(size_t)item_ids[b]*D_ + t];
}

// ---------------- logits + mask + new_targets (bf16 tables) ----------------
__global__ __launch_bounds__(256) void k_logits(
    const int* __restrict__ pos_t, const int* __restrict__ neg_t,
    const int* __restrict__ pos_l, const int* __restrict__ neg_l,
    const ushort* __restrict__ oeu, const ushort* __restrict__ oei,
    const float* __restrict__ user_out, const float* __restrict__ item_out,
    float* __restrict__ out)
{
  const int g = blockIdx.x*4 + (threadIdx.x >> 6);
  const int lane = threadIdx.x & 63;
  const int b = g / NT_;
  const int k = g - b*NT_;
  const int tid_ = (k < LP_) ? pos_t[b*LP_ + k] : neg_t[b*LNEG_ + (k-LP_)];
  const ushort* eu = oeu + (size_t)tid_*512;
  const ushort* ei = oei + (size_t)tid_*512;
  const float* uo = user_out + (size_t)b*512;
  const float* io = item_out + (size_t)b*512;
  const int d0 = lane*8;
  float s = 0.f;
  ushort4 a0 = *(const ushort4*)(eu+d0), a1 = *(const ushort4*)(eu+d0+4);
  float4 u0 = *(const float4*)(uo+d0), u1 = *(const float4*)(uo+d0+4);
  s += b2f(a0.x)*u0.x + b2f(a0.y)*u0.y + b2f(a0.z)*u0.z + b2f(a0.w)*u0.w;
  s += b2f(a1.x)*u1.x + b2f(a1.y)*u1.y + b2f(a1.z)*u1.z + b2f(a1.w)*u1.w;
  ushort4 c0 = *(const ushort4*)(ei+d0), c1 = *(const ushort4*)(ei+d0+4);
  float4 i0 = *(const float4*)(io+d0), i1 = *(const float4*)(io+d0+4);
  s += b2f(c0.x)*i0.x + b2f(c0.y)*i0.y + b2f(c0.z)*i0.z + b2f(c0.w)*i0.w;
  s += b2f(c1.x)*i1.x + b2f(c1.y)*i1.y + b2f(c1.z)*i1.z + b2f(c1.w)*i1.w;
  #pragma unroll
  for (int off=32; off>0; off>>=1) s += __shfl_xor(s, off, 64);
  if (lane == 0) {
    out[(size_t)b*NT_ + k] = s;
    float mv, nt;
    if (k < LP_) { mv = (k < pos_l[b]) ? 1.f : 0.f; nt = mv; }
    else         { mv = ((k - LP_) < neg_l[b]) ? 1.f : 0.f; nt = 0.f; }
    out[(size_t)B_*NT_   + (size_t)b*NT_ + k] = mv;
    out[(size_t)2*B_*NT_ + (size_t)b*NT_ + k] = nt;
  }
}

extern "C" void kernel_launch(void* const* d_in, const int* in_sizes, int n_in,
                              void* d_out, int out_size, void* d_ws, size_t ws_size,
                              hipStream_t stream)
{
  const int*   attr      = (const int*)d_in[0];
  const int*   attr_inds = (const int*)d_in[1];
  const float* attr_tf   = (const float*)d_in[2];
  const float* attr_feat = (const float*)d_in[3];
  const int*   attr_lens = (const int*)d_in[4];
  const int*   lens_u    = (const int*)d_in[5];
  const int*   lens_i    = (const int*)d_in[6];
  const int*   user_ids  = (const int*)d_in[7];
  const int*   item_ids  = (const int*)d_in[8];
  const int*   pos_t     = (const int*)d_in[9];
  const int*   pos_l     = (const int*)d_in[10];
  const int*   neg_t     = (const int*)d_in[11];
  const int*   neg_l     = (const int*)d_in[12];
  const float* attr_emb  = (const float*)d_in[13];
  const float* ind_emb   = (const float*)d_in[14];
  const float* user_tab  = (const float*)d_in[15];
  const float* item_tab  = (const float*)d_in[16];
  const float* oeu       = (const float*)d_in[17];
  const float* oei       = (const float*)d_in[18];
  const float* feat_w    = (const float*)d_in[19];
  const float* feat_b    = (const float*)d_in[20];
  const float* Wqkv      = (const float*)d_in[21];
  const float* bqkv      = (const float*)d_in[22];
  const float* Wo        = (const float*)d_in[23];
  const float* bo        = (const float*)d_in[24];
  const float* ln1s      = (const float*)d_in[25];
  const float* ln1b      = (const float*)d_in[26];
  const float* W1        = (const float*)d_in[27];
  const float* b1        = (const float*)d_in[28];
  const float* W2        = (const float*)d_in[29];
  const float* b2        = (const float*)d_in[30];
  const float* ln2s      = (const float*)d_in[31];
  const float* ln2b      = (const float*)d_in[32];

  // ---- ws layout: ints[768] | uo[B,512]f32 | io[B,512]f32 | xb[M,256]bf16 | weights bf16 | oeu_b | oei_b | chunk scratch ----
  int* ioff  = (int*)d_ws;            // off[513]
  int* ccnt  = ioff + 520;
  int* ccntp = ccnt + 64;
  float* ws = (float*)d_ws + 768;
  float* uo = ws;
  float* io = uo + (size_t)B_*512;
  ushort* xb   = (ushort*)(io + (size_t)B_*512);
  ushort* wq_b = xb + (size_t)M_*D_;
  ushort* wo_b = wq_b + (size_t)2*768*256;
  ushort* w1_b = wo_b + (size_t)2*256*256;
  ushort* w2_b = w1_b + (size_t)2*1024*256;
  ushort* oeu_b = w2_b + (size_t)2*256*1024;
  ushort* oei_b = oeu_b + (size_t)V_*512;
  float* scratch = (float*)(oei_b + (size_t)V_*512);

  // scratch per chunk: qkv_b(Mc*384 f32-equiv) + ctx_b(Mc*128) = Mc*512 floats; FF h_b aliases.
  const size_t fixed_floats = 768 + (size_t)B_*1024 + (size_t)M_*(D_/2) + 786432 + (size_t)V_*512;
  int Bc = 8;
  for (int cand = 512; cand >= 8; cand >>= 1) {
    size_t need = (fixed_floats + (size_t)cand*L_*512) * sizeof(float);
    if (need <= ws_size) { Bc = cand; break; }
  }
  const int nchunks = B_ / Bc;
  const size_t Mc = (size_t)Bc * L_;

  float* out = (float*)d_out;

  k_prefix<<<1, 512, 0, stream>>>(attr_lens, ioff, ccnt, ccntp, Bc, nchunks);
  k_f2b4<<<768, 256, 0, stream>>>(Wqkv, Wo, W1, W2, wq_b, wo_b, w1_b, w2_b);
  k_f2b<<<(V_*512)/2048, 256, 0, stream>>>(oeu, oeu_b);
  k_f2b<<<(V_*512)/2048, 256, 0, stream>>>(oei, oei_b);
  k_embed<<<M_*64/256, 256, 0, stream>>>(attr, attr_inds, attr_lens, ioff, attr_emb, ind_emb, xb);

  for (int l=0; l<NL_; ++l) {
    const float* bqkv_l = bqkv + (size_t)l*768;
    const float* bo_l   = bo   + (size_t)l*D_;
    const float* b1_l   = b1   + (size_t)l*FF_;
    const float* b2_l   = b2   + (size_t)l*D_;
    for (int c=0; c<nchunks; ++c) {
      const int* offc = ioff + c*Bc;
      const int* cntp = ccntp + c;
      const int* cnt  = ccnt + c;
      ushort* qkv_b = (ushort*)scratch;                 // [Mc,768] bf16
      ushort* ctx_b = (ushort*)(scratch + Mc*384);      // [Mc,256] bf16
      ushort* h_b   = (ushort*)scratch;                 // [Mc,1024] bf16 (FF phase, aliases)

      k_gemm_mfma<1,0><<<dim3(768/128, Mc/128), 256, 0, stream>>>(
          xb, offc, cntp, wq_b + (size_t)l*768*256, bqkv_l, qkv_b, 768, 256);
      k_attn_mfma<<<Bc*H_, 256, 0, stream>>>(qkv_b, ctx_b, offc);
      k_gemm_ln<<<Mc/128, 512, 0, stream>>>(
          ctx_b, cntp, cnt, offc, wo_b + (size_t)l*256*256, bo_l,
          ln1s + (size_t)l*D_, ln1b + (size_t)l*D_, xb, 256);
      k_gemm_mfma<1,1><<<dim3(1024/128, Mc/128), 256, 0, stream>>>(
          xb, offc, cntp, w1_b + (size_t)l*1024*256, b1_l, h_b, 1024, 256);
      k_gemm_ln<<<Mc/128, 512, 0, stream>>>(
          h_b, cntp, cnt, offc, w2_b + (size_t)l*256*1024, b2_l,
          ln2s + (size_t)l*D_, ln2b + (size_t)l*D_, xb, 1024);
    }
  }
  k_pool<<<B_, 256, 0, stream>>>(xb, ioff, attr_tf, attr_feat, lens_u, lens_i, user_ids, item_ids,
                                 user_tab, item_tab, feat_w, feat_b, uo, io);
  k_logits<<<B_*NT_/4, 256, 0, stream>>>(pos_t, neg_t, pos_l, neg_l, oeu_b, oei_b, uo, io, out);
}

// Round 8
// 714.846 us; speedup vs baseline: 7.3917x; 1.0726x over previous
//
#include <hip/hip_runtime.h>
#include <hip/hip_bf16.h>
#include <cstdint>
#include <cstddef>

#define B_ 512
#define L_ 192
#define D_ 256
#define H_ 4
#define DH_ 64
#define FF_ 1024
#define NL_ 2
#define LP_ 30
#define LNEG_ 300
#define NF_ 13
#define M_ (B_*L_)   // 98304 tokens
#define NT_ 330      // LP_+LNEG_
#define V_ 30000

typedef __attribute__((ext_vector_type(8))) short bf16x8;
typedef __attribute__((ext_vector_type(4))) float f32x4;

// RNE float -> bf16 bits (finite inputs only)
__device__ __forceinline__ ushort f2b(float f) {
  union { float f; uint32_t u; } v; v.f = f;
  uint32_t u = v.u;
  return (ushort)((u + 0x7FFFu + ((u >> 16) & 1u)) >> 16);
}
__device__ __forceinline__ float b2f(ushort u) {
  union { uint32_t u; float f; } v; v.u = (uint32_t)u << 16; return v.f;
}

// ---------------- prefix sums of lens: off[513], per-chunk counts ----------------
__global__ __launch_bounds__(512) void k_prefix(
    const int* __restrict__ lens, int* __restrict__ off,
    int* __restrict__ ccnt, int* __restrict__ ccntp, int Bc, int nchunks)
{
  const int t = threadIdx.x;
  int s = 0;
  for (int i = 0; i < t; ++i) s += lens[i];
  off[t] = s;
  if (t == 511) off[512] = s + lens[511];
  if (t < nchunks) {
    int s2 = 0;
    const int c0 = t * Bc;
    for (int i = 0; i < Bc; ++i) s2 += lens[c0 + i];
    ccnt[t]  = s2;
    ccntp[t] = (s2 + 127) & ~127;
  }
}

// ---------------- generic fp32 -> bf16 conversion (2048 elems/block) ----------------
__global__ __launch_bounds__(256) void k_f2b(const float* __restrict__ in, ushort* __restrict__ out) {
  const int i = (blockIdx.x*256 + threadIdx.x)*8;
  float4 a = *(const float4*)(in+i);
  float4 b = *(const float4*)(in+i+4);
  ushort4 o1; o1.x=f2b(a.x); o1.y=f2b(a.y); o1.z=f2b(a.z); o1.w=f2b(a.w);
  ushort4 o2; o2.x=f2b(b.x); o2.y=f2b(b.y); o2.z=f2b(b.z); o2.w=f2b(b.w);
  *(ushort4*)(out+i)   = o1;
  *(ushort4*)(out+i+4) = o2;
}

// ---------------- weight conversion, all 4 groups in one launch ----------------
__global__ __launch_bounds__(256) void k_f2b4(
    const float* __restrict__ wq, const float* __restrict__ wo,
    const float* __restrict__ w1, const float* __restrict__ w2,
    ushort* __restrict__ oq, ushort* __restrict__ oo,
    ushort* __restrict__ o1, ushort* __restrict__ o2)
{
  int bb = blockIdx.x;
  const float* in; ushort* out; int base;
  if (bb < 192)      { in = wq; out = oq; base = bb; }
  else if (bb < 256) { in = wo; out = oo; base = bb - 192; }
  else if (bb < 512) { in = w1; out = o1; base = bb - 256; }
  else               { in = w2; out = o2; base = bb - 512; }
  const int i = base*2048 + threadIdx.x*8;
  float4 a = *(const float4*)(in+i);
  float4 b = *(const float4*)(in+i+4);
  ushort4 q1; q1.x=f2b(a.x); q1.y=f2b(a.y); q1.z=f2b(a.z); q1.w=f2b(a.w);
  ushort4 q2; q2.x=f2b(b.x); q2.y=f2b(b.y); q2.z=f2b(b.z); q2.w=f2b(b.w);
  *(ushort4*)(out+i)   = q1;
  *(ushort4*)(out+i+4) = q2;
}

// ---------------- embedding gather into COMPACT token space (bf16 state only) ----------------
__global__ __launch_bounds__(256) void k_embed(
    const int* __restrict__ attr, const int* __restrict__ inds,
    const int* __restrict__ lens, const int* __restrict__ off,
    const float* __restrict__ attr_emb, const float* __restrict__ ind_emb,
    ushort* __restrict__ xb)
{
  int idx = blockIdx.x*256 + threadIdx.x;
  int token = idx >> 6;
  int c = (idx & 63) * 4;
  int b = token / L_;
  int l = token - b*L_;
  if (l >= lens[b]) return;
  size_t crow = (size_t)off[b] + l;
  int a = attr[token];
  int id = inds[token];
  const float4 e  = *(const float4*)(attr_emb + (size_t)a*D_ + c);
  const float4 ie = *(const float4*)(ind_emb  + (size_t)id*D_ + c);
  ushort4 ob; ob.x=f2b(e.x+ie.x); ob.y=f2b(e.y+ie.y); ob.z=f2b(e.z+ie.z); ob.w=f2b(e.w+ie.w);
  *(ushort4*)(xb + crow*D_ + c) = ob;
}

// ---------------- bf16 MFMA GEMM (128x128), T2-swizzled LDS: C = A[aoff..] @ W^T + bias ----------------
// LDS tiles [128 rows][128 B]; byte col XOR'd with (row&7)<<4 (pre-swizzled global src, linear dest).
template<int OUT_BF16, int RELU>
__global__ __launch_bounds__(256) void k_gemm_mfma(
    const ushort* __restrict__ A, const int* __restrict__ aoffp,
    const int* __restrict__ cntp,
    const ushort* __restrict__ W, const float* __restrict__ bias,
    void* __restrict__ Cv, int N, int K)
{
  if ((int)blockIdx.y * 128 >= *cntp) return;
  __shared__ alignas(16) ushort As[8192];
  __shared__ alignas(16) ushort Bs[8192];
  const int abase = *aoffp;
  const int tid = threadIdx.x;
  const int w = tid >> 6, l = tid & 63;
  const int g = l >> 4, c16 = l & 15;
  const int m0 = blockIdx.y*128, n0 = blockIdx.x*128;
  const int wr = w >> 1, wc = w & 1;
  const int swzr = (c16 & 7) << 4;            // fragment-read XOR (row&7 == c16&7)

  f32x4 acc[4][4];
  #pragma unroll
  for (int i=0;i<4;++i)
    #pragma unroll
    for (int j=0;j<4;++j) acc[i][j] = (f32x4){0.f,0.f,0.f,0.f};

  for (int k0=0; k0<K; k0+=64) {
    #pragma unroll
    for (int i=0;i<4;++i) {
      const int li  = i*4096 + tid*16;          // linear dest byte in 16 KB tile
      const int row = li >> 7;
      const int col = ((li & 127) ^ ((row & 7) << 4)) >> 1;   // pre-swizzled source col
      const ushort* ga = A + (size_t)(abase+m0+row)*K + k0 + col;
      const ushort* gb = W + (size_t)(n0+row)*K + k0 + col;
      ushort* la = As + i*2048 + w*512;
      ushort* lb = Bs + i*2048 + w*512;
      __builtin_amdgcn_global_load_lds((const __attribute__((address_space(1))) unsigned int*)ga,
                                       (__attribute__((address_space(3))) unsigned int*)la, 16, 0, 0);
      __builtin_amdgcn_global_load_lds((const __attribute__((address_space(1))) unsigned int*)gb,
                                       (__attribute__((address_space(3))) unsigned int*)lb, 16, 0, 0);
    }
    __syncthreads();
    #pragma unroll
    for (int ks=0; ks<2; ++ks) {
      const int cb = ((g*16 + ks*64) ^ swzr) >> 1;   // swizzled read col (ushorts)
      bf16x8 af[4], bfr[4];
      #pragma unroll
      for (int i2=0;i2<4;++i2) {
        af[i2]  = *(const bf16x8*)(As + (size_t)(wr*64 + i2*16 + c16)*64 + cb);
        bfr[i2] = *(const bf16x8*)(Bs + (size_t)(wc*64 + i2*16 + c16)*64 + cb);
      }
      #pragma unroll
      for (int mi=0;mi<4;++mi)
        #pragma unroll
        for (int ni=0;ni<4;++ni)
          acc[mi][ni] = __builtin_amdgcn_mfma_f32_16x16x32_bf16(af[mi], bfr[ni], acc[mi][ni], 0,0,0);
    }
    __syncthreads();
  }
  const int col0 = n0 + wc*64 + c16;
  const int row0 = m0 + wr*64 + (g<<2);
  #pragma unroll
  for (int ni=0;ni<4;++ni) {
    const float bv = bias[col0 + ni*16];
    #pragma unroll
    for (int mi=0;mi<4;++mi) {
      #pragma unroll
      for (int r=0;r<4;++r) {
        float v = acc[mi][ni][r] + bv;
        if (RELU) v = fmaxf(v, 0.f);
        const size_t idx = (size_t)(row0 + mi*16 + r)*N + col0 + ni*16;
        if (OUT_BF16) ((ushort*)Cv)[idx] = f2b(v);
        else          ((float*)Cv)[idx]  = v;
      }
    }
  }
}

// ---------------- fused GEMM(N=256) + residual + LN, bf16 state, T2-swizzled LDS ----------------
// BM=128, BN=256, 512 threads = 8 waves as 2x4 (each 64 rows x 64 cols).
__global__ __launch_bounds__(512) void k_gemm_ln(
    const ushort* __restrict__ A,      // chunk-local [.., K] bf16
    const int* __restrict__ cntp, const int* __restrict__ cnt,
    const int* __restrict__ xoffp,     // global compact row base
    const ushort* __restrict__ W,      // [256, K] bf16
    const float* __restrict__ bias,
    const float* __restrict__ lns, const float* __restrict__ lnb,
    ushort* __restrict__ xb, int K)
{
  const int m0 = blockIdx.x*128;
  if (m0 >= *cntp) return;
  __shared__ alignas(16) ushort As[8192];    // [128][64]
  __shared__ alignas(16) ushort Bs[16384];   // [256][64]
  __shared__ float red[4][2][128];           // [wc][{sum,sq}][local row]
  const int tid = threadIdx.x;
  const int w = tid >> 6, l = tid & 63;
  const int g = l >> 4, c16 = l & 15;
  const int wr = w >> 2, wc = w & 3;
  const int swzr = (c16 & 7) << 4;

  f32x4 acc[4][4];
  #pragma unroll
  for (int i=0;i<4;++i)
    #pragma unroll
    for (int j=0;j<4;++j) acc[i][j] = (f32x4){0.f,0.f,0.f,0.f};

  for (int k0=0; k0<K; k0+=64) {
    #pragma unroll
    for (int i=0;i<2;++i) {          // stage As: 16 KB over 512 threads x 16 B = 2 rounds
      const int li  = i*8192 + tid*16;
      const int row = li >> 7;
      const int col = ((li & 127) ^ ((row & 7) << 4)) >> 1;
      const ushort* ga = A + (size_t)(m0+row)*K + k0 + col;
      ushort* la = As + i*4096 + w*512;
      __builtin_amdgcn_global_load_lds((const __attribute__((address_space(1))) unsigned int*)ga,
                                       (__attribute__((address_space(3))) unsigned int*)la, 16, 0, 0);
    }
    #pragma unroll
    for (int i=0;i<4;++i) {          // stage Bs: 32 KB = 4 rounds
      const int li  = i*8192 + tid*16;
      const int row = li >> 7;
      const int col = ((li & 127) ^ ((row & 7) << 4)) >> 1;
      const ushort* gb = W + (size_t)row*K + k0 + col;
      ushort* lb = Bs + i*4096 + w*512;
      __builtin_amdgcn_global_load_lds((const __attribute__((address_space(1))) unsigned int*)gb,
                                       (__attribute__((address_space(3))) unsigned int*)lb, 16, 0, 0);
    }
    __syncthreads();
    #pragma unroll
    for (int ks=0; ks<2; ++ks) {
      const int cb = ((g*16 + ks*64) ^ swzr) >> 1;
      bf16x8 af[4], bfr[4];
      #pragma unroll
      for (int i2=0;i2<4;++i2) {
        af[i2]  = *(const bf16x8*)(As + (size_t)(wr*64 + i2*16 + c16)*64 + cb);
        bfr[i2] = *(const bf16x8*)(Bs + (size_t)(wc*64 + i2*16 + c16)*64 + cb);
      }
      #pragma unroll
      for (int mi=0;mi<4;++mi)
        #pragma unroll
        for (int ni=0;ni<4;++ni)
          acc[mi][ni] = __builtin_amdgcn_mfma_f32_16x16x32_bf16(af[mi], bfr[ni], acc[mi][ni], 0,0,0);
    }
    __syncthreads();
  }

  // ---- epilogue: y = acc + bias + resid(bf16); LN over 256 cols; write xb ----
  const int xbase = *xoffp + m0;
  float bvs[4], svs[4], bbs[4];
  #pragma unroll
  for (int ni=0;ni<4;++ni) {
    int col = wc*64 + ni*16 + c16;
    bvs[ni] = bias[col]; svs[ni] = lns[col]; bbs[ni] = lnb[col];
  }
  float ps[4][4], pq[4][4];
  #pragma unroll
  for (int mi=0;mi<4;++mi) {
    #pragma unroll
    for (int r=0;r<4;++r) {
      ps[mi][r]=0.f; pq[mi][r]=0.f;
      const int lrow = wr*64 + mi*16 + 4*g + r;
      const ushort* xr = xb + (size_t)(xbase + lrow)*256;
      #pragma unroll
      for (int ni=0;ni<4;++ni) {
        float y = acc[mi][ni][r] + bvs[ni] + b2f(xr[wc*64 + ni*16 + c16]);
        acc[mi][ni][r] = y;
        ps[mi][r] += y;
        pq[mi][r] += y*y;
      }
    }
  }
  #pragma unroll
  for (int mi=0;mi<4;++mi)
    #pragma unroll
    for (int r=0;r<4;++r) {
      #pragma unroll
      for (int off=1; off<16; off<<=1) {
        ps[mi][r] += __shfl_xor(ps[mi][r], off, 16);
        pq[mi][r] += __shfl_xor(pq[mi][r], off, 16);
      }
    }
  if (c16 == 0) {
    #pragma unroll
    for (int mi=0;mi<4;++mi)
      #pragma unroll
      for (int r=0;r<4;++r) {
        const int lrow = wr*64 + mi*16 + 4*g + r;
        red[wc][0][lrow] = ps[mi][r];
        red[wc][1][lrow] = pq[mi][r];
      }
  }
  __syncthreads();
  const int cexact = *cnt;
  #pragma unroll
  for (int mi=0;mi<4;++mi) {
    #pragma unroll
    for (int r=0;r<4;++r) {
      const int lrow = wr*64 + mi*16 + 4*g + r;
      float tsum = red[0][0][lrow] + red[1][0][lrow] + red[2][0][lrow] + red[3][0][lrow];
      float tsq  = red[0][1][lrow] + red[1][1][lrow] + red[2][1][lrow] + red[3][1][lrow];
      float mean = tsum * (1.f/256.f);
      float var  = tsq * (1.f/256.f) - mean*mean;
      float inv  = rsqrtf(var + 1e-5f);
      if (m0 + lrow < cexact) {
        ushort* xbr = xb + (size_t)(xbase + lrow)*256;
        #pragma unroll
        for (int ni=0;ni<4;++ni) {
          int col = wc*64 + ni*16 + c16;
          xbr[col] = f2b((acc[mi][ni][r] - mean)*inv*svs[ni] + bbs[ni]);
        }
      }
    }
  }
}

// ---------------- MFMA flash attention on compact rows: block per (b,h) ----------------
__global__ __launch_bounds__(256) void k_attn_mfma(
    const ushort* __restrict__ qkv, ushort* __restrict__ ctx,
    const int* __restrict__ offc)
{
  __shared__ alignas(16) char lds[81920];
  char* Kb = lds;
  char* Vt = lds + 24576;
  const int tid = threadIdx.x;
  const int w = tid >> 6, l = tid & 63;
  const int g = l >> 4, c = l & 15;
  char* Pw = lds + 57344 + w*6144;
  const int bl = blockIdx.x >> 2, h = blockIdx.x & 3;
  const int rowbase = offc[bl] - offc[0];
  const int len = offc[bl+1] - offc[bl];
  const int nkt = (len + 15) >> 4;
  const int nkf = (len + 31) >> 5;
  const ushort* base = qkv + (size_t)rowbase*768;
  ushort* cbase = ctx + (size_t)rowbase*256;

  const int lenk8 = nkt*16*8;
  for (int idx = tid; idx < lenk8; idx += 256) {
    int row = idx >> 3, ch = idx & 7;
    uint4 v = *(const uint4*)(base + (size_t)row*768 + 256 + h*64 + ch*8);
    *(uint4*)(Kb + ((row*128 + ch*16) ^ ((row&7)<<4))) = v;
  }
  {
    const int lenv = nkf*32;
    int d0 = (tid & 15)*4;
    for (int key = tid >> 4; key < lenv; key += 16) {
      ushort4 v = *(const ushort4*)(base + (size_t)key*768 + 512 + h*64 + d0);
      ushort vv[4] = {v.x, v.y, v.z, v.w};
      #pragma unroll
      for (int j=0;j<4;++j) {
        int d = d0 + j;
        *(ushort*)(Vt + ((d*512 + key*2) ^ ((d&7)<<4))) = vv[j];
      }
    }
  }
  __syncthreads();

  for (int t = nkt; t < 2*nkf; ++t) {
    #pragma unroll
    for (int r=0;r<4;++r) {
      int q = 4*g + r;
      *(ushort*)(Pw + (((t>>1)*1024 + q*64 + ((t&1)*16 + c)*2) ^ (((q>>2)&3)<<4))) = 0;
    }
  }

  const int nst = (len + 15) >> 4;
  for (int s = w; s < nst; s += 4) {
    const ushort* qp = base + (size_t)(s*16 + c)*768 + h*64 + g*8;
    bf16x8 aq0 = *(const bf16x8*)qp;
    bf16x8 aq1 = *(const bf16x8*)(qp + 32);

    f32x4 sc[12];
    #pragma unroll
    for (int t=0;t<12;++t) {
      sc[t] = (f32x4){0.f,0.f,0.f,0.f};
      if (t < nkt) {
        int ba0 = ((t*16 + c)*128 + g*16)      ^ ((c&7)<<4);
        int ba1 = ((t*16 + c)*128 + g*16 + 64) ^ ((c&7)<<4);
        bf16x8 k0 = *(const bf16x8*)(Kb + ba0);
        bf16x8 k1 = *(const bf16x8*)(Kb + ba1);
        sc[t] = __builtin_amdgcn_mfma_f32_16x16x32_bf16(aq0, k0, sc[t], 0,0,0);
        sc[t] = __builtin_amdgcn_mfma_f32_16x16x32_bf16(aq1, k1, sc[t], 0,0,0);
        if (t == nkt-1 && t*16 + c >= len)
          sc[t] = (f32x4){-1e30f,-1e30f,-1e30f,-1e30f};
      }
    }
    float mr[4] = {-1e30f,-1e30f,-1e30f,-1e30f};
    #pragma unroll
    for (int t=0;t<12;++t) if (t<nkt) {
      #pragma unroll
      for (int r=0;r<4;++r) mr[r] = fmaxf(mr[r], sc[t][r]);
    }
    #pragma unroll
    for (int r=0;r<4;++r) {
      mr[r] = fmaxf(mr[r], __shfl_xor(mr[r], 1, 16));
      mr[r] = fmaxf(mr[r], __shfl_xor(mr[r], 2, 16));
      mr[r] = fmaxf(mr[r], __shfl_xor(mr[r], 4, 16));
      mr[r] = fmaxf(mr[r], __shfl_xor(mr[r], 8, 16));
    }
    float sr[4] = {0.f,0.f,0.f,0.f};
    #pragma unroll
    for (int t=0;t<12;++t) if (t<nkt) {
      #pragma unroll
      for (int r=0;r<4;++r) {
        float p = __expf((sc[t][r] - mr[r]) * 0.125f);
        sr[r] += p;
        int q = 4*g + r;
        *(ushort*)(Pw + (((t>>1)*1024 + q*64 + ((t&1)*16 + c)*2) ^ (((q>>2)&3)<<4))) = f2b(p);
      }
    }
    #pragma unroll
    for (int r=0;r<4;++r) {
      sr[r] += __shfl_xor(sr[r], 1, 16);
      sr[r] += __shfl_xor(sr[r], 2, 16);
      sr[r] += __shfl_xor(sr[r], 4, 16);
      sr[r] += __shfl_xor(sr[r], 8, 16);
    }
    f32x4 oa[4];
    #pragma unroll
    for (int dt=0;dt<4;++dt) oa[dt] = (f32x4){0.f,0.f,0.f,0.f};
    #pragma unroll
    for (int kf=0;kf<6;++kf) if (kf<nkf) {
      bf16x8 pf = *(const bf16x8*)(Pw + ((kf*1024 + c*64 + g*16) ^ (((c>>2)&3)<<4)));
      #pragma unroll
      for (int dt=0;dt<4;++dt) {
        int d = dt*16 + c;
        bf16x8 vf = *(const bf16x8*)(Vt + ((d*512 + kf*64 + g*16) ^ ((d&7)<<4)));
        oa[dt] = __builtin_amdgcn_mfma_f32_16x16x32_bf16(pf, vf, oa[dt], 0,0,0);
      }
    }
    float inv[4];
    #pragma unroll
    for (int r=0;r<4;++r) inv[r] = 1.f / sr[r];
    ushort* orow = cbase + (size_t)(s*16)*256 + h*64;
    #pragma unroll
    for (int r=0;r<4;++r) {
      int q = 4*g + r;
      if (s*16 + q < len) {
        #pragma unroll
        for (int dt=0;dt<4;++dt)
          orow[(size_t)q*256 + dt*16 + c] = f2b(oa[dt][r] * inv[r]);
      }
    }
  }
}

// ---------------- ragged weighted pooling (compact bf16 x) + concat id embeddings ----------------
__global__ __launch_bounds__(256) void k_pool(
    const ushort* __restrict__ xb, const int* __restrict__ off,
    const float* __restrict__ attr_tf, const float* __restrict__ attr_feat,
    const int* __restrict__ lens_u, const int* __restrict__ lens_i,
    const int* __restrict__ user_ids, const int* __restrict__ item_ids,
    const float* __restrict__ user_tab, const float* __restrict__ item_tab,
    const float* __restrict__ feat_w, const float* __restrict__ feat_b,
    float* __restrict__ user_out, float* __restrict__ item_out)
{
  __shared__ float wu[L_], tf[L_];
  const int b = blockIdx.x;
  const int t = threadIdx.x;
  if (t < L_) {
    const float* f = attr_feat + ((size_t)b*L_ + t)*NF_;
    float sacc = feat_b[0];
    #pragma unroll
    for (int j=0;j<NF_;++j) sacc = fmaf(f[j], feat_w[j], sacc);
    wu[t] = 1.f/(1.f+__expf(-sacc));
    tf[t] = attr_tf[b*L_+t];
  }
  __syncthreads();
  const int Lu = lens_u[b], Li = lens_i[b];
  const ushort* xrow = xb + (size_t)off[b]*D_;
  float su=0.f, si=0.f;
  for (int l=0;l<Lu+Li;++l) {
    float val = b2f(xrow[(size_t)l*D_ + t]) * tf[l];
    if (l < Lu) su = fmaf(val, wu[l], su);
    else        si = fmaf(val, 1.f-wu[l], si);
  }
  user_out[(size_t)b*512 + t]       = su/(float)Lu;
  item_out[(size_t)b*512 + t]       = si/(float)Li;
  user_out[(size_t)b*512 + 256 + t] = user_tab[(size_t)user_ids[b]*D_ + t];
  item_out[(size_t)b*512 + 256 + t] = item_tab[(size_t)item_ids[b]*D_ + t];
}

// ---------------- logits + mask + new_targets (bf16 tables) ----------------
__global__ __launch_bounds__(256) void k_logits(
    const int* __restrict__ pos_t, const int* __restrict__ neg_t,
    const int* __restrict__ pos_l, const int* __restrict__ neg_l,
    const ushort* __restrict__ oeu, const ushort* __restrict__ oei,
    const float* __restrict__ user_out, const float* __restrict__ item_out,
    float* __restrict__ out)
{
  const int g = blockIdx.x*4 + (threadIdx.x >> 6);
  const int lane = threadIdx.x & 63;
  const int b = g / NT_;
  const int k = g - b*NT_;
  const int tid_ = (k < LP_) ? pos_t[b*LP_ + k] : neg_t[b*LNEG_ + (k-LP_)];
  const ushort* eu = oeu + (size_t)tid_*512;
  const ushort* ei = oei + (size_t)tid_*512;
  const float* uo = user_out + (size_t)b*512;
  const float* io = item_out + (size_t)b*512;
  const int d0 = lane*8;
  float s = 0.f;
  ushort4 a0 = *(const ushort4*)(eu+d0), a1 = *(const ushort4*)(eu+d0+4);
  float4 u0 = *(const float4*)(uo+d0), u1 = *(const float4*)(uo+d0+4);
  s += b2f(a0.x)*u0.x + b2f(a0.y)*u0.y + b2f(a0.z)*u0.z + b2f(a0.w)*u0.w;
  s += b2f(a1.x)*u1.x + b2f(a1.y)*u1.y + b2f(a1.z)*u1.z + b2f(a1.w)*u1.w;
  ushort4 c0 = *(const ushort4*)(ei+d0), c1 = *(const ushort4*)(ei+d0+4);
  float4 i0 = *(const float4*)(io+d0), i1 = *(const float4*)(io+d0+4);
  s += b2f(c0.x)*i0.x + b2f(c0.y)*i0.y + b2f(c0.z)*i0.z + b2f(c0.w)*i0.w;
  s += b2f(c1.x)*i1.x + b2f(c1.y)*i1.y + b2f(c1.z)*i1.z + b2f(c1.w)*i1.w;
  #pragma unroll
  for (int off=32; off>0; off>>=1) s += __shfl_xor(s, off, 64);
  if (lane == 0) {
    out[(size_t)b*NT_ + k] = s;
    float mv, nt;
    if (k < LP_) { mv = (k < pos_l[b]) ? 1.f : 0.f; nt = mv; }
    else         { mv = ((k - LP_) < neg_l[b]) ? 1.f : 0.f; nt = 0.f; }
    out[(size_t)B_*NT_   + (size_t)b*NT_ + k] = mv;
    out[(size_t)2*B_*NT_ + (size_t)b*NT_ + k] = nt;
  }
}

extern "C" void kernel_launch(void* const* d_in, const int* in_sizes, int n_in,
                              void* d_out, int out_size, void* d_ws, size_t ws_size,
                              hipStream_t stream)
{
  const int*   attr      = (const int*)d_in[0];
  const int*   attr_inds = (const int*)d_in[1];
  const float* attr_tf   = (const float*)d_in[2];
  const float* attr_feat = (const float*)d_in[3];
  const int*   attr_lens = (const int*)d_in[4];
  const int*   lens_u    = (const int*)d_in[5];
  const int*   lens_i    = (const int*)d_in[6];
  const int*   user_ids  = (const int*)d_in[7];
  const int*   item_ids  = (const int*)d_in[8];
  const int*   pos_t     = (const int*)d_in[9];
  const int*   pos_l     = (const int*)d_in[10];
  const int*   neg_t     = (const int*)d_in[11];
  const int*   neg_l     = (const int*)d_in[12];
  const float* attr_emb  = (const float*)d_in[13];
  const float* ind_emb   = (const float*)d_in[14];
  const float* user_tab  = (const float*)d_in[15];
  const float* item_tab  = (const float*)d_in[16];
  const float* oeu       = (const float*)d_in[17];
  const float* oei       = (const float*)d_in[18];
  const float* feat_w    = (const float*)d_in[19];
  const float* feat_b    = (const float*)d_in[20];
  const float* Wqkv      = (const float*)d_in[21];
  const float* bqkv      = (const float*)d_in[22];
  const float* Wo        = (const float*)d_in[23];
  const float* bo        = (const float*)d_in[24];
  const float* ln1s      = (const float*)d_in[25];
  const float* ln1b      = (const float*)d_in[26];
  const float* W1        = (const float*)d_in[27];
  const float* b1        = (const float*)d_in[28];
  const float* W2        = (const float*)d_in[29];
  const float* b2        = (const float*)d_in[30];
  const float* ln2s      = (const float*)d_in[31];
  const float* ln2b      = (const float*)d_in[32];

  // ---- ws layout: ints[768] | uo[B,512]f32 | io[B,512]f32 | xb[M,256]bf16 | weights bf16 | oeu_b | oei_b | chunk scratch ----
  int* ioff  = (int*)d_ws;            // off[513]
  int* ccnt  = ioff + 520;
  int* ccntp = ccnt + 64;
  float* ws = (float*)d_ws + 768;
  float* uo = ws;
  float* io = uo + (size_t)B_*512;
  ushort* xb   = (ushort*)(io + (size_t)B_*512);
  ushort* wq_b = xb + (size_t)M_*D_;
  ushort* wo_b = wq_b + (size_t)2*768*256;
  ushort* w1_b = wo_b + (size_t)2*256*256;
  ushort* w2_b = w1_b + (size_t)2*1024*256;
  ushort* oeu_b = w2_b + (size_t)2*256*1024;
  ushort* oei_b = oeu_b + (size_t)V_*512;
  float* scratch = (float*)(oei_b + (size_t)V_*512);

  const size_t fixed_floats = 768 + (size_t)B_*1024 + (size_t)M_*(D_/2) + 786432 + (size_t)V_*512;
  int Bc = 8;
  for (int cand = 512; cand >= 8; cand >>= 1) {
    size_t need = (fixed_floats + (size_t)cand*L_*512) * sizeof(float);
    if (need <= ws_size) { Bc = cand; break; }
  }
  const int nchunks = B_ / Bc;
  const size_t Mc = (size_t)Bc * L_;

  float* out = (float*)d_out;

  k_prefix<<<1, 512, 0, stream>>>(attr_lens, ioff, ccnt, ccntp, Bc, nchunks);
  k_f2b4<<<768, 256, 0, stream>>>(Wqkv, Wo, W1, W2, wq_b, wo_b, w1_b, w2_b);
  k_f2b<<<(V_*512)/2048, 256, 0, stream>>>(oeu, oeu_b);
  k_f2b<<<(V_*512)/2048, 256, 0, stream>>>(oei, oei_b);
  k_embed<<<M_*64/256, 256, 0, stream>>>(attr, attr_inds, attr_lens, ioff, attr_emb, ind_emb, xb);

  for (int l=0; l<NL_; ++l) {
    const float* bqkv_l = bqkv + (size_t)l*768;
    const float* bo_l   = bo   + (size_t)l*D_;
    const float* b1_l   = b1   + (size_t)l*FF_;
    const float* b2_l   = b2   + (size_t)l*D_;
    for (int c=0; c<nchunks; ++c) {
      const int* offc = ioff + c*Bc;
      const int* cntp = ccntp + c;
      const int* cnt  = ccnt + c;
      ushort* qkv_b = (ushort*)scratch;                 // [Mc,768] bf16
      ushort* ctx_b = (ushort*)(scratch + Mc*384);      // [Mc,256] bf16
      ushort* h_b   = (ushort*)scratch;                 // [Mc,1024] bf16 (FF phase, aliases)

      k_gemm_mfma<1,0><<<dim3(768/128, Mc/128), 256, 0, stream>>>(
          xb, offc, cntp, wq_b + (size_t)l*768*256, bqkv_l, qkv_b, 768, 256);
      k_attn_mfma<<<Bc*H_, 256, 0, stream>>>(qkv_b, ctx_b, offc);
      k_gemm_ln<<<Mc/128, 512, 0, stream>>>(
          ctx_b, cntp, cnt, offc, wo_b + (size_t)l*256*256, bo_l,
          ln1s + (size_t)l*D_, ln1b + (size_t)l*D_, xb, 256);
      k_gemm_mfma<1,1><<<dim3(1024/128, Mc/128), 256, 0, stream>>>(
          xb, offc, cntp, w1_b + (size_t)l*1024*256, b1_l, h_b, 1024, 256);
      k_gemm_ln<<<Mc/128, 512, 0, stream>>>(
          h_b, cntp, cnt, offc, w2_b + (size_t)l*256*1024, b2_l,
          ln2s + (size_t)l*D_, ln2b + (size_t)l*D_, xb, 1024);
    }
  }
  k_pool<<<B_, 256, 0, stream>>>(xb, ioff, attr_tf, attr_feat, lens_u, lens_i, user_ids, item_ids,
                                 user_tab, item_tab, feat_w, feat_b, uo, io);
  k_logits<<<B_*NT_/4, 256, 0, stream>>>(pos_t, neg_t, pos_l, neg_l, oeu_b, oei_b, uo, io, out);
}

// Round 9
// 703.408 us; speedup vs baseline: 7.5119x; 1.0163x over previous
//
#include <hip/hip_runtime.h>
#include <hip/hip_bf16.h>
#include <cstdint>
#include <cstddef>

#define B_ 512
#define L_ 192
#define D_ 256
#define H_ 4
#define DH_ 64
#define FF_ 1024
#define NL_ 2
#define LP_ 30
#define LNEG_ 300
#define NF_ 13
#define M_ (B_*L_)   // 98304 tokens
#define NT_ 330      // LP_+LNEG_
#define V_ 30000

typedef __attribute__((ext_vector_type(8))) short bf16x8;
typedef __attribute__((ext_vector_type(4))) float f32x4;

// RNE float -> bf16 bits (finite inputs only)
__device__ __forceinline__ ushort f2b(float f) {
  union { float f; uint32_t u; } v; v.f = f;
  uint32_t u = v.u;
  return (ushort)((u + 0x7FFFu + ((u >> 16) & 1u)) >> 16);
}
__device__ __forceinline__ float b2f(ushort u) {
  union { uint32_t u; float f; } v; v.u = (uint32_t)u << 16; return v.f;
}

// ---------------- prefix sums of lens: off[513], per-chunk counts ----------------
__global__ __launch_bounds__(512) void k_prefix(
    const int* __restrict__ lens, int* __restrict__ off,
    int* __restrict__ ccnt, int* __restrict__ ccntp, int Bc, int nchunks)
{
  const int t = threadIdx.x;
  int s = 0;
  for (int i = 0; i < t; ++i) s += lens[i];
  off[t] = s;
  if (t == 511) off[512] = s + lens[511];
  if (t < nchunks) {
    int s2 = 0;
    const int c0 = t * Bc;
    for (int i = 0; i < Bc; ++i) s2 += lens[c0 + i];
    ccnt[t]  = s2;
    ccntp[t] = (s2 + 127) & ~127;
  }
}

// ---------------- generic fp32 -> bf16 conversion (2048 elems/block) ----------------
__global__ __launch_bounds__(256) void k_f2b(const float* __restrict__ in, ushort* __restrict__ out) {
  const int i = (blockIdx.x*256 + threadIdx.x)*8;
  float4 a = *(const float4*)(in+i);
  float4 b = *(const float4*)(in+i+4);
  ushort4 o1; o1.x=f2b(a.x); o1.y=f2b(a.y); o1.z=f2b(a.z); o1.w=f2b(a.w);
  ushort4 o2; o2.x=f2b(b.x); o2.y=f2b(b.y); o2.z=f2b(b.z); o2.w=f2b(b.w);
  *(ushort4*)(out+i)   = o1;
  *(ushort4*)(out+i+4) = o2;
}

// ---------------- weight conversion, all 4 groups in one launch ----------------
__global__ __launch_bounds__(256) void k_f2b4(
    const float* __restrict__ wq, const float* __restrict__ wo,
    const float* __restrict__ w1, const float* __restrict__ w2,
    ushort* __restrict__ oq, ushort* __restrict__ oo,
    ushort* __restrict__ o1, ushort* __restrict__ o2)
{
  int bb = blockIdx.x;
  const float* in; ushort* out; int base;
  if (bb < 192)      { in = wq; out = oq; base = bb; }
  else if (bb < 256) { in = wo; out = oo; base = bb - 192; }
  else if (bb < 512) { in = w1; out = o1; base = bb - 256; }
  else               { in = w2; out = o2; base = bb - 512; }
  const int i = base*2048 + threadIdx.x*8;
  float4 a = *(const float4*)(in+i);
  float4 b = *(const float4*)(in+i+4);
  ushort4 q1; q1.x=f2b(a.x); q1.y=f2b(a.y); q1.z=f2b(a.z); q1.w=f2b(a.w);
  ushort4 q2; q2.x=f2b(b.x); q2.y=f2b(b.y); q2.z=f2b(b.z); q2.w=f2b(b.w);
  *(ushort4*)(out+i)   = q1;
  *(ushort4*)(out+i+4) = q2;
}

// ---------------- embedding gather into COMPACT token space (bf16 state only) ----------------
__global__ __launch_bounds__(256) void k_embed(
    const int* __restrict__ attr, const int* __restrict__ inds,
    const int* __restrict__ lens, const int* __restrict__ off,
    const float* __restrict__ attr_emb, const float* __restrict__ ind_emb,
    ushort* __restrict__ xb)
{
  int idx = blockIdx.x*256 + threadIdx.x;
  int token = idx >> 6;
  int c = (idx & 63) * 4;
  int b = token / L_;
  int l = token - b*L_;
  if (l >= lens[b]) return;
  size_t crow = (size_t)off[b] + l;
  int a = attr[token];
  int id = inds[token];
  const float4 e  = *(const float4*)(attr_emb + (size_t)a*D_ + c);
  const float4 ie = *(const float4*)(ind_emb  + (size_t)id*D_ + c);
  ushort4 ob; ob.x=f2b(e.x+ie.x); ob.y=f2b(e.y+ie.y); ob.z=f2b(e.z+ie.z); ob.w=f2b(e.w+ie.w);
  *(ushort4*)(xb + crow*D_ + c) = ob;
}

// ---------------- bf16 MFMA GEMM (128x128), T2-swizzled LDS: C = A[aoff..] @ W^T + bias ----------------
template<int OUT_BF16, int RELU>
__global__ __launch_bounds__(256) void k_gemm_mfma(
    const ushort* __restrict__ A, const int* __restrict__ aoffp,
    const int* __restrict__ cntp,
    const ushort* __restrict__ W, const float* __restrict__ bias,
    void* __restrict__ Cv, int N, int K)
{
  if ((int)blockIdx.y * 128 >= *cntp) return;
  __shared__ alignas(16) ushort As[8192];
  __shared__ alignas(16) ushort Bs[8192];
  const int abase = *aoffp;
  const int tid = threadIdx.x;
  const int w = tid >> 6, l = tid & 63;
  const int g = l >> 4, c16 = l & 15;
  const int m0 = blockIdx.y*128, n0 = blockIdx.x*128;
  const int wr = w >> 1, wc = w & 1;
  const int swzr = (c16 & 7) << 4;

  f32x4 acc[4][4];
  #pragma unroll
  for (int i=0;i<4;++i)
    #pragma unroll
    for (int j=0;j<4;++j) acc[i][j] = (f32x4){0.f,0.f,0.f,0.f};

  for (int k0=0; k0<K; k0+=64) {
    #pragma unroll
    for (int i=0;i<4;++i) {
      const int li  = i*4096 + tid*16;
      const int row = li >> 7;
      const int col = ((li & 127) ^ ((row & 7) << 4)) >> 1;
      const ushort* ga = A + (size_t)(abase+m0+row)*K + k0 + col;
      const ushort* gb = W + (size_t)(n0+row)*K + k0 + col;
      ushort* la = As + i*2048 + w*512;
      ushort* lb = Bs + i*2048 + w*512;
      __builtin_amdgcn_global_load_lds((const __attribute__((address_space(1))) unsigned int*)ga,
                                       (__attribute__((address_space(3))) unsigned int*)la, 16, 0, 0);
      __builtin_amdgcn_global_load_lds((const __attribute__((address_space(1))) unsigned int*)gb,
                                       (__attribute__((address_space(3))) unsigned int*)lb, 16, 0, 0);
    }
    __syncthreads();
    #pragma unroll
    for (int ks=0; ks<2; ++ks) {
      const int cb = ((g*16 + ks*64) ^ swzr) >> 1;
      bf16x8 af[4], bfr[4];
      #pragma unroll
      for (int i2=0;i2<4;++i2) {
        af[i2]  = *(const bf16x8*)(As + (size_t)(wr*64 + i2*16 + c16)*64 + cb);
        bfr[i2] = *(const bf16x8*)(Bs + (size_t)(wc*64 + i2*16 + c16)*64 + cb);
      }
      #pragma unroll
      for (int mi=0;mi<4;++mi)
        #pragma unroll
        for (int ni=0;ni<4;++ni)
          acc[mi][ni] = __builtin_amdgcn_mfma_f32_16x16x32_bf16(af[mi], bfr[ni], acc[mi][ni], 0,0,0);
    }
    __syncthreads();
  }
  const int col0 = n0 + wc*64 + c16;
  const int row0 = m0 + wr*64 + (g<<2);
  #pragma unroll
  for (int ni=0;ni<4;++ni) {
    const float bv = bias[col0 + ni*16];
    #pragma unroll
    for (int mi=0;mi<4;++mi) {
      #pragma unroll
      for (int r=0;r<4;++r) {
        float v = acc[mi][ni][r] + bv;
        if (RELU) v = fmaxf(v, 0.f);
        const size_t idx = (size_t)(row0 + mi*16 + r)*N + col0 + ni*16;
        if (OUT_BF16) ((ushort*)Cv)[idx] = f2b(v);
        else          ((float*)Cv)[idx]  = v;
      }
    }
  }
}

// ---------------- fused GEMM(N=256) + residual + LN, bf16 state, T2-swizzled LDS ----------------
// BM=128, BN=256, 512 threads = 8 waves as 2x4 (each 64 rows x 64 cols).
__global__ __launch_bounds__(512) void k_gemm_ln(
    const ushort* __restrict__ A,      // chunk-local [.., K] bf16
    const int* __restrict__ cntp, const int* __restrict__ cnt,
    const int* __restrict__ xoffp,     // global compact row base
    const ushort* __restrict__ W,      // [256, K] bf16
    const float* __restrict__ bias,
    const float* __restrict__ lns, const float* __restrict__ lnb,
    ushort* __restrict__ xb, int K)
{
  const int m0 = blockIdx.x*128;
  if (m0 >= *cntp) return;
  __shared__ alignas(16) ushort As[8192];    // [128][64]
  __shared__ alignas(16) ushort Bs[16384];   // [256][64]
  __shared__ float red[4][2][128];
  const int tid = threadIdx.x;
  const int w = tid >> 6, l = tid & 63;
  const int g = l >> 4, c16 = l & 15;
  const int wr = w >> 2, wc = w & 3;
  const int swzr = (c16 & 7) << 4;

  f32x4 acc[4][4];
  #pragma unroll
  for (int i=0;i<4;++i)
    #pragma unroll
    for (int j=0;j<4;++j) acc[i][j] = (f32x4){0.f,0.f,0.f,0.f};

  for (int k0=0; k0<K; k0+=64) {
    #pragma unroll
    for (int i=0;i<2;++i) {
      const int li  = i*8192 + tid*16;
      const int row = li >> 7;
      const int col = ((li & 127) ^ ((row & 7) << 4)) >> 1;
      const ushort* ga = A + (size_t)(m0+row)*K + k0 + col;
      ushort* la = As + i*4096 + w*512;
      __builtin_amdgcn_global_load_lds((const __attribute__((address_space(1))) unsigned int*)ga,
                                       (__attribute__((address_space(3))) unsigned int*)la, 16, 0, 0);
    }
    #pragma unroll
    for (int i=0;i<4;++i) {
      const int li  = i*8192 + tid*16;
      const int row = li >> 7;
      const int col = ((li & 127) ^ ((row & 7) << 4)) >> 1;
      const ushort* gb = W + (size_t)row*K + k0 + col;
      ushort* lb = Bs + i*4096 + w*512;
      __builtin_amdgcn_global_load_lds((const __attribute__((address_space(1))) unsigned int*)gb,
                                       (__attribute__((address_space(3))) unsigned int*)lb, 16, 0, 0);
    }
    __syncthreads();
    #pragma unroll
    for (int ks=0; ks<2; ++ks) {
      const int cb = ((g*16 + ks*64) ^ swzr) >> 1;
      bf16x8 af[4], bfr[4];
      #pragma unroll
      for (int i2=0;i2<4;++i2) {
        af[i2]  = *(const bf16x8*)(As + (size_t)(wr*64 + i2*16 + c16)*64 + cb);
        bfr[i2] = *(const bf16x8*)(Bs + (size_t)(wc*64 + i2*16 + c16)*64 + cb);
      }
      #pragma unroll
      for (int mi=0;mi<4;++mi)
        #pragma unroll
        for (int ni=0;ni<4;++ni)
          acc[mi][ni] = __builtin_amdgcn_mfma_f32_16x16x32_bf16(af[mi], bfr[ni], acc[mi][ni], 0,0,0);
    }
    __syncthreads();
  }

  const int xbase = *xoffp + m0;
  float bvs[4], svs[4], bbs[4];
  #pragma unroll
  for (int ni=0;ni<4;++ni) {
    int col = wc*64 + ni*16 + c16;
    bvs[ni] = bias[col]; svs[ni] = lns[col]; bbs[ni] = lnb[col];
  }
  float ps[4][4], pq[4][4];
  #pragma unroll
  for (int mi=0;mi<4;++mi) {
    #pragma unroll
    for (int r=0;r<4;++r) {
      ps[mi][r]=0.f; pq[mi][r]=0.f;
      const int lrow = wr*64 + mi*16 + 4*g + r;
      const ushort* xr = xb + (size_t)(xbase + lrow)*256;
      #pragma unroll
      for (int ni=0;ni<4;++ni) {
        float y = acc[mi][ni][r] + bvs[ni] + b2f(xr[wc*64 + ni*16 + c16]);
        acc[mi][ni][r] = y;
        ps[mi][r] += y;
        pq[mi][r] += y*y;
      }
    }
  }
  #pragma unroll
  for (int mi=0;mi<4;++mi)
    #pragma unroll
    for (int r=0;r<4;++r) {
      #pragma unroll
      for (int off=1; off<16; off<<=1) {
        ps[mi][r] += __shfl_xor(ps[mi][r], off, 16);
        pq[mi][r] += __shfl_xor(pq[mi][r], off, 16);
      }
    }
  if (c16 == 0) {
    #pragma unroll
    for (int mi=0;mi<4;++mi)
      #pragma unroll
      for (int r=0;r<4;++r) {
        const int lrow = wr*64 + mi*16 + 4*g + r;
        red[wc][0][lrow] = ps[mi][r];
        red[wc][1][lrow] = pq[mi][r];
      }
  }
  __syncthreads();
  const int cexact = *cnt;
  #pragma unroll
  for (int mi=0;mi<4;++mi) {
    #pragma unroll
    for (int r=0;r<4;++r) {
      const int lrow = wr*64 + mi*16 + 4*g + r;
      float tsum = red[0][0][lrow] + red[1][0][lrow] + red[2][0][lrow] + red[3][0][lrow];
      float tsq  = red[0][1][lrow] + red[1][1][lrow] + red[2][1][lrow] + red[3][1][lrow];
      float mean = tsum * (1.f/256.f);
      float var  = tsq * (1.f/256.f) - mean*mean;
      float inv  = rsqrtf(var + 1e-5f);
      if (m0 + lrow < cexact) {
        ushort* xbr = xb + (size_t)(xbase + lrow)*256;
        #pragma unroll
        for (int ni=0;ni<4;++ni) {
          int col = wc*64 + ni*16 + c16;
          xbr[col] = f2b((acc[mi][ni][r] - mean)*inv*svs[ni] + bbs[ni]);
        }
      }
    }
  }
}

// ---------------- fused FFN: xb = LN(xb + relu(xb@W1^T+b1)@W2^T + b2)*s + b ----------------
// BM=128 rows/block, 512 threads = 8 waves (2 wr x 4 wc). FF sliced 8 x 128 cols; h slice in LDS.
// LDS bytes: [0,16384) As x-chunk [128][64] | [16384,32768) Ws1 [128][64] | [32768,65536) Hs [128][128]
//            phase B overlays [0,32768) with Ws2 [256][64]. + red 4 KB.
__global__ __launch_bounds__(512) void k_ffn(
    const int* __restrict__ cntp, const int* __restrict__ cnt,
    const int* __restrict__ xoffp,
    const ushort* __restrict__ W1, const float* __restrict__ b1,
    const ushort* __restrict__ W2, const float* __restrict__ b2,
    const float* __restrict__ lns, const float* __restrict__ lnb,
    ushort* __restrict__ xb)
{
  const int m0 = blockIdx.x*128;
  if (m0 >= *cntp) return;
  __shared__ alignas(16) char lds[65536];
  __shared__ float red[4][2][128];
  const int tid = threadIdx.x;
  const int w = tid >> 6, l = tid & 63;
  const int g = l >> 4, c16 = l & 15;
  const int wr = w >> 2, wc = w & 3;
  const int swzr = (c16 & 7) << 4;
  const int xbase = *xoffp + m0;

  f32x4 tac[4][4];
  #pragma unroll
  for (int i=0;i<4;++i)
    #pragma unroll
    for (int j=0;j<4;++j) tac[i][j] = (f32x4){0.f,0.f,0.f,0.f};

  for (int s=0; s<8; ++s) {
    // ---- phase A: h_s[128][128] = relu(x @ W1_s^T + b1_s); wave tile 64r x 32c
    f32x4 hac[4][2];
    #pragma unroll
    for (int i=0;i<4;++i)
      #pragma unroll
      for (int j=0;j<2;++j) hac[i][j] = (f32x4){0.f,0.f,0.f,0.f};
    for (int kc=0; kc<4; ++kc) {
      __syncthreads();                 // As/Ws1 (or Ws2 from prev slice) free
      #pragma unroll
      for (int i=0;i<2;++i) {          // stage As [128][64] from x, cols kc*64..
        const int li  = i*8192 + tid*16;
        const int row = li >> 7;
        const int col = ((li & 127) ^ ((row & 7) << 4)) >> 1;
        const ushort* ga = xb + (size_t)(xbase+row)*256 + kc*64 + col;
        char* la = lds + i*8192 + w*1024;
        __builtin_amdgcn_global_load_lds((const __attribute__((address_space(1))) unsigned int*)ga,
                                         (__attribute__((address_space(3))) unsigned int*)la, 16, 0, 0);
      }
      #pragma unroll
      for (int i=0;i<2;++i) {          // stage Ws1 [128][64] from W1 rows s*128.., cols kc*64..
        const int li  = i*8192 + tid*16;
        const int row = li >> 7;
        const int col = ((li & 127) ^ ((row & 7) << 4)) >> 1;
        const ushort* gb = W1 + (size_t)(s*128+row)*256 + kc*64 + col;
        char* lb = lds + 16384 + i*8192 + w*1024;
        __builtin_amdgcn_global_load_lds((const __attribute__((address_space(1))) unsigned int*)gb,
                                         (__attribute__((address_space(3))) unsigned int*)lb, 16, 0, 0);
      }
      __syncthreads();
      #pragma unroll
      for (int ks=0; ks<2; ++ks) {
        const int cb = (g*16 + ks*64) ^ swzr;
        bf16x8 af[4], bf[2];
        #pragma unroll
        for (int mi=0;mi<4;++mi)
          af[mi] = *(const bf16x8*)(lds + (wr*64 + mi*16 + c16)*128 + cb);
        #pragma unroll
        for (int ni=0;ni<2;++ni)
          bf[ni] = *(const bf16x8*)(lds + 16384 + (wc*32 + ni*16 + c16)*128 + cb);
        #pragma unroll
        for (int mi=0;mi<4;++mi)
          #pragma unroll
          for (int ni=0;ni<2;++ni)
            hac[mi][ni] = __builtin_amdgcn_mfma_f32_16x16x32_bf16(af[mi], bf[ni], hac[mi][ni], 0,0,0);
      }
    }
    // bias + relu, write h_s to Hs (bf16, swizzled)
    {
      float bv1[2];
      #pragma unroll
      for (int ni=0;ni<2;++ni) bv1[ni] = b1[s*128 + wc*32 + ni*16 + c16];
      #pragma unroll
      for (int mi=0;mi<4;++mi)
        #pragma unroll
        for (int ni=0;ni<2;++ni)
          #pragma unroll
          for (int r=0;r<4;++r) {
            int row = wr*64 + mi*16 + 4*g + r;
            int colb = (wc*32 + ni*16 + c16)*2;
            float h = fmaxf(hac[mi][ni][r] + bv1[ni], 0.f);
            *(ushort*)(lds + 32768 + row*256 + (colb ^ ((row&7)<<4))) = f2b(h);
          }
    }
    __syncthreads();                   // Hs visible; As/Ws1 region free for Ws2
    // ---- phase B: t += h_s @ W2_s^T; wave tile 64r x 64c; K=128 in 2 chunks of 64
    for (int kc2=0; kc2<2; ++kc2) {
      if (kc2) __syncthreads();        // Ws2 restage
      #pragma unroll
      for (int i=0;i<4;++i) {          // stage Ws2 [256][64] from W2, k cols s*128+kc2*64..
        const int li  = i*8192 + tid*16;
        const int row = li >> 7;
        const int col = ((li & 127) ^ ((row & 7) << 4)) >> 1;
        const ushort* gb = W2 + (size_t)row*1024 + s*128 + kc2*64 + col;
        char* lb = lds + i*8192 + w*1024;
        __builtin_amdgcn_global_load_lds((const __attribute__((address_space(1))) unsigned int*)gb,
                                         (__attribute__((address_space(3))) unsigned int*)lb, 16, 0, 0);
      }
      __syncthreads();
      #pragma unroll
      for (int ks=0; ks<2; ++ks) {
        bf16x8 af[4], bf[4];
        #pragma unroll
        for (int mi=0;mi<4;++mi) {
          int row = wr*64 + mi*16 + c16;
          int colb = kc2*128 + g*16 + ks*64;     // byte col in Hs row (256 B)
          af[mi] = *(const bf16x8*)(lds + 32768 + row*256 + (colb ^ ((row&7)<<4)));
        }
        const int cb = (g*16 + ks*64) ^ swzr;
        #pragma unroll
        for (int ni=0;ni<4;++ni)
          bf[ni] = *(const bf16x8*)(lds + (wc*64 + ni*16 + c16)*128 + cb);
        #pragma unroll
        for (int mi=0;mi<4;++mi)
          #pragma unroll
          for (int ni=0;ni<4;++ni)
            tac[mi][ni] = __builtin_amdgcn_mfma_f32_16x16x32_bf16(af[mi], bf[ni], tac[mi][ni], 0,0,0);
      }
    }
    __syncthreads();                   // Ws2/Hs reads done before next slice overwrites
  }

  // ---- epilogue: y = t + b2 + resid; LN over 256 cols; write xb ----
  float bvs[4], svs[4], bbs[4];
  #pragma unroll
  for (int ni=0;ni<4;++ni) {
    int col = wc*64 + ni*16 + c16;
    bvs[ni] = b2[col]; svs[ni] = lns[col]; bbs[ni] = lnb[col];
  }
  float ps[4][4], pq[4][4];
  #pragma unroll
  for (int mi=0;mi<4;++mi) {
    #pragma unroll
    for (int r=0;r<4;++r) {
      ps[mi][r]=0.f; pq[mi][r]=0.f;
      const int lrow = wr*64 + mi*16 + 4*g + r;
      const ushort* xr = xb + (size_t)(xbase + lrow)*256;
      #pragma unroll
      for (int ni=0;ni<4;++ni) {
        float y = tac[mi][ni][r] + bvs[ni] + b2f(xr[wc*64 + ni*16 + c16]);
        tac[mi][ni][r] = y;
        ps[mi][r] += y;
        pq[mi][r] += y*y;
      }
    }
  }
  #pragma unroll
  for (int mi=0;mi<4;++mi)
    #pragma unroll
    for (int r=0;r<4;++r) {
      #pragma unroll
      for (int off=1; off<16; off<<=1) {
        ps[mi][r] += __shfl_xor(ps[mi][r], off, 16);
        pq[mi][r] += __shfl_xor(pq[mi][r], off, 16);
      }
    }
  if (c16 == 0) {
    #pragma unroll
    for (int mi=0;mi<4;++mi)
      #pragma unroll
      for (int r=0;r<4;++r) {
        const int lrow = wr*64 + mi*16 + 4*g + r;
        red[wc][0][lrow] = ps[mi][r];
        red[wc][1][lrow] = pq[mi][r];
      }
  }
  __syncthreads();
  const int cexact = *cnt;
  #pragma unroll
  for (int mi=0;mi<4;++mi) {
    #pragma unroll
    for (int r=0;r<4;++r) {
      const int lrow = wr*64 + mi*16 + 4*g + r;
      float tsum = red[0][0][lrow] + red[1][0][lrow] + red[2][0][lrow] + red[3][0][lrow];
      float tsq  = red[0][1][lrow] + red[1][1][lrow] + red[2][1][lrow] + red[3][1][lrow];
      float mean = tsum * (1.f/256.f);
      float var  = tsq * (1.f/256.f) - mean*mean;
      float inv  = rsqrtf(var + 1e-5f);
      if (m0 + lrow < cexact) {
        ushort* xbr = xb + (size_t)(xbase + lrow)*256;
        #pragma unroll
        for (int ni=0;ni<4;++ni) {
          int col = wc*64 + ni*16 + c16;
          xbr[col] = f2b((tac[mi][ni][r] - mean)*inv*svs[ni] + bbs[ni]);
        }
      }
    }
  }
}

// ---------------- MFMA flash attention on compact rows: block per (b,h) ----------------
__global__ __launch_bounds__(256) void k_attn_mfma(
    const ushort* __restrict__ qkv, ushort* __restrict__ ctx,
    const int* __restrict__ offc)
{
  __shared__ alignas(16) char lds[81920];
  char* Kb = lds;
  char* Vt = lds + 24576;
  const int tid = threadIdx.x;
  const int w = tid >> 6, l = tid & 63;
  const int g = l >> 4, c = l & 15;
  char* Pw = lds + 57344 + w*6144;
  const int bl = blockIdx.x >> 2, h = blockIdx.x & 3;
  const int rowbase = offc[bl] - offc[0];
  const int len = offc[bl+1] - offc[bl];
  const int nkt = (len + 15) >> 4;
  const int nkf = (len + 31) >> 5;
  const ushort* base = qkv + (size_t)rowbase*768;
  ushort* cbase = ctx + (size_t)rowbase*256;

  const int lenk8 = nkt*16*8;
  for (int idx = tid; idx < lenk8; idx += 256) {
    int row = idx >> 3, ch = idx & 7;
    uint4 v = *(const uint4*)(base + (size_t)row*768 + 256 + h*64 + ch*8);
    *(uint4*)(Kb + ((row*128 + ch*16) ^ ((row&7)<<4))) = v;
  }
  {
    const int lenv = nkf*32;
    int d0 = (tid & 15)*4;
    for (int key = tid >> 4; key < lenv; key += 16) {
      ushort4 v = *(const ushort4*)(base + (size_t)key*768 + 512 + h*64 + d0);
      ushort vv[4] = {v.x, v.y, v.z, v.w};
      #pragma unroll
      for (int j=0;j<4;++j) {
        int d = d0 + j;
        *(ushort*)(Vt + ((d*512 + key*2) ^ ((d&7)<<4))) = vv[j];
      }
    }
  }
  __syncthreads();

  for (int t = nkt; t < 2*nkf; ++t) {
    #pragma unroll
    for (int r=0;r<4;++r) {
      int q = 4*g + r;
      *(ushort*)(Pw + (((t>>1)*1024 + q*64 + ((t&1)*16 + c)*2) ^ (((q>>2)&3)<<4))) = 0;
    }
  }

  const int nst = (len + 15) >> 4;
  for (int s = w; s < nst; s += 4) {
    const ushort* qp = base + (size_t)(s*16 + c)*768 + h*64 + g*8;
    bf16x8 aq0 = *(const bf16x8*)qp;
    bf16x8 aq1 = *(const bf16x8*)(qp + 32);

    f32x4 sc[12];
    #pragma unroll
    for (int t=0;t<12;++t) {
      sc[t] = (f32x4){0.f,0.f,0.f,0.f};
      if (t < nkt) {
        int ba0 = ((t*16 + c)*128 + g*16)      ^ ((c&7)<<4);
        int ba1 = ((t*16 + c)*128 + g*16 + 64) ^ ((c&7)<<4);
        bf16x8 k0 = *(const bf16x8*)(Kb + ba0);
        bf16x8 k1 = *(const bf16x8*)(Kb + ba1);
        sc[t] = __builtin_amdgcn_mfma_f32_16x16x32_bf16(aq0, k0, sc[t], 0,0,0);
        sc[t] = __builtin_amdgcn_mfma_f32_16x16x32_bf16(aq1, k1, sc[t], 0,0,0);
        if (t == nkt-1 && t*16 + c >= len)
          sc[t] = (f32x4){-1e30f,-1e30f,-1e30f,-1e30f};
      }
    }
    float mr[4] = {-1e30f,-1e30f,-1e30f,-1e30f};
    #pragma unroll
    for (int t=0;t<12;++t) if (t<nkt) {
      #pragma unroll
      for (int r=0;r<4;++r) mr[r] = fmaxf(mr[r], sc[t][r]);
    }
    #pragma unroll
    for (int r=0;r<4;++r) {
      mr[r] = fmaxf(mr[r], __shfl_xor(mr[r], 1, 16));
      mr[r] = fmaxf(mr[r], __shfl_xor(mr[r], 2, 16));
      mr[r] = fmaxf(mr[r], __shfl_xor(mr[r], 4, 16));
      mr[r] = fmaxf(mr[r], __shfl_xor(mr[r], 8, 16));
    }
    float sr[4] = {0.f,0.f,0.f,0.f};
    #pragma unroll
    for (int t=0;t<12;++t) if (t<nkt) {
      #pragma unroll
      for (int r=0;r<4;++r) {
        float p = __expf((sc[t][r] - mr[r]) * 0.125f);
        sr[r] += p;
        int q = 4*g + r;
        *(ushort*)(Pw + (((t>>1)*1024 + q*64 + ((t&1)*16 + c)*2) ^ (((q>>2)&3)<<4))) = f2b(p);
      }
    }
    #pragma unroll
    for (int r=0;r<4;++r) {
      sr[r] += __shfl_xor(sr[r], 1, 16);
      sr[r] += __shfl_xor(sr[r], 2, 16);
      sr[r] += __shfl_xor(sr[r], 4, 16);
      sr[r] += __shfl_xor(sr[r], 8, 16);
    }
    f32x4 oa[4];
    #pragma unroll
    for (int dt=0;dt<4;++dt) oa[dt] = (f32x4){0.f,0.f,0.f,0.f};
    #pragma unroll
    for (int kf=0;kf<6;++kf) if (kf<nkf) {
      bf16x8 pf = *(const bf16x8*)(Pw + ((kf*1024 + c*64 + g*16) ^ (((c>>2)&3)<<4)));
      #pragma unroll
      for (int dt=0;dt<4;++dt) {
        int d = dt*16 + c;
        bf16x8 vf = *(const bf16x8*)(Vt + ((d*512 + kf*64 + g*16) ^ ((d&7)<<4)));
        oa[dt] = __builtin_amdgcn_mfma_f32_16x16x32_bf16(pf, vf, oa[dt], 0,0,0);
      }
    }
    float inv[4];
    #pragma unroll
    for (int r=0;r<4;++r) inv[r] = 1.f / sr[r];
    ushort* orow = cbase + (size_t)(s*16)*256 + h*64;
    #pragma unroll
    for (int r=0;r<4;++r) {
      int q = 4*g + r;
      if (s*16 + q < len) {
        #pragma unroll
        for (int dt=0;dt<4;++dt)
          orow[(size_t)q*256 + dt*16 + c] = f2b(oa[dt][r] * inv[r]);
      }
    }
  }
}

// ---------------- ragged weighted pooling (compact bf16 x) + concat id embeddings ----------------
__global__ __launch_bounds__(256) void k_pool(
    const ushort* __restrict__ xb, const int* __restrict__ off,
    const float* __restrict__ attr_tf, const float* __restrict__ attr_feat,
    const int* __restrict__ lens_u, const int* __restrict__ lens_i,
    const int* __restrict__ user_ids, const int* __restrict__ item_ids,
    const float* __restrict__ user_tab, const float* __restrict__ item_tab,
    const float* __restrict__ feat_w, const float* __restrict__ feat_b,
    float* __restrict__ user_out, float* __restrict__ item_out)
{
  __shared__ float wu[L_], tf[L_];
  const int b = blockIdx.x;
  const int t = threadIdx.x;
  if (t < L_) {
    const float* f = attr_feat + ((size_t)b*L_ + t)*NF_;
    float sacc = feat_b[0];
    #pragma unroll
    for (int j=0;j<NF_;++j) sacc = fmaf(f[j], feat_w[j], sacc);
    wu[t] = 1.f/(1.f+__expf(-sacc));
    tf[t] = attr_tf[b*L_+t];
  }
  __syncthreads();
  const int Lu = lens_u[b], Li = lens_i[b];
  const ushort* xrow = xb + (size_t)off[b]*D_;
  float su=0.f, si=0.f;
  for (int l=0;l<Lu+Li;++l) {
    float val = b2f(xrow[(size_t)l*D_ + t]) * tf[l];
    if (l < Lu) su = fmaf(val, wu[l], su);
    else        si = fmaf(val, 1.f-wu[l], si);
  }
  user_out[(size_t)b*512 + t]       = su/(float)Lu;
  item_out[(size_t)b*512 + t]       = si/(float)Li;
  user_out[(size_t)b*512 + 256 + t] = user_tab[(size_t)user_ids[b]*D_ + t];
  item_out[(size_t)b*512 + 256 + t] = item_tab[(size_t)item_ids[b]*D_ + t];
}

// ---------------- logits + mask + new_targets (bf16 tables) ----------------
__global__ __launch_bounds__(256) void k_logits(
    const int* __restrict__ pos_t, const int* __restrict__ neg_t,
    const int* __restrict__ pos_l, const int* __restrict__ neg_l,
    const ushort* __restrict__ oeu, const ushort* __restrict__ oei,
    const float* __restrict__ user_out, const float* __restrict__ item_out,
    float* __restrict__ out)
{
  const int g = blockIdx.x*4 + (threadIdx.x >> 6);
  const int lane = threadIdx.x & 63;
  const int b = g / NT_;
  const int k = g - b*NT_;
  const int tid_ = (k < LP_) ? pos_t[b*LP_ + k] : neg_t[b*LNEG_ + (k-LP_)];
  const ushort* eu = oeu + (size_t)tid_*512;
  const ushort* ei = oei + (size_t)tid_*512;
  const float* uo = user_out + (size_t)b*512;
  const float* io = item_out + (size_t)b*512;
  const int d0 = lane*8;
  float s = 0.f;
  ushort4 a0 = *(const ushort4*)(eu+d0), a1 = *(const ushort4*)(eu+d0+4);
  float4 u0 = *(const float4*)(uo+d0), u1 = *(const float4*)(uo+d0+4);
  s += b2f(a0.x)*u0.x + b2f(a0.y)*u0.y + b2f(a0.z)*u0.z + b2f(a0.w)*u0.w;
  s += b2f(a1.x)*u1.x + b2f(a1.y)*u1.y + b2f(a1.z)*u1.z + b2f(a1.w)*u1.w;
  ushort4 c0 = *(const ushort4*)(ei+d0), c1 = *(const ushort4*)(ei+d0+4);
  float4 i0 = *(const float4*)(io+d0), i1 = *(const float4*)(io+d0+4);
  s += b2f(c0.x)*i0.x + b2f(c0.y)*i0.y + b2f(c0.z)*i0.z + b2f(c0.w)*i0.w;
  s += b2f(c1.x)*i1.x + b2f(c1.y)*i1.y + b2f(c1.z)*i1.z + b2f(c1.w)*i1.w;
  #pragma unroll
  for (int off=32; off>0; off>>=1) s += __shfl_xor(s, off, 64);
  if (lane == 0) {
    out[(size_t)b*NT_ + k] = s;
    float mv, nt;
    if (k < LP_) { mv = (k < pos_l[b]) ? 1.f : 0.f; nt = mv; }
    else         { mv = ((k - LP_) < neg_l[b]) ? 1.f : 0.f; nt = 0.f; }
    out[(size_t)B_*NT_   + (size_t)b*NT_ + k] = mv;
    out[(size_t)2*B_*NT_ + (size_t)b*NT_ + k] = nt;
  }
}

extern "C" void kernel_launch(void* const* d_in, const int* in_sizes, int n_in,
                              void* d_out, int out_size, void* d_ws, size_t ws_size,
                              hipStream_t stream)
{
  const int*   attr      = (const int*)d_in[0];
  const int*   attr_inds = (const int*)d_in[1];
  const float* attr_tf   = (const float*)d_in[2];
  const float* attr_feat = (const float*)d_in[3];
  const int*   attr_lens = (const int*)d_in[4];
  const int*   lens_u    = (const int*)d_in[5];
  const int*   lens_i    = (const int*)d_in[6];
  const int*   user_ids  = (const int*)d_in[7];
  const int*   item_ids  = (const int*)d_in[8];
  const int*   pos_t     = (const int*)d_in[9];
  const int*   pos_l     = (const int*)d_in[10];
  const int*   neg_t     = (const int*)d_in[11];
  const int*   neg_l     = (const int*)d_in[12];
  const float* attr_emb  = (const float*)d_in[13];
  const float* ind_emb   = (const float*)d_in[14];
  const float* user_tab  = (const float*)d_in[15];
  const float* item_tab  = (const float*)d_in[16];
  const float* oeu       = (const float*)d_in[17];
  const float* oei       = (const float*)d_in[18];
  const float* feat_w    = (const float*)d_in[19];
  const float* feat_b    = (const float*)d_in[20];
  const float* Wqkv      = (const float*)d_in[21];
  const float* bqkv      = (const float*)d_in[22];
  const float* Wo        = (const float*)d_in[23];
  const float* bo        = (const float*)d_in[24];
  const float* ln1s      = (const float*)d_in[25];
  const float* ln1b      = (const float*)d_in[26];
  const float* W1        = (const float*)d_in[27];
  const float* b1        = (const float*)d_in[28];
  const float* W2        = (const float*)d_in[29];
  const float* b2        = (const float*)d_in[30];
  const float* ln2s      = (const float*)d_in[31];
  const float* ln2b      = (const float*)d_in[32];

  // ---- ws layout: ints[768] | uo[B,512]f32 | io[B,512]f32 | xb[M,256]bf16 | weights bf16 | oeu_b | oei_b | chunk scratch ----
  int* ioff  = (int*)d_ws;            // off[513]
  int* ccnt  = ioff + 520;
  int* ccntp = ccnt + 64;
  float* ws = (float*)d_ws + 768;
  float* uo = ws;
  float* io = uo + (size_t)B_*512;
  ushort* xb   = (ushort*)(io + (size_t)B_*512);
  ushort* wq_b = xb + (size_t)M_*D_;
  ushort* wo_b = wq_b + (size_t)2*768*256;
  ushort* w1_b = wo_b + (size_t)2*256*256;
  ushort* w2_b = w1_b + (size_t)2*1024*256;
  ushort* oeu_b = w2_b + (size_t)2*256*1024;
  ushort* oei_b = oeu_b + (size_t)V_*512;
  float* scratch = (float*)(oei_b + (size_t)V_*512);

  // scratch per chunk: qkv_b(Mc*384) + ctx_b(Mc*128) = Mc*512 floats
  const size_t fixed_floats = 768 + (size_t)B_*1024 + (size_t)M_*(D_/2) + 786432 + (size_t)V_*512;
  int Bc = 8;
  for (int cand = 512; cand >= 8; cand >>= 1) {
    size_t need = (fixed_floats + (size_t)cand*L_*512) * sizeof(float);
    if (need <= ws_size) { Bc = cand; break; }
  }
  const int nchunks = B_ / Bc;
  const size_t Mc = (size_t)Bc * L_;

  float* out = (float*)d_out;

  k_prefix<<<1, 512, 0, stream>>>(attr_lens, ioff, ccnt, ccntp, Bc, nchunks);
  k_f2b4<<<768, 256, 0, stream>>>(Wqkv, Wo, W1, W2, wq_b, wo_b, w1_b, w2_b);
  k_f2b<<<(V_*512)/2048, 256, 0, stream>>>(oeu, oeu_b);
  k_f2b<<<(V_*512)/2048, 256, 0, stream>>>(oei, oei_b);
  k_embed<<<M_*64/256, 256, 0, stream>>>(attr, attr_inds, attr_lens, ioff, attr_emb, ind_emb, xb);

  for (int l=0; l<NL_; ++l) {
    const float* bqkv_l = bqkv + (size_t)l*768;
    const float* bo_l   = bo   + (size_t)l*D_;
    const float* b1_l   = b1   + (size_t)l*FF_;
    const float* b2_l   = b2   + (size_t)l*D_;
    for (int c=0; c<nchunks; ++c) {
      const int* offc = ioff + c*Bc;
      const int* cntp = ccntp + c;
      const int* cnt  = ccnt + c;
      ushort* qkv_b = (ushort*)scratch;                 // [Mc,768] bf16
      ushort* ctx_b = (ushort*)(scratch + Mc*384);      // [Mc,256] bf16

      k_gemm_mfma<1,0><<<dim3(768/128, Mc/128), 256, 0, stream>>>(
          xb, offc, cntp, wq_b + (size_t)l*768*256, bqkv_l, qkv_b, 768, 256);
      k_attn_mfma<<<Bc*H_, 256, 0, stream>>>(qkv_b, ctx_b, offc);
      k_gemm_ln<<<Mc/128, 512, 0, stream>>>(
          ctx_b, cntp, cnt, offc, wo_b + (size_t)l*256*256, bo_l,
          ln1s + (size_t)l*D_, ln1b + (size_t)l*D_, xb, 256);
      k_ffn<<<Mc/128, 512, 0, stream>>>(
          cntp, cnt, offc, w1_b + (size_t)l*1024*256, b1_l,
          w2_b + (size_t)l*256*1024, b2_l,
          ln2s + (size_t)l*D_, ln2b + (size_t)l*D_, xb);
    }
  }
  k_pool<<<B_, 256, 0, stream>>>(xb, ioff, attr_tf, attr_feat, lens_u, lens_i, user_ids, item_ids,
                                 user_tab, item_tab, feat_w, feat_b, uo, io);
  k_logits<<<B_*NT_/4, 256, 0, stream>>>(pos_t, neg_t, pos_l, neg_l, oeu_b, oei_b, uo, io, out);
}